// Round 9
// baseline (1035.818 us; speedup 1.0000x reference)
//
#include <hip/hip_runtime.h>
#include <hip/hip_bf16.h>
#include <cstdint>
#include <cstddef>

typedef __attribute__((ext_vector_type(8))) short short8;   // 8 x bf16 (4 VGPRs)
typedef __attribute__((ext_vector_type(4))) float f32x4;    // MFMA accumulator

#define DEV static __device__ __forceinline__

constexpr int kS = 1024, kD = 2048, kH = 16, kHD = 128, kF = 8192;
constexpr int kM = 4096;            // B*S rows
constexpr float kEPS = 1e-5f;

// ---------------- workspace layout (bytes) ----------------
constexpr size_t SZ_DD   = (size_t)kD * kD * 2;    // 8 MB   bf16 DxD weight
constexpr size_t SZ_FD   = (size_t)kF * kD * 2;    // 32 MB  bf16 FxD weight
constexpr size_t SZ_MD16 = (size_t)kM * kD * 2;    // 16 MB  bf16 activation
constexpr size_t SZ_MD32 = (size_t)kM * kD * 4;    // 32 MB  f32 activation
constexpr size_t OFF_WQ  = 0;                      // wq/wk/wv contiguous => fused QKV weight
constexpr size_t OFF_WK  = OFF_WQ + SZ_DD;
constexpr size_t OFF_WV  = OFF_WK + SZ_DD;
constexpr size_t OFF_WO  = OFF_WV + SZ_DD;
constexpr size_t OFF_WI  = OFF_WO + SZ_DD;
constexpr size_t OFF_WO2 = OFF_WI + SZ_FD;
constexpr size_t OFF_XB  = OFF_WO2 + SZ_FD;        // region reused for h later
constexpr size_t OFF_Q   = OFF_XB + SZ_MD16;       // q/k/vt contiguous (fused epilogue)
constexpr size_t OFF_K   = OFF_Q + SZ_MD16;
constexpr size_t OFF_V   = OFF_K + SZ_MD16;        // holds V^T layout [bh][hd][s]
constexpr size_t OFF_H   = OFF_XB;                 // 64 MB: xb+q+k+v dead by FFN1
constexpr size_t OFF_CTX = OFF_V + SZ_MD16;
constexpr size_t OFF_Y1  = OFF_CTX + SZ_MD16;      // f32
constexpr size_t OFF_A1B = OFF_Y1 + SZ_MD32;       // bf16 attn_out
constexpr size_t OFF_Y2  = OFF_A1B + SZ_MD16;      // f32 (first 24KB doubles as bqkv early)
constexpr size_t WS_NEED = OFF_Y2 + SZ_MD32;       // 256 MB total
// FFN2 second split-K partial reuses dead wq..wo region (4 x 8MB = 32MB) at OFF_WQ.

DEV void gload16(const void* g, void* l) {
  __builtin_amdgcn_global_load_lds(
      (const __attribute__((address_space(1))) unsigned int*)g,
      (__attribute__((address_space(3))) unsigned int*)l, 16, 0, 0);
}

// ---------------- fp32 -> bf16 convert ----------------
__global__ void cvt_bf16(const float* __restrict__ in, __hip_bfloat16* __restrict__ out, int n4) {
  int stride = gridDim.x * blockDim.x;
  for (int i = blockIdx.x * blockDim.x + threadIdx.x; i < n4; i += stride) {
    float4 v = reinterpret_cast<const float4*>(in)[i];
    union { ushort4 u; __hip_bfloat16 h[4]; } o;
    o.h[0] = __float2bfloat16(v.x);
    o.h[1] = __float2bfloat16(v.y);
    o.h[2] = __float2bfloat16(v.z);
    o.h[3] = __float2bfloat16(v.w);
    reinterpret_cast<ushort4*>(out)[i] = o.u;
  }
}

// ---------------- 256x256 GEMM — m201-style 8-phase barrier-pair schedule ----------------
// C = A[MxK] * Bt[NxK]^T. BK=64, 8 waves 2x4 inside one 128x128 C-quadrant.
// Per phase (4 phases/K-tile, one C-quadrant = 16 MFMA each):
//   { ds_reads ; stage 1 half-tile of t+1 ; s_barrier ; lgkmcnt(0)+sched_barrier ;
//     setprio(1) ; 16 MFMA ; setprio(0) ; [counted vmcnt] ; s_barrier }
// Quads q0(M0N0,A0B0) q1(M0N1,A0B1) q2(M1N1,A1B1) q3(M1N0,A1B0-reread).
// Stage order per tile: A0',B0',B1',A1' at q0..q3. Ledger-derived waits:
// vmcnt(4) at ends of q0,q1,q3 (each waited half >=3 phases old; newest 2
// halves never drained — T4); tail tile: 2/0/none. Reads [12,4,8,4]/wave/tile.
// MODE 0: fused QKV scatter (q/k -> [b,h,s,hd], v -> [b,h,hd,s]), outb = q base
// MODE 2: out bf16 = gelu(acc + bias) at [row*N+col], outb
// MODE 3: raw f32 partial (split-K): out0/out1 selected by split index
template <int MODE>
__global__ __launch_bounds__(512, 2)
void gemm256(const __hip_bfloat16* __restrict__ A,
             const __hip_bfloat16* __restrict__ Bt,
             const float* __restrict__ bias,
             float* __restrict__ out0, float* __restrict__ out1,
             void* __restrict__ outb,
             int M, int N, int K, int kLen) {
  __shared__ __align__(16) char lds[131072];   // A: [2][256][64]b16 @0, B: @65536
  const int tid = threadIdx.x;
  const int lane = tid & 63, w = tid >> 6;
  const int wm = w >> 2, wn = w & 3;           // 2x4 waves inside a 128x128 quadrant
  const int lg = lane >> 4, lr = lane & 15;
  const int gy = M >> 8, gx = N >> 8;
  const int nwg = gridDim.x, orig = blockIdx.x;
  const int l = (orig & 7) * (nwg >> 3) + (orig >> 3);   // XCD-chunked (nwg%8==0)
  const int tilesPer = gx * gy;
  const int spl = l / tilesPer;
  const int rem = l - spl * tilesPer;
  const int bx = rem / gy, by = rem - bx * gy;           // n-panel-major
  const int m0 = by * 256, n0 = bx * 256;
  const int k0 = spl * kLen;
  const int NT = kLen >> 6;                               // even for all our shapes

  // staging source pointers (half 0=A0,1=A1,2=B0,3=B1; i 0..1), tile-0 based
  const char* gs[8];
  #pragma unroll
  for (int h = 0; h < 4; ++h) {
    const __hip_bfloat16* src = (h < 2) ? A : Bt;
    const int r0 = ((h < 2) ? m0 : n0) + (h & 1) * 128;
    #pragma unroll
    for (int i = 0; i < 2; ++i) {
      int c = i * 512 + tid;
      int row = c >> 3, slot = c & 7;
      gs[h * 2 + i] =
          (const char*)(src + (size_t)(r0 + row) * K + k0 + (slot ^ (row & 7)) * 8);
    }
  }

#define STAGE(P, H, TOFF)                                                          \
  {                                                                                \
    char* dstb = lds + (((H) < 2) ? 0 : 65536) + (P) * 32768 + ((H) & 1) * 16384;  \
    gload16(gs[(H) * 2 + 0] + (TOFF) * 128, dstb + (0 * 512 + tid) * 16);          \
    gload16(gs[(H) * 2 + 1] + (TOFF) * 128, dstb + (1 * 512 + tid) * 16);          \
  }

  auto ldA = [&](int P, int qm, int mr, int kk) {
    int row = qm * 128 + wm * 64 + mr * 16 + lr;
    return *reinterpret_cast<const short8*>(
        lds + P * 32768 + row * 128 + (((kk * 4 + lg) ^ (row & 7)) * 16));
  };
  auto ldB = [&](int P, int qn, int nr, int kk) {
    int row = qn * 128 + wn * 32 + nr * 16 + lr;
    return *reinterpret_cast<const short8*>(
        lds + 65536 + P * 32768 + row * 128 + (((kk * 4 + lg) ^ (row & 7)) * 16));
  };

  f32x4 acc[4][4][2] = {};   // [quad][mi][ni]

#define MFMA_QUAD(q, B)                                                         \
  _Pragma("unroll")                                                             \
  for (int kk = 0; kk < 2; ++kk)                                                \
    _Pragma("unroll")                                                           \
    for (int mi = 0; mi < 4; ++mi)                                              \
      _Pragma("unroll")                                                         \
      for (int ni = 0; ni < 2; ++ni)                                            \
        acc[q][mi][ni] = __builtin_amdgcn_mfma_f32_16x16x32_bf16(               \
            av[kk][mi], B[kk][ni], acc[q][mi][ni], 0, 0, 0);

// phase core: opening barrier, full lgkm drain, prio-wrapped 16-MFMA burst,
// optional counted vmcnt, closing barrier (publishes the waited halves).
#define PHASE_CORE(Q, B, WAITSTMT)                                              \
    __builtin_amdgcn_s_barrier();                                               \
    asm volatile("s_waitcnt lgkmcnt(0)" ::: "memory");                          \
    __builtin_amdgcn_sched_barrier(0);                                          \
    __builtin_amdgcn_s_setprio(1);                                              \
    MFMA_QUAD(Q, B)                                                             \
    __builtin_amdgcn_s_setprio(0);                                              \
    WAITSTMT                                                                    \
    __builtin_amdgcn_s_barrier();

#define VM(n) asm volatile("s_waitcnt vmcnt(" #n ")" ::: "memory");

// One K-tile; P = literal buffer parity, PF = prefetch next tile (TOFF = 1+P).
#define TILE_BODY(P, PF)                                                        \
  {                                                                             \
    /* q0: read A0(8)+B0(4); stage A0' ; end-wait covers q1's B1(t) */          \
    _Pragma("unroll")                                                           \
    for (int i = 0; i < 4; ++i) av[0][i] = ldA(P, 0, i, 0);                     \
    _Pragma("unroll")                                                           \
    for (int i = 0; i < 2; ++i) b0[0][i] = ldB(P, 0, i, 0);                     \
    _Pragma("unroll")                                                           \
    for (int i = 0; i < 4; ++i) av[1][i] = ldA(P, 0, i, 1);                     \
    _Pragma("unroll")                                                           \
    for (int i = 0; i < 2; ++i) b0[1][i] = ldB(P, 0, i, 1);                     \
    if (PF) STAGE((P) ^ 1, 0, 1 + (P))                                          \
    if (PF) { PHASE_CORE(0, b0, VM(4)) } else { PHASE_CORE(0, b0, VM(2)) }      \
    /* q1: read B1(4), reuse av(A0); stage B0' ; end-wait covers q2's A1(t) */  \
    _Pragma("unroll")                                                           \
    for (int i = 0; i < 2; ++i) b1[0][i] = ldB(P, 1, i, 0);                     \
    _Pragma("unroll")                                                           \
    for (int i = 0; i < 2; ++i) b1[1][i] = ldB(P, 1, i, 1);                     \
    if (PF) STAGE((P) ^ 1, 2, 1 + (P))                                          \
    if (PF) { PHASE_CORE(1, b1, VM(4)) } else { PHASE_CORE(1, b1, VM(0)) }      \
    /* q2: read A1(8), reuse b1; stage B1' ; no end-wait */                     \
    _Pragma("unroll")                                                           \
    for (int i = 0; i < 4; ++i) av[0][i] = ldA(P, 1, i, 0);                     \
    _Pragma("unroll")                                                           \
    for (int i = 0; i < 4; ++i) av[1][i] = ldA(P, 1, i, 1);                     \
    if (PF) STAGE((P) ^ 1, 3, 1 + (P))                                          \
    PHASE_CORE(2, b1, )                                                         \
    /* q3: re-read B0(4), reuse av(A1); stage A1' ; end-wait covers next q0 */  \
    _Pragma("unroll")                                                           \
    for (int i = 0; i < 2; ++i) b0[0][i] = ldB(P, 0, i, 0);                     \
    _Pragma("unroll")                                                           \
    for (int i = 0; i < 2; ++i) b0[1][i] = ldB(P, 0, i, 1);                     \
    if (PF) STAGE((P) ^ 1, 1, 1 + (P))                                          \
    if (PF) { PHASE_CORE(3, b0, VM(4)) } else { PHASE_CORE(3, b0, ) }           \
  }

  // prologue: stage tile0 in order A0,B0,B1,A1; retire A0,B0 (q0's operands)
  STAGE(0, 0, 0) STAGE(0, 2, 0) STAGE(0, 3, 0) STAGE(0, 1, 0)
  VM(4)
  __builtin_amdgcn_s_barrier();

  for (int t2 = 0; t2 < NT; t2 += 2) {
    short8 av[2][4], b0[2][2], b1[2][2];
    TILE_BODY(0, true)
    TILE_BODY(1, (t2 + 2 < NT))
    #pragma unroll
    for (int j = 0; j < 8; ++j) gs[j] += 256;
  }
#undef TILE_BODY
#undef PHASE_CORE
#undef MFMA_QUAD
#undef VM
#undef STAGE

  // epilogue: q0=(0,0) q1=(0,1) q2=(1,1) q3=(1,0)
  #pragma unroll
  for (int q = 0; q < 4; ++q) {
    const int qm = (q >= 2) ? 1 : 0;
    const int qn = (q == 1 || q == 2) ? 1 : 0;
    #pragma unroll
    for (int ni = 0; ni < 2; ++ni) {
      int col = n0 + qn * 128 + wn * 32 + ni * 16 + lr;
      float bvv = 0.f;
      if constexpr (MODE != 3) bvv = bias[col];
      #pragma unroll
      for (int mi = 0; mi < 4; ++mi) {
        int row0 = m0 + qm * 128 + wm * 64 + mi * 16 + lg * 4;
        #pragma unroll
        for (int r = 0; r < 4; ++r) {
          int row = row0 + r;
          float val = acc[q][mi][ni][r] + bvv;
          if constexpr (MODE == 0) {
            int which = col >> 11;                  // 0=q 1=k 2=v
            int d = col & 2047;
            int hh = d >> 7, hd = d & 127;
            int bb = row >> 10, ss = row & 1023;
            __hip_bfloat16* base = (__hip_bfloat16*)outb + (size_t)which * ((size_t)kM * kD);
            if (which < 2)
              base[(((size_t)(bb * kH + hh)) * kS + ss) * kHD + hd] = __float2bfloat16(val);
            else
              base[(((size_t)(bb * kH + hh)) * kHD + hd) * kS + ss] = __float2bfloat16(val);
          } else if constexpr (MODE == 2) {
            float g = 0.5f * val * (1.0f + erff(val * 0.70710678118654752f));
            ((__hip_bfloat16*)outb)[(size_t)row * N + col] = __float2bfloat16(g);
          } else {
            float* o = spl ? out1 : out0;
            o[(size_t)row * N + col] = val;
          }
        }
      }
    }
  }
}

// ---------------- flash attention (unchanged) ----------------
__global__ __launch_bounds__(512, 4)
void attn_fwd(const __hip_bfloat16* __restrict__ q,
              const __hip_bfloat16* __restrict__ k,
              const __hip_bfloat16* __restrict__ vt,
              const float* __restrict__ mask,
              __hip_bfloat16* __restrict__ ctx) {
  __shared__ __align__(16) char Ks[2][64 * 256];    // [buf][key][dim] slot16^(row&15)
  __shared__ __align__(16) char Vt[2][128 * 128];   // [buf][hd][key64] slot8^(row&7)
  __shared__ __align__(16) char Ps[8][2048];        // per-wave P [16][64], ^((row&7)<<4)
  const int tid = threadIdx.x, lane = tid & 63, w = tid >> 6;
  const int lg = lane >> 4, lr = lane & 15;
  const int orig = blockIdx.x;                      // 512 blocks
  const int l = (orig & 7) * 64 + (orig >> 3);      // XCD-chunked: 8 bh per XCD
  const int qt = l & 7, bh = l >> 3;
  const int b = bh >> 4;

  short8 qf[4];
  {
    const __hip_bfloat16* qp =
        q + ((size_t)bh * kS + qt * 128 + w * 16 + lr) * kHD + lg * 8;
    #pragma unroll
    for (int kk = 0; kk < 4; ++kk) qf[kk] = *reinterpret_cast<const short8*>(qp + kk * 32);
  }

  auto stage = [&](int bufi, int t) {
    #pragma unroll
    for (int i = 0; i < 2; ++i) {                   // K tile: 64 rows x 256B
      int c = i * 512 + tid;
      int row = c >> 4, slot = c & 15;
      gload16(k + ((size_t)bh * kS + t * 64 + row) * kHD + (slot ^ (row & 15)) * 8,
              Ks[bufi] + c * 16);
    }
    #pragma unroll
    for (int i = 0; i < 2; ++i) {                   // V^T tile: 128 rows x 128B
      int c = i * 512 + tid;
      int row = c >> 3, slot = c & 7;
      gload16(vt + ((size_t)bh * kHD + row) * kS + t * 64 + (slot ^ (row & 7)) * 8,
              Vt[bufi] + c * 16);
    }
  };

  f32x4 o[8] = {};
  float mrun[4], lrun[4];
  #pragma unroll
  for (int r = 0; r < 4; ++r) { mrun[r] = -1e30f; lrun[r] = 0.f; }
  const float scale = 0.08838834764831845f;         // 1/sqrt(128)

  stage(0, 0);
  __syncthreads();

  int buf = 0;
  for (int t = 0; t < 16; ++t) {
    if (t + 1 < 16) stage(buf ^ 1, t + 1);

    f32x4 sacc[4] = {};
    #pragma unroll
    for (int j = 0; j < 4; ++j) {
      int key = j * 16 + lr;
      #pragma unroll
      for (int kk = 0; kk < 4; ++kk) {
        short8 bfrag = *reinterpret_cast<const short8*>(
            Ks[buf] + key * 256 + (((kk * 4 + lg) ^ (key & 15)) * 16));
        sacc[j] = __builtin_amdgcn_mfma_f32_16x16x32_bf16(qf[kk], bfrag, sacc[j], 0, 0, 0);
      }
    }
    float sarr[4][4];
    #pragma unroll
    for (int j = 0; j < 4; ++j) {
      float mv = mask[(size_t)b * kS + t * 64 + j * 16 + lr];
      #pragma unroll
      for (int r = 0; r < 4; ++r) sarr[j][r] = sacc[j][r] * scale + mv;
    }
    #pragma unroll
    for (int r = 0; r < 4; ++r) {
      float tm = fmaxf(fmaxf(sarr[0][r], sarr[1][r]), fmaxf(sarr[2][r], sarr[3][r]));
      #pragma unroll
      for (int d = 1; d < 16; d <<= 1) tm = fmaxf(tm, __shfl_xor(tm, d));
      float mnew = fmaxf(mrun[r], tm);
      float alpha = __expf(mrun[r] - mnew);
      mrun[r] = mnew;
      float rs = 0.f;
      #pragma unroll
      for (int j = 0; j < 4; ++j) {
        float p = __expf(sarr[j][r] - mnew);
        sarr[j][r] = p;
        rs += p;
      }
      #pragma unroll
      for (int d = 1; d < 16; d <<= 1) rs += __shfl_xor(rs, d);
      lrun[r] = lrun[r] * alpha + rs;
      #pragma unroll
      for (int n = 0; n < 8; ++n) o[n][r] *= alpha;
    }
    #pragma unroll
    for (int r = 0; r < 4; ++r) {
      int qr = lg * 4 + r;
      #pragma unroll
      for (int j = 0; j < 4; ++j)
        *reinterpret_cast<__hip_bfloat16*>(
            Ps[w] + ((qr * 128 + (j * 16 + lr) * 2) ^ ((qr & 7) << 4))) =
            __float2bfloat16(sarr[j][r]);
    }
    #pragma unroll
    for (int kk2 = 0; kk2 < 2; ++kk2) {
      short8 pa = *reinterpret_cast<const short8*>(
          Ps[w] + ((lr * 128 + kk2 * 64 + lg * 16) ^ ((lr & 7) << 4)));
      #pragma unroll
      for (int n = 0; n < 8; ++n) {
        int hd = n * 16 + lr;
        short8 vb = *reinterpret_cast<const short8*>(
            Vt[buf] + hd * 128 + (((kk2 * 4 + lg) ^ (hd & 7)) * 16));
        o[n] = __builtin_amdgcn_mfma_f32_16x16x32_bf16(pa, vb, o[n], 0, 0, 0);
      }
    }
    __syncthreads();
    buf ^= 1;
  }

  const int h = bh & 15;
  #pragma unroll
  for (int r = 0; r < 4; ++r) {
    float inv = 1.0f / lrun[r];
    int srow = qt * 128 + w * 16 + lg * 4 + r;
    __hip_bfloat16* cp = ctx + ((size_t)b * kS + srow) * kD + h * 128 + lr;
    #pragma unroll
    for (int n = 0; n < 8; ++n) cp[n * 16] = __float2bfloat16(o[n][r] * inv);
  }
}

// ------- LayerNorm over (p0 + p1 + bias + res), one 2048-row per block -------
template <bool WB16>
__global__ void ln_fuse(const float* __restrict__ p0, const float* __restrict__ p1,
                        const float* __restrict__ bias, const float* __restrict__ res,
                        const float* __restrict__ w, const float* __restrict__ b,
                        float* __restrict__ outf, __hip_bfloat16* __restrict__ outb) {
  const int row = blockIdx.x, tid = threadIdx.x;
  const size_t base = (size_t)row * kD;
  float v[8];
  #pragma unroll
  for (int i = 0; i < 2; ++i) {
    int c4 = tid * 2 + i;
    float4 a  = reinterpret_cast<const float4*>(p0 + base)[c4];
    float4 bb = reinterpret_cast<const float4*>(p1 + base)[c4];
    float4 rr = reinterpret_cast<const float4*>(res + base)[c4];
    float4 bs = reinterpret_cast<const float4*>(bias)[c4];
    v[i * 4 + 0] = a.x + bb.x + rr.x + bs.x;
    v[i * 4 + 1] = a.y + bb.y + rr.y + bs.y;
    v[i * 4 + 2] = a.z + bb.z + rr.z + bs.z;
    v[i * 4 + 3] = a.w + bb.w + rr.w + bs.w;
  }
  float s = 0.f;
  #pragma unroll
  for (int i = 0; i < 8; ++i) s += v[i];
  #pragma unroll
  for (int off = 32; off > 0; off >>= 1) s += __shfl_down(s, off);
  __shared__ float r1[4], r2[4];
  if ((tid & 63) == 0) r1[tid >> 6] = s;
  __syncthreads();
  float mean = (r1[0] + r1[1] + r1[2] + r1[3]) * (1.0f / kD);
  float qv = 0.f;
  #pragma unroll
  for (int i = 0; i < 8; ++i) { float d = v[i] - mean; qv += d * d; }
  #pragma unroll
  for (int off = 32; off > 0; off >>= 1) qv += __shfl_down(qv, off);
  if ((tid & 63) == 0) r2[tid >> 6] = qv;
  __syncthreads();
  float rstd = rsqrtf((r2[0] + r2[1] + r2[2] + r2[3]) * (1.0f / kD) + kEPS);
  #pragma unroll
  for (int i = 0; i < 8; ++i) {
    int col = tid * 8 + i;
    float ov = (v[i] - mean) * rstd * w[col] + b[col];
    outf[base + col] = ov;
    if constexpr (WB16) outb[base + col] = __float2bfloat16(ov);
  }
}

// ---------------- launcher ----------------
extern "C" void kernel_launch(void* const* d_in, const int* in_sizes, int n_in,
                              void* d_out, int out_size, void* d_ws, size_t ws_size,
                              hipStream_t stream) {
  (void)in_sizes; (void)n_in; (void)out_size;
  if (ws_size < WS_NEED) return;
  const float* x    = (const float*)d_in[0];
  const float* mask = (const float*)d_in[1];
  const float* wq   = (const float*)d_in[2];
  const float* bq   = (const float*)d_in[3];
  const float* wk   = (const float*)d_in[4];
  const float* bk   = (const float*)d_in[5];
  const float* wv   = (const float*)d_in[6];
  const float* bv   = (const float*)d_in[7];
  const float* wo   = (const float*)d_in[8];
  const float* bo   = (const float*)d_in[9];
  const float* l1w  = (const float*)d_in[10];
  const float* l1b  = (const float*)d_in[11];
  const float* wi   = (const float*)d_in[12];
  const float* bi   = (const float*)d_in[13];
  const float* wo2  = (const float*)d_in[14];
  const float* bo2  = (const float*)d_in[15];
  const float* l2w  = (const float*)d_in[16];
  const float* l2b  = (const float*)d_in[17];

  char* ws = (char*)d_ws;
  __hip_bfloat16* wqb  = (__hip_bfloat16*)(ws + OFF_WQ);   // fused QKV weight base
  __hip_bfloat16* wkb  = (__hip_bfloat16*)(ws + OFF_WK);
  __hip_bfloat16* wvb  = (__hip_bfloat16*)(ws + OFF_WV);
  __hip_bfloat16* wob  = (__hip_bfloat16*)(ws + OFF_WO);
  __hip_bfloat16* wib  = (__hip_bfloat16*)(ws + OFF_WI);
  __hip_bfloat16* wo2b = (__hip_bfloat16*)(ws + OFF_WO2);
  __hip_bfloat16* xb   = (__hip_bfloat16*)(ws + OFF_XB);
  __hip_bfloat16* qb   = (__hip_bfloat16*)(ws + OFF_Q);    // q/k/vt contiguous
  __hip_bfloat16* kb2  = (__hip_bfloat16*)(ws + OFF_K);
  __hip_bfloat16* vtb  = (__hip_bfloat16*)(ws + OFF_V);
  __hip_bfloat16* hb   = (__hip_bfloat16*)(ws + OFF_H);
  __hip_bfloat16* ctxb = (__hip_bfloat16*)(ws + OFF_CTX);
  __hip_bfloat16* a1b  = (__hip_bfloat16*)(ws + OFF_A1B);
  float* y1   = (float*)(ws + OFF_Y1);
  float* y2   = (float*)(ws + OFF_Y2);
  float* f2p  = (float*)(ws + OFF_WQ);   // FFN2 split-K partial 1 (32MB, weights dead)
  float* bqkv = (float*)(ws + OFF_Y2);   // 24KB concat bias; dead before Wo writes y2

  // fp32 -> bf16 conversions
  cvt_bf16<<<2048, 256, 0, stream>>>(x,   xb,   kM * kD / 4);
  cvt_bf16<<<1024, 256, 0, stream>>>(wq,  wqb,  kD * kD / 4);
  cvt_bf16<<<1024, 256, 0, stream>>>(wk,  wkb,  kD * kD / 4);
  cvt_bf16<<<1024, 256, 0, stream>>>(wv,  wvb,  kD * kD / 4);
  cvt_bf16<<<1024, 256, 0, stream>>>(wo,  wob,  kD * kD / 4);
  cvt_bf16<<<2048, 256, 0, stream>>>(wi,  wib,  kF * kD / 4);
  cvt_bf16<<<2048, 256, 0, stream>>>(wo2, wo2b, kF * kD / 4);
  // concat QKV bias into scratch
  hipMemcpyAsync(bqkv,          bq, kD * 4, hipMemcpyDeviceToDevice, stream);
  hipMemcpyAsync(bqkv + kD,     bk, kD * 4, hipMemcpyDeviceToDevice, stream);
  hipMemcpyAsync(bqkv + 2 * kD, bv, kD * 4, hipMemcpyDeviceToDevice, stream);

  dim3 blk(512);
  // fused QKV projection: M=4096, N=6144, K=2048 -> grid 24*16 = 384
  gemm256<0><<<dim3(384), blk, 0, stream>>>(
      xb, wqb, bqkv, nullptr, nullptr, qb, kM, 6144, kD, kD);
  // attention
  attn_fwd<<<dim3(512), dim3(512), 0, stream>>>(qb, kb2, vtb, mask, ctxb);
  // out proj, split-K x2 (grid 2*8*16 = 256), partials y1,y2; LN1 fuses +bo+x
  gemm256<3><<<dim3(256), blk, 0, stream>>>(
      ctxb, wob, nullptr, y1, y2, nullptr, kM, kD, kD, kD / 2);
  ln_fuse<true><<<kM, 256, 0, stream>>>(y1, y2, bo, x, l1w, l1b, y1, a1b);
  // FFN1: M=4096, N=8192, K=2048 -> grid 32*16 = 512, GELU epilogue
  gemm256<2><<<dim3(512), blk, 0, stream>>>(
      a1b, wib, bi, nullptr, nullptr, hb, kM, kF, kD, kD);
  // FFN2: split-K x2 (grid 256), partials y2,f2p; LN2 fuses +bo2+attn_out(y1)
  gemm256<3><<<dim3(256), blk, 0, stream>>>(
      hb, wo2b, nullptr, y2, f2p, nullptr, kM, kD, kF, kF / 2);
  ln_fuse<false><<<kM, 256, 0, stream>>>(y2, f2p, bo2, y1, l2w, l2b, (float*)d_out, nullptr);
}

// Round 10
// 673.841 us; speedup vs baseline: 1.5372x; 1.5372x over previous
//
#include <hip/hip_runtime.h>
#include <hip/hip_bf16.h>
#include <cstdint>
#include <cstddef>

typedef __attribute__((ext_vector_type(8))) short short8;   // 8 x bf16 (4 VGPRs)
typedef __attribute__((ext_vector_type(4))) float f32x4;    // MFMA accumulator

#define DEV static __device__ __forceinline__

constexpr int kS = 1024, kD = 2048, kH = 16, kHD = 128, kF = 8192;
constexpr int kM = 4096;            // B*S rows
constexpr float kEPS = 1e-5f;

// ---------------- workspace layout (bytes) ----------------
constexpr size_t SZ_DD   = (size_t)kD * kD * 2;    // 8 MB   bf16 DxD weight
constexpr size_t SZ_FD   = (size_t)kF * kD * 2;    // 32 MB  bf16 FxD weight
constexpr size_t SZ_MD16 = (size_t)kM * kD * 2;    // 16 MB  bf16 activation
constexpr size_t SZ_MD32 = (size_t)kM * kD * 4;    // 32 MB  f32 activation
constexpr size_t OFF_WQ  = 0;                      // wq/wk/wv contiguous => fused QKV weight
constexpr size_t OFF_WK  = OFF_WQ + SZ_DD;
constexpr size_t OFF_WV  = OFF_WK + SZ_DD;
constexpr size_t OFF_WO  = OFF_WV + SZ_DD;
constexpr size_t OFF_WI  = OFF_WO + SZ_DD;
constexpr size_t OFF_WO2 = OFF_WI + SZ_FD;
constexpr size_t OFF_XB  = OFF_WO2 + SZ_FD;        // region reused for h later
constexpr size_t OFF_Q   = OFF_XB + SZ_MD16;       // q/k/v contiguous (fused epilogue)
constexpr size_t OFF_K   = OFF_Q + SZ_MD16;
constexpr size_t OFF_V   = OFF_K + SZ_MD16;        // V in [b,h,s,hd] (attn transposes)
constexpr size_t OFF_H   = OFF_XB;                 // 64 MB: xb+q+k+v dead by FFN1
constexpr size_t OFF_CTX = OFF_V + SZ_MD16;
constexpr size_t OFF_Y1  = OFF_CTX + SZ_MD16;      // f32
constexpr size_t OFF_A1B = OFF_Y1 + SZ_MD32;       // bf16 attn_out
constexpr size_t OFF_Y2  = OFF_A1B + SZ_MD16;      // f32 (first 24KB doubles as bqkv early)
constexpr size_t WS_NEED = OFF_Y2 + SZ_MD32;       // 256 MB total
// FFN2 second split-K partial reuses dead wq..wo region (4 x 8MB = 32MB) at OFF_WQ.

DEV void gload16(const void* g, void* l) {
  __builtin_amdgcn_global_load_lds(
      (const __attribute__((address_space(1))) unsigned int*)g,
      (__attribute__((address_space(3))) unsigned int*)l, 16, 0, 0);
}

// ---------------- fp32 -> bf16 convert ----------------
__global__ void cvt_bf16(const float* __restrict__ in, __hip_bfloat16* __restrict__ out, int n4) {
  int stride = gridDim.x * blockDim.x;
  for (int i = blockIdx.x * blockDim.x + threadIdx.x; i < n4; i += stride) {
    float4 v = reinterpret_cast<const float4*>(in)[i];
    union { ushort4 u; __hip_bfloat16 h[4]; } o;
    o.h[0] = __float2bfloat16(v.x);
    o.h[1] = __float2bfloat16(v.y);
    o.h[2] = __float2bfloat16(v.z);
    o.h[3] = __float2bfloat16(v.w);
    reinterpret_cast<ushort4*>(out)[i] = o.u;
  }
}

// ---------------- 256x256 GEMM, max-lead staging, 1 barrier/tile (r8) ----------------
// C = A[MxK] * Bt[NxK]^T. BK=64, 8 waves 2x4 inside one 128x128 C-quadrant,
// quads q0(M0N0) q1(M0N1) q2(M1N1) q3(M1N0). ALL FOUR halves of tile t+1 are
// staged during tile t's first two phases; boundary vmcnt(0) is the only drain
// and serves as the full publish fence. ONE s_barrier per tile. Counted lgkm
// ladder overlaps kk=1 reads under kk=0 MFMA. K-loop unrolled x2 (literal parity).
// MODE 0: fused QKV scatter — all of q/k/v -> [b,h,s,hd] (uniform), outb = q base
// MODE 2: out bf16 = gelu(acc + bias) at [row*N+col], outb
// MODE 3: raw f32 partial (split-K): out0/out1 selected by split index
template <int MODE>
__global__ __launch_bounds__(512, 2)
void gemm256(const __hip_bfloat16* __restrict__ A,
             const __hip_bfloat16* __restrict__ Bt,
             const float* __restrict__ bias,
             float* __restrict__ out0, float* __restrict__ out1,
             void* __restrict__ outb,
             int M, int N, int K, int kLen) {
  __shared__ __align__(16) char lds[131072];   // A: [2][256][64]b16 @0, B: @65536
  const int tid = threadIdx.x;
  const int lane = tid & 63, w = tid >> 6;
  const int wm = w >> 2, wn = w & 3;           // 2x4 waves inside a 128x128 quadrant
  const int lg = lane >> 4, lr = lane & 15;
  const int gy = M >> 8, gx = N >> 8;
  const int nwg = gridDim.x, orig = blockIdx.x;
  const int l = (orig & 7) * (nwg >> 3) + (orig >> 3);   // XCD-chunked (nwg%8==0)
  const int tilesPer = gx * gy;
  const int spl = l / tilesPer;
  const int rem = l - spl * tilesPer;
  const int bx = rem / gy, by = rem - bx * gy;           // n-panel-major
  const int m0 = by * 256, n0 = bx * 256;
  const int k0 = spl * kLen;
  const int NT = kLen >> 6;                               // even for all our shapes

  // staging source pointers (half 0=A0,1=A1,2=B0,3=B1; i 0..1), tile-0 based
  const char* gs[8];
  #pragma unroll
  for (int h = 0; h < 4; ++h) {
    const __hip_bfloat16* src = (h < 2) ? A : Bt;
    const int r0 = ((h < 2) ? m0 : n0) + (h & 1) * 128;
    #pragma unroll
    for (int i = 0; i < 2; ++i) {
      int c = i * 512 + tid;
      int row = c >> 3, slot = c & 7;
      gs[h * 2 + i] =
          (const char*)(src + (size_t)(r0 + row) * K + k0 + (slot ^ (row & 7)) * 8);
    }
  }

#define STAGE(P, H, TOFF)                                                          \
  {                                                                                \
    char* dstb = lds + (((H) < 2) ? 0 : 65536) + (P) * 32768 + ((H) & 1) * 16384;  \
    gload16(gs[(H) * 2 + 0] + (TOFF) * 128, dstb + (0 * 512 + tid) * 16);          \
    gload16(gs[(H) * 2 + 1] + (TOFF) * 128, dstb + (1 * 512 + tid) * 16);          \
  }

  auto ldA = [&](int P, int qm, int mr, int kk) {
    int row = qm * 128 + wm * 64 + mr * 16 + lr;
    return *reinterpret_cast<const short8*>(
        lds + P * 32768 + row * 128 + (((kk * 4 + lg) ^ (row & 7)) * 16));
  };
  auto ldB = [&](int P, int qn, int nr, int kk) {
    int row = qn * 128 + wn * 32 + nr * 16 + lr;
    return *reinterpret_cast<const short8*>(
        lds + 65536 + P * 32768 + row * 128 + (((kk * 4 + lg) ^ (row & 7)) * 16));
  };

  f32x4 acc[4][4][2] = {};   // [quad][mi][ni]

#define MFMA_HALF(q, kk, B)                                                     \
  _Pragma("unroll")                                                             \
  for (int mi = 0; mi < 4; ++mi)                                                \
    _Pragma("unroll")                                                           \
    for (int ni = 0; ni < 2; ++ni)                                              \
      acc[q][mi][ni] = __builtin_amdgcn_mfma_f32_16x16x32_bf16(                 \
          av[kk][mi], B[kk][ni], acc[q][mi][ni], 0, 0, 0);

#define WAIT_LGKM(n)                                                            \
  asm volatile("s_waitcnt lgkmcnt(" #n ")" ::: "memory");                       \
  __builtin_amdgcn_sched_barrier(0);

// One K-tile; P = literal buffer parity, PF = prefetch next tile (TOFF = 1+P).
#define TILE_BODY(P, PF)                                                        \
  {                                                                             \
    /* BOUNDARY: tile t fully staged >=2.5 phases ago; drain + publish. */      \
    asm volatile("s_waitcnt vmcnt(0)" ::: "memory");                            \
    __builtin_amdgcn_s_barrier();                                               \
    /* P0: q0 — reads A0,B0 (12 ds); stage A0,B0(next) */                       \
    _Pragma("unroll")                                                           \
    for (int i = 0; i < 4; ++i) av[0][i] = ldA(P, 0, i, 0);                     \
    _Pragma("unroll")                                                           \
    for (int i = 0; i < 2; ++i) b0[0][i] = ldB(P, 0, i, 0);                     \
    _Pragma("unroll")                                                           \
    for (int i = 0; i < 4; ++i) av[1][i] = ldA(P, 0, i, 1);                     \
    _Pragma("unroll")                                                           \
    for (int i = 0; i < 2; ++i) b0[1][i] = ldB(P, 0, i, 1);                     \
    if (PF) { STAGE((P) ^ 1, 0, 1 + (P)) STAGE((P) ^ 1, 2, 1 + (P)) }           \
    WAIT_LGKM(6)                                                                \
    __builtin_amdgcn_s_setprio(1);                                              \
    MFMA_HALF(0, 0, b0)                                                         \
    WAIT_LGKM(0)                                                                \
    MFMA_HALF(0, 1, b0)                                                         \
    __builtin_amdgcn_s_setprio(0);                                              \
    /* P1: q1 — reads B1 (4); stage B1,A1(next); reuse av */                    \
    _Pragma("unroll")                                                           \
    for (int i = 0; i < 2; ++i) b1[0][i] = ldB(P, 1, i, 0);                     \
    _Pragma("unroll")                                                           \
    for (int i = 0; i < 2; ++i) b1[1][i] = ldB(P, 1, i, 1);                     \
    if (PF) { STAGE((P) ^ 1, 3, 1 + (P)) STAGE((P) ^ 1, 1, 1 + (P)) }           \
    WAIT_LGKM(2)                                                                \
    __builtin_amdgcn_s_setprio(1);                                              \
    MFMA_HALF(1, 0, b1)                                                         \
    WAIT_LGKM(0)                                                                \
    MFMA_HALF(1, 1, b1)                                                         \
    __builtin_amdgcn_s_setprio(0);                                              \
    /* P2: q2 — reads A1 (8); reuse b1 */                                       \
    _Pragma("unroll")                                                           \
    for (int i = 0; i < 4; ++i) av[0][i] = ldA(P, 1, i, 0);                     \
    _Pragma("unroll")                                                           \
    for (int i = 0; i < 4; ++i) av[1][i] = ldA(P, 1, i, 1);                     \
    WAIT_LGKM(4)                                                                \
    __builtin_amdgcn_s_setprio(1);                                              \
    MFMA_HALF(2, 0, b1)                                                         \
    WAIT_LGKM(0)                                                                \
    MFMA_HALF(2, 1, b1)                                                         \
    __builtin_amdgcn_s_setprio(0);                                              \
    /* P3: q3 — re-reads B0 (4); reuse av */                                    \
    _Pragma("unroll")                                                           \
    for (int i = 0; i < 2; ++i) b0[0][i] = ldB(P, 0, i, 0);                     \
    _Pragma("unroll")                                                           \
    for (int i = 0; i < 2; ++i) b0[1][i] = ldB(P, 0, i, 1);                     \
    WAIT_LGKM(2)                                                                \
    __builtin_amdgcn_s_setprio(1);                                              \
    MFMA_HALF(3, 0, b0)                                                         \
    WAIT_LGKM(0)                                                                \
    MFMA_HALF(3, 1, b0)                                                         \
    __builtin_amdgcn_s_setprio(0);                                              \
  }

  // prologue: stage tile 0's four halves; first boundary vmcnt(0) drains them
  STAGE(0, 0, 0) STAGE(0, 2, 0) STAGE(0, 3, 0) STAGE(0, 1, 0)

  for (int t2 = 0; t2 < NT; t2 += 2) {
    short8 av[2][4], b0[2][2], b1[2][2];
    TILE_BODY(0, true)
    TILE_BODY(1, (t2 + 2 < NT))
    #pragma unroll
    for (int j = 0; j < 8; ++j) gs[j] += 256;
  }
#undef TILE_BODY
#undef MFMA_HALF
#undef WAIT_LGKM
#undef STAGE

  // epilogue: q0=(0,0) q1=(0,1) q2=(1,1) q3=(1,0)
  #pragma unroll
  for (int q = 0; q < 4; ++q) {
    const int qm = (q >= 2) ? 1 : 0;
    const int qn = (q == 1 || q == 2) ? 1 : 0;
    #pragma unroll
    for (int ni = 0; ni < 2; ++ni) {
      int col = n0 + qn * 128 + wn * 32 + ni * 16 + lr;
      float bvv = 0.f;
      if constexpr (MODE != 3) bvv = bias[col];
      #pragma unroll
      for (int mi = 0; mi < 4; ++mi) {
        int row0 = m0 + qm * 128 + wm * 64 + mi * 16 + lg * 4;
        #pragma unroll
        for (int r = 0; r < 4; ++r) {
          int row = row0 + r;
          float val = acc[q][mi][ni][r] + bvv;
          if constexpr (MODE == 0) {
            int which = col >> 11;                  // 0=q 1=k 2=v (uniform layout now)
            int d = col & 2047;
            int hh = d >> 7, hd = d & 127;
            int bb = row >> 10, ss = row & 1023;
            __hip_bfloat16* base = (__hip_bfloat16*)outb + (size_t)which * ((size_t)kM * kD);
            base[(((size_t)(bb * kH + hh)) * kS + ss) * kHD + hd] = __float2bfloat16(val);
          } else if constexpr (MODE == 2) {
            float g = 0.5f * val * (1.0f + erff(val * 0.70710678118654752f));
            ((__hip_bfloat16*)outb)[(size_t)row * N + col] = __float2bfloat16(g);
          } else {
            float* o = spl ? out1 : out0;
            o[(size_t)row * N + col] = val;
          }
        }
      }
    }
  }
}

// ---------------- flash attention — V now [b,h,s,hd]; in-kernel transpose ----------------
// K staged via global_load_lds (swizzled source); V reg-staged: each thread
// loads 4x8B (coalesced), transposes in regs, writes 4x ds_write_b64 into the
// swizzled Vt[hd][s] tile the PV loop reads. Write swizzle matches read:
// slot = (s/8)^(hd&7), half-slot = s4&1.
__global__ __launch_bounds__(512, 4)
void attn_fwd(const __hip_bfloat16* __restrict__ q,
              const __hip_bfloat16* __restrict__ k,
              const __hip_bfloat16* __restrict__ v,
              const float* __restrict__ mask,
              __hip_bfloat16* __restrict__ ctx) {
  __shared__ __align__(16) char Ks[2][64 * 256];    // [buf][key][dim] slot16^(row&15)
  __shared__ __align__(16) char Vt[2][128 * 128];   // [buf][hd][key64] slot8^(hd&7)
  __shared__ __align__(16) char Ps[8][2048];        // per-wave P [16][64], ^((row&7)<<4)
  const int tid = threadIdx.x, lane = tid & 63, w = tid >> 6;
  const int lg = lane >> 4, lr = lane & 15;
  const int orig = blockIdx.x;                      // 512 blocks
  const int l = (orig & 7) * 64 + (orig >> 3);      // XCD-chunked: 8 bh per XCD
  const int qt = l & 7, bh = l >> 3;
  const int b = bh >> 4;
  const int s4 = tid >> 5, hd4 = tid & 31;          // V-transpose role

  short8 qf[4];
  {
    const __hip_bfloat16* qp =
        q + ((size_t)bh * kS + qt * 128 + w * 16 + lr) * kHD + lg * 8;
    #pragma unroll
    for (int kk = 0; kk < 4; ++kk) qf[kk] = *reinterpret_cast<const short8*>(qp + kk * 32);
  }

  auto stageK = [&](int bufi, int t) {
    #pragma unroll
    for (int i = 0; i < 2; ++i) {                   // K tile: 64 rows x 256B
      int c = i * 512 + tid;
      int row = c >> 4, slot = c & 15;
      gload16(k + ((size_t)bh * kS + t * 64 + row) * kHD + (slot ^ (row & 15)) * 8,
              Ks[bufi] + c * 16);
    }
  };
  union VU { uint2 u; ushort s[4]; };
  VU vr[4];
  auto loadV = [&](int t) {                         // 4 x 8B coalesced per thread
    #pragma unroll
    for (int i = 0; i < 4; ++i)
      vr[i].u = *reinterpret_cast<const uint2*>(
          v + ((size_t)bh * kS + t * 64 + s4 * 4 + i) * kHD + hd4 * 4);
  };
  auto writeV = [&](int bufi) {                     // transpose -> 4 x ds_write_b64
    #pragma unroll
    for (int j = 0; j < 4; ++j) {
      int hd = hd4 * 4 + j;
      ushort4 o;
      o.x = vr[0].s[j]; o.y = vr[1].s[j]; o.z = vr[2].s[j]; o.w = vr[3].s[j];
      *reinterpret_cast<ushort4*>(
          Vt[bufi] + hd * 128 + (((s4 >> 1) ^ (hd & 7)) << 4) + ((s4 & 1) << 3)) = o;
    }
  };

  f32x4 o[8] = {};
  float mrun[4], lrun[4];
  #pragma unroll
  for (int r = 0; r < 4; ++r) { mrun[r] = -1e30f; lrun[r] = 0.f; }
  const float scale = 0.08838834764831845f;         // 1/sqrt(128)

  stageK(0, 0);
  loadV(0);
  writeV(0);            // compiler auto-waits vr loads
  __syncthreads();      // drains vmcnt (K) + lgkm (V writes), publishes buf 0

  int buf = 0;
  for (int t = 0; t < 16; ++t) {
    if (t + 1 < 16) { stageK(buf ^ 1, t + 1); loadV(t + 1); }

    f32x4 sacc[4] = {};
    #pragma unroll
    for (int j = 0; j < 4; ++j) {
      int key = j * 16 + lr;
      #pragma unroll
      for (int kk = 0; kk < 4; ++kk) {
        short8 bfrag = *reinterpret_cast<const short8*>(
            Ks[buf] + key * 256 + (((kk * 4 + lg) ^ (key & 15)) * 16));
        sacc[j] = __builtin_amdgcn_mfma_f32_16x16x32_bf16(qf[kk], bfrag, sacc[j], 0, 0, 0);
      }
    }
    float sarr[4][4];
    #pragma unroll
    for (int j = 0; j < 4; ++j) {
      float mv = mask[(size_t)b * kS + t * 64 + j * 16 + lr];
      #pragma unroll
      for (int r = 0; r < 4; ++r) sarr[j][r] = sacc[j][r] * scale + mv;
    }
    #pragma unroll
    for (int r = 0; r < 4; ++r) {
      float tm = fmaxf(fmaxf(sarr[0][r], sarr[1][r]), fmaxf(sarr[2][r], sarr[3][r]));
      #pragma unroll
      for (int d = 1; d < 16; d <<= 1) tm = fmaxf(tm, __shfl_xor(tm, d));
      float mnew = fmaxf(mrun[r], tm);
      float alpha = __expf(mrun[r] - mnew);
      mrun[r] = mnew;
      float rs = 0.f;
      #pragma unroll
      for (int j = 0; j < 4; ++j) {
        float p = __expf(sarr[j][r] - mnew);
        sarr[j][r] = p;
        rs += p;
      }
      #pragma unroll
      for (int d = 1; d < 16; d <<= 1) rs += __shfl_xor(rs, d);
      lrun[r] = lrun[r] * alpha + rs;
      #pragma unroll
      for (int n = 0; n < 8; ++n) o[n][r] *= alpha;
    }
    #pragma unroll
    for (int r = 0; r < 4; ++r) {
      int qr = lg * 4 + r;
      #pragma unroll
      for (int j = 0; j < 4; ++j)
        *reinterpret_cast<__hip_bfloat16*>(
            Ps[w] + ((qr * 128 + (j * 16 + lr) * 2) ^ ((qr & 7) << 4))) =
            __float2bfloat16(sarr[j][r]);
    }
    #pragma unroll
    for (int kk2 = 0; kk2 < 2; ++kk2) {
      short8 pa = *reinterpret_cast<const short8*>(
          Ps[w] + ((lr * 128 + kk2 * 64 + lg * 16) ^ ((lr & 7) << 4)));
      #pragma unroll
      for (int n = 0; n < 8; ++n) {
        int hd = n * 16 + lr;
        short8 vb = *reinterpret_cast<const short8*>(
            Vt[buf] + hd * 128 + (((kk2 * 4 + lg) ^ (hd & 7)) * 16));
        o[n] = __builtin_amdgcn_mfma_f32_16x16x32_bf16(pa, vb, o[n], 0, 0, 0);
      }
    }
    if (t + 1 < 16) writeV(buf ^ 1);   // transpose-write next V tile (auto-waits vr)
    __syncthreads();                   // drains vmcnt+lgkm, publishes buf^1
    buf ^= 1;
  }

  const int h = bh & 15;
  #pragma unroll
  for (int r = 0; r < 4; ++r) {
    float inv = 1.0f / lrun[r];
    int srow = qt * 128 + w * 16 + lg * 4 + r;
    __hip_bfloat16* cp = ctx + ((size_t)b * kS + srow) * kD + h * 128 + lr;
    #pragma unroll
    for (int n = 0; n < 8; ++n) cp[n * 16] = __float2bfloat16(o[n][r] * inv);
  }
}

// ------- LayerNorm over (p0 + p1 + bias + res), one 2048-row per block -------
template <bool WB16>
__global__ void ln_fuse(const float* __restrict__ p0, const float* __restrict__ p1,
                        const float* __restrict__ bias, const float* __restrict__ res,
                        const float* __restrict__ w, const float* __restrict__ b,
                        float* __restrict__ outf, __hip_bfloat16* __restrict__ outb) {
  const int row = blockIdx.x, tid = threadIdx.x;
  const size_t base = (size_t)row * kD;
  float v[8];
  #pragma unroll
  for (int i = 0; i < 2; ++i) {
    int c4 = tid * 2 + i;
    float4 a  = reinterpret_cast<const float4*>(p0 + base)[c4];
    float4 bb = reinterpret_cast<const float4*>(p1 + base)[c4];
    float4 rr = reinterpret_cast<const float4*>(res + base)[c4];
    float4 bs = reinterpret_cast<const float4*>(bias)[c4];
    v[i * 4 + 0] = a.x + bb.x + rr.x + bs.x;
    v[i * 4 + 1] = a.y + bb.y + rr.y + bs.y;
    v[i * 4 + 2] = a.z + bb.z + rr.z + bs.z;
    v[i * 4 + 3] = a.w + bb.w + rr.w + bs.w;
  }
  float s = 0.f;
  #pragma unroll
  for (int i = 0; i < 8; ++i) s += v[i];
  #pragma unroll
  for (int off = 32; off > 0; off >>= 1) s += __shfl_down(s, off);
  __shared__ float r1[4], r2[4];
  if ((tid & 63) == 0) r1[tid >> 6] = s;
  __syncthreads();
  float mean = (r1[0] + r1[1] + r1[2] + r1[3]) * (1.0f / kD);
  float qv = 0.f;
  #pragma unroll
  for (int i = 0; i < 8; ++i) { float d = v[i] - mean; qv += d * d; }
  #pragma unroll
  for (int off = 32; off > 0; off >>= 1) qv += __shfl_down(qv, off);
  if ((tid & 63) == 0) r2[tid >> 6] = qv;
  __syncthreads();
  float rstd = rsqrtf((r2[0] + r2[1] + r2[2] + r2[3]) * (1.0f / kD) + kEPS);
  #pragma unroll
  for (int i = 0; i < 8; ++i) {
    int col = tid * 8 + i;
    float ov = (v[i] - mean) * rstd * w[col] + b[col];
    outf[base + col] = ov;
    if constexpr (WB16) outb[base + col] = __float2bfloat16(ov);
  }
}

// ---------------- launcher ----------------
extern "C" void kernel_launch(void* const* d_in, const int* in_sizes, int n_in,
                              void* d_out, int out_size, void* d_ws, size_t ws_size,
                              hipStream_t stream) {
  (void)in_sizes; (void)n_in; (void)out_size;
  if (ws_size < WS_NEED) return;
  const float* x    = (const float*)d_in[0];
  const float* mask = (const float*)d_in[1];
  const float* wq   = (const float*)d_in[2];
  const float* bq   = (const float*)d_in[3];
  const float* wk   = (const float*)d_in[4];
  const float* bk   = (const float*)d_in[5];
  const float* wv   = (const float*)d_in[6];
  const float* bv   = (const float*)d_in[7];
  const float* wo   = (const float*)d_in[8];
  const float* bo   = (const float*)d_in[9];
  const float* l1w  = (const float*)d_in[10];
  const float* l1b  = (const float*)d_in[11];
  const float* wi   = (const float*)d_in[12];
  const float* bi   = (const float*)d_in[13];
  const float* wo2  = (const float*)d_in[14];
  const float* bo2  = (const float*)d_in[15];
  const float* l2w  = (const float*)d_in[16];
  const float* l2b  = (const float*)d_in[17];

  char* ws = (char*)d_ws;
  __hip_bfloat16* wqb  = (__hip_bfloat16*)(ws + OFF_WQ);   // fused QKV weight base
  __hip_bfloat16* wkb  = (__hip_bfloat16*)(ws + OFF_WK);
  __hip_bfloat16* wvb  = (__hip_bfloat16*)(ws + OFF_WV);
  __hip_bfloat16* wob  = (__hip_bfloat16*)(ws + OFF_WO);
  __hip_bfloat16* wib  = (__hip_bfloat16*)(ws + OFF_WI);
  __hip_bfloat16* wo2b = (__hip_bfloat16*)(ws + OFF_WO2);
  __hip_bfloat16* xb   = (__hip_bfloat16*)(ws + OFF_XB);
  __hip_bfloat16* qb   = (__hip_bfloat16*)(ws + OFF_Q);    // q/k/v contiguous
  __hip_bfloat16* kb2  = (__hip_bfloat16*)(ws + OFF_K);
  __hip_bfloat16* vb2  = (__hip_bfloat16*)(ws + OFF_V);    // [b,h,s,hd]
  __hip_bfloat16* hb   = (__hip_bfloat16*)(ws + OFF_H);
  __hip_bfloat16* ctxb = (__hip_bfloat16*)(ws + OFF_CTX);
  __hip_bfloat16* a1b  = (__hip_bfloat16*)(ws + OFF_A1B);
  float* y1   = (float*)(ws + OFF_Y1);
  float* y2   = (float*)(ws + OFF_Y2);
  float* f2p  = (float*)(ws + OFF_WQ);   // FFN2 split-K partial 1 (32MB, weights dead)
  float* bqkv = (float*)(ws + OFF_Y2);   // 24KB concat bias; dead before Wo writes y2

  // fp32 -> bf16 conversions
  cvt_bf16<<<2048, 256, 0, stream>>>(x,   xb,   kM * kD / 4);
  cvt_bf16<<<1024, 256, 0, stream>>>(wq,  wqb,  kD * kD / 4);
  cvt_bf16<<<1024, 256, 0, stream>>>(wk,  wkb,  kD * kD / 4);
  cvt_bf16<<<1024, 256, 0, stream>>>(wv,  wvb,  kD * kD / 4);
  cvt_bf16<<<1024, 256, 0, stream>>>(wo,  wob,  kD * kD / 4);
  cvt_bf16<<<2048, 256, 0, stream>>>(wi,  wib,  kF * kD / 4);
  cvt_bf16<<<2048, 256, 0, stream>>>(wo2, wo2b, kF * kD / 4);
  // concat QKV bias into scratch
  hipMemcpyAsync(bqkv,          bq, kD * 4, hipMemcpyDeviceToDevice, stream);
  hipMemcpyAsync(bqkv + kD,     bk, kD * 4, hipMemcpyDeviceToDevice, stream);
  hipMemcpyAsync(bqkv + 2 * kD, bv, kD * 4, hipMemcpyDeviceToDevice, stream);

  dim3 blk(512);
  // fused QKV projection: M=4096, N=6144, K=2048 -> grid 24*16 = 384
  gemm256<0><<<dim3(384), blk, 0, stream>>>(
      xb, wqb, bqkv, nullptr, nullptr, qb, kM, 6144, kD, kD);
  // attention
  attn_fwd<<<dim3(512), dim3(512), 0, stream>>>(qb, kb2, vb2, mask, ctxb);
  // out proj, split-K x2 (grid 2*8*16 = 256), partials y1,y2; LN1 fuses +bo+x
  gemm256<3><<<dim3(256), blk, 0, stream>>>(
      ctxb, wob, nullptr, y1, y2, nullptr, kM, kD, kD, kD / 2);
  ln_fuse<true><<<kM, 256, 0, stream>>>(y1, y2, bo, x, l1w, l1b, y1, a1b);
  // FFN1: M=4096, N=8192, K=2048 -> grid 32*16 = 512, GELU epilogue
  gemm256<2><<<dim3(512), blk, 0, stream>>>(
      a1b, wib, bi, nullptr, nullptr, hb, kM, kF, kD, kD);
  // FFN2: split-K x2 (grid 256), partials y2,f2p; LN2 fuses +bo2+attn_out(y1)
  gemm256<3><<<dim3(256), blk, 0, stream>>>(
      hb, wo2b, nullptr, y2, f2p, nullptr, kM, kD, kF, kF / 2);
  ln_fuse<false><<<kM, 256, 0, stream>>>(y2, f2p, bo2, y1, l2w, l2b, (float*)d_out, nullptr);
}

// Round 11
// 672.528 us; speedup vs baseline: 1.5402x; 1.0020x over previous
//
#include <hip/hip_runtime.h>
#include <hip/hip_bf16.h>
#include <cstdint>
#include <cstddef>

typedef __attribute__((ext_vector_type(8))) short short8;   // 8 x bf16 (4 VGPRs)
typedef __attribute__((ext_vector_type(4))) float f32x4;    // MFMA accumulator

#define DEV static __device__ __forceinline__

constexpr int kS = 1024, kD = 2048, kH = 16, kHD = 128, kF = 8192;
constexpr int kM = 4096;            // B*S rows
constexpr float kEPS = 1e-5f;

// ---------------- workspace layout (bytes) ----------------
constexpr size_t SZ_DD   = (size_t)kD * kD * 2;    // 8 MB   bf16 DxD weight
constexpr size_t SZ_FD   = (size_t)kF * kD * 2;    // 32 MB  bf16 FxD weight
constexpr size_t SZ_MD16 = (size_t)kM * kD * 2;    // 16 MB  bf16 activation
constexpr size_t SZ_MD32 = (size_t)kM * kD * 4;    // 32 MB  f32 activation
constexpr size_t OFF_WQ  = 0;                      // wq/wk/wv contiguous => fused QKV weight
constexpr size_t OFF_WK  = OFF_WQ + SZ_DD;
constexpr size_t OFF_WV  = OFF_WK + SZ_DD;
constexpr size_t OFF_WO  = OFF_WV + SZ_DD;
constexpr size_t OFF_WI  = OFF_WO + SZ_DD;
constexpr size_t OFF_WO2 = OFF_WI + SZ_FD;
constexpr size_t OFF_XB  = OFF_WO2 + SZ_FD;        // region reused for h later
constexpr size_t OFF_Q   = OFF_XB + SZ_MD16;       // q/k/v contiguous (fused epilogue)
constexpr size_t OFF_K   = OFF_Q + SZ_MD16;
constexpr size_t OFF_V   = OFF_K + SZ_MD16;        // V in [b,h,s,hd] (attn transposes)
constexpr size_t OFF_H   = OFF_XB;                 // 64 MB: xb+q+k+v dead by FFN1
constexpr size_t OFF_CTX = OFF_V + SZ_MD16;
constexpr size_t OFF_Y1  = OFF_CTX + SZ_MD16;      // f32
constexpr size_t OFF_A1B = OFF_Y1 + SZ_MD32;       // bf16 attn_out
constexpr size_t OFF_Y2  = OFF_A1B + SZ_MD16;      // f32 (first 24KB doubles as bqkv early)
constexpr size_t WS_NEED = OFF_Y2 + SZ_MD32;       // 256 MB total
// FFN2 second split-K partial reuses dead wq..wo region (4 x 8MB = 32MB) at OFF_WQ.

DEV void gload16(const void* g, void* l) {
  __builtin_amdgcn_global_load_lds(
      (const __attribute__((address_space(1))) unsigned int*)g,
      (__attribute__((address_space(3))) unsigned int*)l, 16, 0, 0);
}

// ---------------- fp32 -> bf16 convert ----------------
__global__ void cvt_bf16(const float* __restrict__ in, __hip_bfloat16* __restrict__ out, int n4) {
  int stride = gridDim.x * blockDim.x;
  for (int i = blockIdx.x * blockDim.x + threadIdx.x; i < n4; i += stride) {
    float4 v = reinterpret_cast<const float4*>(in)[i];
    union { ushort4 u; __hip_bfloat16 h[4]; } o;
    o.h[0] = __float2bfloat16(v.x);
    o.h[1] = __float2bfloat16(v.y);
    o.h[2] = __float2bfloat16(v.z);
    o.h[3] = __float2bfloat16(v.w);
    reinterpret_cast<ushort4*>(out)[i] = o.u;
  }
}

// ---------------- 256x256 GEMM, wave-group phase shift (anti-convoy) ----------------
// C = A[MxK] * Bt[NxK]^T. BK=64, 8 waves 2x4 inside one 128x128 C-quadrant.
// r8 staging: ALL FOUR halves of tile t+1 staged during tile t's first two
// phases; single boundary vmcnt(0)+s_barrier per tile publishes everything.
// NEW: waves 0-3 walk quads q0,q1,q2,q3; waves 4-7 (the second wave on each
// SIMD) walk q2,q3,q0,q1 (hw = w>>2 selects the half-tile roles). At any
// moment each SIMD has one wave in its read-phase and one in its MFMA-phase,
// breaking the block-wide read-convoy/MFMA-convoy alternation that serialized
// the LDS and matrix pipes. Legal since the whole tile is staged at boundary.
// MODE 0: fused QKV scatter — all of q/k/v -> [b,h,s,hd] (uniform), outb = q base
// MODE 2: out bf16 = gelu(acc + bias) at [row*N+col], outb
// MODE 3: raw f32 partial (split-K): out0/out1 selected by split index
template <int MODE>
__global__ __launch_bounds__(512, 2)
void gemm256(const __hip_bfloat16* __restrict__ A,
             const __hip_bfloat16* __restrict__ Bt,
             const float* __restrict__ bias,
             float* __restrict__ out0, float* __restrict__ out1,
             void* __restrict__ outb,
             int M, int N, int K, int kLen) {
  __shared__ __align__(16) char lds[131072];   // A: [2][256][64]b16 @0, B: @65536
  const int tid = threadIdx.x;
  const int lane = tid & 63, w = tid >> 6;
  const int wm = w >> 2, wn = w & 3;           // 2x4 waves inside a 128x128 quadrant
  const int hw = w >> 2;                       // phase-shift group: 0 (waves 0-3) / 1 (4-7)
  const int lg = lane >> 4, lr = lane & 15;
  const int gy = M >> 8, gx = N >> 8;
  const int nwg = gridDim.x, orig = blockIdx.x;
  const int l = (orig & 7) * (nwg >> 3) + (orig >> 3);   // XCD-chunked (nwg%8==0)
  const int tilesPer = gx * gy;
  const int spl = l / tilesPer;
  const int rem = l - spl * tilesPer;
  const int bx = rem / gy, by = rem - bx * gy;           // n-panel-major
  const int m0 = by * 256, n0 = bx * 256;
  const int k0 = spl * kLen;
  const int NT = kLen >> 6;                               // even for all our shapes

  // staging source pointers (half 0=A0,1=A1,2=B0,3=B1; i 0..1), tile-0 based
  const char* gs[8];
  #pragma unroll
  for (int h = 0; h < 4; ++h) {
    const __hip_bfloat16* src = (h < 2) ? A : Bt;
    const int r0 = ((h < 2) ? m0 : n0) + (h & 1) * 128;
    #pragma unroll
    for (int i = 0; i < 2; ++i) {
      int c = i * 512 + tid;
      int row = c >> 3, slot = c & 7;
      gs[h * 2 + i] =
          (const char*)(src + (size_t)(r0 + row) * K + k0 + (slot ^ (row & 7)) * 8);
    }
  }

#define STAGE(P, H, TOFF)                                                          \
  {                                                                                \
    char* dstb = lds + (((H) < 2) ? 0 : 65536) + (P) * 32768 + ((H) & 1) * 16384;  \
    gload16(gs[(H) * 2 + 0] + (TOFF) * 128, dstb + (0 * 512 + tid) * 16);          \
    gload16(gs[(H) * 2 + 1] + (TOFF) * 128, dstb + (1 * 512 + tid) * 16);          \
  }

  auto ldA = [&](int P, int qm, int mr, int kk) {
    int row = qm * 128 + wm * 64 + mr * 16 + lr;
    return *reinterpret_cast<const short8*>(
        lds + P * 32768 + row * 128 + (((kk * 4 + lg) ^ (row & 7)) * 16));
  };
  auto ldB = [&](int P, int qn, int nr, int kk) {
    int row = qn * 128 + wn * 32 + nr * 16 + lr;
    return *reinterpret_cast<const short8*>(
        lds + 65536 + P * 32768 + row * 128 + (((kk * 4 + lg) ^ (row & 7)) * 16));
  };

  f32x4 acc[4][4][2] = {};   // [phase][mi][ni]; phase->quad mapping depends on hw

#define MFMA_HALF(p, kk, B)                                                     \
  _Pragma("unroll")                                                             \
  for (int mi = 0; mi < 4; ++mi)                                                \
    _Pragma("unroll")                                                           \
    for (int ni = 0; ni < 2; ++ni)                                              \
      acc[p][mi][ni] = __builtin_amdgcn_mfma_f32_16x16x32_bf16(                 \
          av[kk][mi], B[kk][ni], acc[p][mi][ni], 0, 0, 0);

#define WAIT_LGKM(n)                                                            \
  asm volatile("s_waitcnt lgkmcnt(" #n ")" ::: "memory");                       \
  __builtin_amdgcn_sched_barrier(0);

// One K-tile; P = literal buffer parity, PF = prefetch next tile (TOFF = 1+P).
// Wave-group hw reads: p0 A(hw)+B(hw); p1 B(1-hw); p2 A(1-hw); p3 B(hw) again.
#define TILE_BODY(P, PF)                                                        \
  {                                                                             \
    /* BOUNDARY: tile t fully staged >=2.5 phases ago; drain + publish. */      \
    asm volatile("s_waitcnt vmcnt(0)" ::: "memory");                            \
    __builtin_amdgcn_s_barrier();                                               \
    /* P0: reads A(hw),B(hw) (12 ds); stage A0,B0(next) */                      \
    _Pragma("unroll")                                                           \
    for (int i = 0; i < 4; ++i) av[0][i] = ldA(P, hw, i, 0);                    \
    _Pragma("unroll")                                                           \
    for (int i = 0; i < 2; ++i) b0[0][i] = ldB(P, hw, i, 0);                    \
    _Pragma("unroll")                                                           \
    for (int i = 0; i < 4; ++i) av[1][i] = ldA(P, hw, i, 1);                    \
    _Pragma("unroll")                                                           \
    for (int i = 0; i < 2; ++i) b0[1][i] = ldB(P, hw, i, 1);                    \
    if (PF) { STAGE((P) ^ 1, 0, 1 + (P)) STAGE((P) ^ 1, 2, 1 + (P)) }           \
    WAIT_LGKM(6)                                                                \
    __builtin_amdgcn_s_setprio(1);                                              \
    MFMA_HALF(0, 0, b0)                                                         \
    WAIT_LGKM(0)                                                                \
    MFMA_HALF(0, 1, b0)                                                         \
    __builtin_amdgcn_s_setprio(0);                                              \
    /* P1: reads B(1-hw) (4); stage B1,A1(next); reuse av */                    \
    _Pragma("unroll")                                                           \
    for (int i = 0; i < 2; ++i) b1[0][i] = ldB(P, 1 - hw, i, 0);                \
    _Pragma("unroll")                                                           \
    for (int i = 0; i < 2; ++i) b1[1][i] = ldB(P, 1 - hw, i, 1);                \
    if (PF) { STAGE((P) ^ 1, 3, 1 + (P)) STAGE((P) ^ 1, 1, 1 + (P)) }           \
    WAIT_LGKM(2)                                                                \
    __builtin_amdgcn_s_setprio(1);                                              \
    MFMA_HALF(1, 0, b1)                                                         \
    WAIT_LGKM(0)                                                                \
    MFMA_HALF(1, 1, b1)                                                         \
    __builtin_amdgcn_s_setprio(0);                                              \
    /* P2: reads A(1-hw) (8); reuse b1 */                                       \
    _Pragma("unroll")                                                           \
    for (int i = 0; i < 4; ++i) av[0][i] = ldA(P, 1 - hw, i, 0);                \
    _Pragma("unroll")                                                           \
    for (int i = 0; i < 4; ++i) av[1][i] = ldA(P, 1 - hw, i, 1);                \
    WAIT_LGKM(4)                                                                \
    __builtin_amdgcn_s_setprio(1);                                              \
    MFMA_HALF(2, 0, b1)                                                         \
    WAIT_LGKM(0)                                                                \
    MFMA_HALF(2, 1, b1)                                                         \
    __builtin_amdgcn_s_setprio(0);                                              \
    /* P3: re-reads B(hw) (4); reuse av */                                      \
    _Pragma("unroll")                                                           \
    for (int i = 0; i < 2; ++i) b0[0][i] = ldB(P, hw, i, 0);                    \
    _Pragma("unroll")                                                           \
    for (int i = 0; i < 2; ++i) b0[1][i] = ldB(P, hw, i, 1);                    \
    WAIT_LGKM(2)                                                                \
    __builtin_amdgcn_s_setprio(1);                                              \
    MFMA_HALF(3, 0, b0)                                                         \
    WAIT_LGKM(0)                                                                \
    MFMA_HALF(3, 1, b0)                                                         \
    __builtin_amdgcn_s_setprio(0);                                              \
  }

  // prologue: stage tile 0's four halves; first boundary vmcnt(0) drains them
  STAGE(0, 0, 0) STAGE(0, 2, 0) STAGE(0, 3, 0) STAGE(0, 1, 0)

  for (int t2 = 0; t2 < NT; t2 += 2) {
    short8 av[2][4], b0[2][2], b1[2][2];
    TILE_BODY(0, true)
    TILE_BODY(1, (t2 + 2 < NT))
    #pragma unroll
    for (int j = 0; j < 8; ++j) gs[j] += 256;
  }
#undef TILE_BODY
#undef MFMA_HALF
#undef WAIT_LGKM
#undef STAGE

  // epilogue: phase p of group hw computed quad (qm,qn):
  // p0:(hw,hw) p1:(hw,1-hw) p2:(1-hw,1-hw) p3:(1-hw,hw)
  #pragma unroll
  for (int p = 0; p < 4; ++p) {
    const int qm = (p < 2) ? hw : 1 - hw;
    const int qn = (p == 0 || p == 3) ? hw : 1 - hw;
    #pragma unroll
    for (int ni = 0; ni < 2; ++ni) {
      int col = n0 + qn * 128 + wn * 32 + ni * 16 + lr;
      float bvv = 0.f;
      if constexpr (MODE != 3) bvv = bias[col];
      #pragma unroll
      for (int mi = 0; mi < 4; ++mi) {
        int row0 = m0 + qm * 128 + wm * 64 + mi * 16 + lg * 4;
        #pragma unroll
        for (int r = 0; r < 4; ++r) {
          int row = row0 + r;
          float val = acc[p][mi][ni][r] + bvv;
          if constexpr (MODE == 0) {
            int which = col >> 11;                  // 0=q 1=k 2=v (uniform layout)
            int d = col & 2047;
            int hh = d >> 7, hd = d & 127;
            int bb = row >> 10, ss = row & 1023;
            __hip_bfloat16* base = (__hip_bfloat16*)outb + (size_t)which * ((size_t)kM * kD);
            base[(((size_t)(bb * kH + hh)) * kS + ss) * kHD + hd] = __float2bfloat16(val);
          } else if constexpr (MODE == 2) {
            float g = 0.5f * val * (1.0f + erff(val * 0.70710678118654752f));
            ((__hip_bfloat16*)outb)[(size_t)row * N + col] = __float2bfloat16(g);
          } else {
            float* o = spl ? out1 : out0;
            o[(size_t)row * N + col] = val;
          }
        }
      }
    }
  }
}

// ---------------- flash attention — V [b,h,s,hd]; in-kernel transpose ----------------
__global__ __launch_bounds__(512, 4)
void attn_fwd(const __hip_bfloat16* __restrict__ q,
              const __hip_bfloat16* __restrict__ k,
              const __hip_bfloat16* __restrict__ v,
              const float* __restrict__ mask,
              __hip_bfloat16* __restrict__ ctx) {
  __shared__ __align__(16) char Ks[2][64 * 256];    // [buf][key][dim] slot16^(row&15)
  __shared__ __align__(16) char Vt[2][128 * 128];   // [buf][hd][key64] slot8^(hd&7)
  __shared__ __align__(16) char Ps[8][2048];        // per-wave P [16][64], ^((row&7)<<4)
  const int tid = threadIdx.x, lane = tid & 63, w = tid >> 6;
  const int lg = lane >> 4, lr = lane & 15;
  const int orig = blockIdx.x;                      // 512 blocks
  const int l = (orig & 7) * 64 + (orig >> 3);      // XCD-chunked: 8 bh per XCD
  const int qt = l & 7, bh = l >> 3;
  const int b = bh >> 4;
  const int s4 = tid >> 5, hd4 = tid & 31;          // V-transpose role

  short8 qf[4];
  {
    const __hip_bfloat16* qp =
        q + ((size_t)bh * kS + qt * 128 + w * 16 + lr) * kHD + lg * 8;
    #pragma unroll
    for (int kk = 0; kk < 4; ++kk) qf[kk] = *reinterpret_cast<const short8*>(qp + kk * 32);
  }

  auto stageK = [&](int bufi, int t) {
    #pragma unroll
    for (int i = 0; i < 2; ++i) {                   // K tile: 64 rows x 256B
      int c = i * 512 + tid;
      int row = c >> 4, slot = c & 15;
      gload16(k + ((size_t)bh * kS + t * 64 + row) * kHD + (slot ^ (row & 15)) * 8,
              Ks[bufi] + c * 16);
    }
  };
  union VU { uint2 u; ushort s[4]; };
  VU vr[4];
  auto loadV = [&](int t) {                         // 4 x 8B coalesced per thread
    #pragma unroll
    for (int i = 0; i < 4; ++i)
      vr[i].u = *reinterpret_cast<const uint2*>(
          v + ((size_t)bh * kS + t * 64 + s4 * 4 + i) * kHD + hd4 * 4);
  };
  auto writeV = [&](int bufi) {                     // transpose -> 4 x ds_write_b64
    #pragma unroll
    for (int j = 0; j < 4; ++j) {
      int hd = hd4 * 4 + j;
      ushort4 o;
      o.x = vr[0].s[j]; o.y = vr[1].s[j]; o.z = vr[2].s[j]; o.w = vr[3].s[j];
      *reinterpret_cast<ushort4*>(
          Vt[bufi] + hd * 128 + (((s4 >> 1) ^ (hd & 7)) << 4) + ((s4 & 1) << 3)) = o;
    }
  };

  f32x4 o[8] = {};
  float mrun[4], lrun[4];
  #pragma unroll
  for (int r = 0; r < 4; ++r) { mrun[r] = -1e30f; lrun[r] = 0.f; }
  const float scale = 0.08838834764831845f;         // 1/sqrt(128)

  stageK(0, 0);
  loadV(0);
  writeV(0);
  __syncthreads();

  int buf = 0;
  for (int t = 0; t < 16; ++t) {
    if (t + 1 < 16) { stageK(buf ^ 1, t + 1); loadV(t + 1); }

    f32x4 sacc[4] = {};
    #pragma unroll
    for (int j = 0; j < 4; ++j) {
      int key = j * 16 + lr;
      #pragma unroll
      for (int kk = 0; kk < 4; ++kk) {
        short8 bfrag = *reinterpret_cast<const short8*>(
            Ks[buf] + key * 256 + (((kk * 4 + lg) ^ (key & 15)) * 16));
        sacc[j] = __builtin_amdgcn_mfma_f32_16x16x32_bf16(qf[kk], bfrag, sacc[j], 0, 0, 0);
      }
    }
    float sarr[4][4];
    #pragma unroll
    for (int j = 0; j < 4; ++j) {
      float mv = mask[(size_t)b * kS + t * 64 + j * 16 + lr];
      #pragma unroll
      for (int r = 0; r < 4; ++r) sarr[j][r] = sacc[j][r] * scale + mv;
    }
    #pragma unroll
    for (int r = 0; r < 4; ++r) {
      float tm = fmaxf(fmaxf(sarr[0][r], sarr[1][r]), fmaxf(sarr[2][r], sarr[3][r]));
      #pragma unroll
      for (int d = 1; d < 16; d <<= 1) tm = fmaxf(tm, __shfl_xor(tm, d));
      float mnew = fmaxf(mrun[r], tm);
      float alpha = __expf(mrun[r] - mnew);
      mrun[r] = mnew;
      float rs = 0.f;
      #pragma unroll
      for (int j = 0; j < 4; ++j) {
        float p = __expf(sarr[j][r] - mnew);
        sarr[j][r] = p;
        rs += p;
      }
      #pragma unroll
      for (int d = 1; d < 16; d <<= 1) rs += __shfl_xor(rs, d);
      lrun[r] = lrun[r] * alpha + rs;
      #pragma unroll
      for (int n = 0; n < 8; ++n) o[n][r] *= alpha;
    }
    #pragma unroll
    for (int r = 0; r < 4; ++r) {
      int qr = lg * 4 + r;
      #pragma unroll
      for (int j = 0; j < 4; ++j)
        *reinterpret_cast<__hip_bfloat16*>(
            Ps[w] + ((qr * 128 + (j * 16 + lr) * 2) ^ ((qr & 7) << 4))) =
            __float2bfloat16(sarr[j][r]);
    }
    #pragma unroll
    for (int kk2 = 0; kk2 < 2; ++kk2) {
      short8 pa = *reinterpret_cast<const short8*>(
          Ps[w] + ((lr * 128 + kk2 * 64 + lg * 16) ^ ((lr & 7) << 4)));
      #pragma unroll
      for (int n = 0; n < 8; ++n) {
        int hd = n * 16 + lr;
        short8 vb = *reinterpret_cast<const short8*>(
            Vt[buf] + hd * 128 + (((kk2 * 4 + lg) ^ (hd & 7)) * 16));
        o[n] = __builtin_amdgcn_mfma_f32_16x16x32_bf16(pa, vb, o[n], 0, 0, 0);
      }
    }
    if (t + 1 < 16) writeV(buf ^ 1);
    __syncthreads();
    buf ^= 1;
  }

  const int h = bh & 15;
  #pragma unroll
  for (int r = 0; r < 4; ++r) {
    float inv = 1.0f / lrun[r];
    int srow = qt * 128 + w * 16 + lg * 4 + r;
    __hip_bfloat16* cp = ctx + ((size_t)b * kS + srow) * kD + h * 128 + lr;
    #pragma unroll
    for (int n = 0; n < 8; ++n) cp[n * 16] = __float2bfloat16(o[n][r] * inv);
  }
}

// ------- LayerNorm over (p0 + p1 + bias + res), one 2048-row per block -------
template <bool WB16>
__global__ void ln_fuse(const float* __restrict__ p0, const float* __restrict__ p1,
                        const float* __restrict__ bias, const float* __restrict__ res,
                        const float* __restrict__ w, const float* __restrict__ b,
                        float* __restrict__ outf, __hip_bfloat16* __restrict__ outb) {
  const int row = blockIdx.x, tid = threadIdx.x;
  const size_t base = (size_t)row * kD;
  float v[8];
  #pragma unroll
  for (int i = 0; i < 2; ++i) {
    int c4 = tid * 2 + i;
    float4 a  = reinterpret_cast<const float4*>(p0 + base)[c4];
    float4 bb = reinterpret_cast<const float4*>(p1 + base)[c4];
    float4 rr = reinterpret_cast<const float4*>(res + base)[c4];
    float4 bs = reinterpret_cast<const float4*>(bias)[c4];
    v[i * 4 + 0] = a.x + bb.x + rr.x + bs.x;
    v[i * 4 + 1] = a.y + bb.y + rr.y + bs.y;
    v[i * 4 + 2] = a.z + bb.z + rr.z + bs.z;
    v[i * 4 + 3] = a.w + bb.w + rr.w + bs.w;
  }
  float s = 0.f;
  #pragma unroll
  for (int i = 0; i < 8; ++i) s += v[i];
  #pragma unroll
  for (int off = 32; off > 0; off >>= 1) s += __shfl_down(s, off);
  __shared__ float r1[4], r2[4];
  if ((tid & 63) == 0) r1[tid >> 6] = s;
  __syncthreads();
  float mean = (r1[0] + r1[1] + r1[2] + r1[3]) * (1.0f / kD);
  float qv = 0.f;
  #pragma unroll
  for (int i = 0; i < 8; ++i) { float d = v[i] - mean; qv += d * d; }
  #pragma unroll
  for (int off = 32; off > 0; off >>= 1) qv += __shfl_down(qv, off);
  if ((tid & 63) == 0) r2[tid >> 6] = qv;
  __syncthreads();
  float rstd = rsqrtf((r2[0] + r2[1] + r2[2] + r2[3]) * (1.0f / kD) + kEPS);
  #pragma unroll
  for (int i = 0; i < 8; ++i) {
    int col = tid * 8 + i;
    float ov = (v[i] - mean) * rstd * w[col] + b[col];
    outf[base + col] = ov;
    if constexpr (WB16) outb[base + col] = __float2bfloat16(ov);
  }
}

// ---------------- launcher ----------------
extern "C" void kernel_launch(void* const* d_in, const int* in_sizes, int n_in,
                              void* d_out, int out_size, void* d_ws, size_t ws_size,
                              hipStream_t stream) {
  (void)in_sizes; (void)n_in; (void)out_size;
  if (ws_size < WS_NEED) return;
  const float* x    = (const float*)d_in[0];
  const float* mask = (const float*)d_in[1];
  const float* wq   = (const float*)d_in[2];
  const float* bq   = (const float*)d_in[3];
  const float* wk   = (const float*)d_in[4];
  const float* bk   = (const float*)d_in[5];
  const float* wv   = (const float*)d_in[6];
  const float* bv   = (const float*)d_in[7];
  const float* wo   = (const float*)d_in[8];
  const float* bo   = (const float*)d_in[9];
  const float* l1w  = (const float*)d_in[10];
  const float* l1b  = (const float*)d_in[11];
  const float* wi   = (const float*)d_in[12];
  const float* bi   = (const float*)d_in[13];
  const float* wo2  = (const float*)d_in[14];
  const float* bo2  = (const float*)d_in[15];
  const float* l2w  = (const float*)d_in[16];
  const float* l2b  = (const float*)d_in[17];

  char* ws = (char*)d_ws;
  __hip_bfloat16* wqb  = (__hip_bfloat16*)(ws + OFF_WQ);   // fused QKV weight base
  __hip_bfloat16* wkb  = (__hip_bfloat16*)(ws + OFF_WK);
  __hip_bfloat16* wvb  = (__hip_bfloat16*)(ws + OFF_WV);
  __hip_bfloat16* wob  = (__hip_bfloat16*)(ws + OFF_WO);
  __hip_bfloat16* wib  = (__hip_bfloat16*)(ws + OFF_WI);
  __hip_bfloat16* wo2b = (__hip_bfloat16*)(ws + OFF_WO2);
  __hip_bfloat16* xb   = (__hip_bfloat16*)(ws + OFF_XB);
  __hip_bfloat16* qb   = (__hip_bfloat16*)(ws + OFF_Q);    // q/k/v contiguous
  __hip_bfloat16* kb2  = (__hip_bfloat16*)(ws + OFF_K);
  __hip_bfloat16* vb2  = (__hip_bfloat16*)(ws + OFF_V);    // [b,h,s,hd]
  __hip_bfloat16* hb   = (__hip_bfloat16*)(ws + OFF_H);
  __hip_bfloat16* ctxb = (__hip_bfloat16*)(ws + OFF_CTX);
  __hip_bfloat16* a1b  = (__hip_bfloat16*)(ws + OFF_A1B);
  float* y1   = (float*)(ws + OFF_Y1);
  float* y2   = (float*)(ws + OFF_Y2);
  float* f2p  = (float*)(ws + OFF_WQ);   // FFN2 split-K partial 1 (32MB, weights dead)
  float* bqkv = (float*)(ws + OFF_Y2);   // 24KB concat bias; dead before Wo writes y2

  // fp32 -> bf16 conversions
  cvt_bf16<<<2048, 256, 0, stream>>>(x,   xb,   kM * kD / 4);
  cvt_bf16<<<1024, 256, 0, stream>>>(wq,  wqb,  kD * kD / 4);
  cvt_bf16<<<1024, 256, 0, stream>>>(wk,  wkb,  kD * kD / 4);
  cvt_bf16<<<1024, 256, 0, stream>>>(wv,  wvb,  kD * kD / 4);
  cvt_bf16<<<1024, 256, 0, stream>>>(wo,  wob,  kD * kD / 4);
  cvt_bf16<<<2048, 256, 0, stream>>>(wi,  wib,  kF * kD / 4);
  cvt_bf16<<<2048, 256, 0, stream>>>(wo2, wo2b, kF * kD / 4);
  // concat QKV bias into scratch
  hipMemcpyAsync(bqkv,          bq, kD * 4, hipMemcpyDeviceToDevice, stream);
  hipMemcpyAsync(bqkv + kD,     bk, kD * 4, hipMemcpyDeviceToDevice, stream);
  hipMemcpyAsync(bqkv + 2 * kD, bv, kD * 4, hipMemcpyDeviceToDevice, stream);

  dim3 blk(512);
  // fused QKV projection: M=4096, N=6144, K=2048 -> grid 24*16 = 384
  gemm256<0><<<dim3(384), blk, 0, stream>>>(
      xb, wqb, bqkv, nullptr, nullptr, qb, kM, 6144, kD, kD);
  // attention
  attn_fwd<<<dim3(512), dim3(512), 0, stream>>>(qb, kb2, vb2, mask, ctxb);
  // out proj, split-K x2 (grid 2*8*16 = 256), partials y1,y2; LN1 fuses +bo+x
  gemm256<3><<<dim3(256), blk, 0, stream>>>(
      ctxb, wob, nullptr, y1, y2, nullptr, kM, kD, kD, kD / 2);
  ln_fuse<true><<<kM, 256, 0, stream>>>(y1, y2, bo, x, l1w, l1b, y1, a1b);
  // FFN1: M=4096, N=8192, K=2048 -> grid 32*16 = 512, GELU epilogue
  gemm256<2><<<dim3(512), blk, 0, stream>>>(
      a1b, wib, bi, nullptr, nullptr, hb, kM, kF, kD, kD);
  // FFN2: split-K x2 (grid 256), partials y2,f2p; LN2 fuses +bo2+attn_out(y1)
  gemm256<3><<<dim3(256), blk, 0, stream>>>(
      hb, wo2b, nullptr, y2, f2p, nullptr, kM, kD, kF, kF / 2);
  ln_fuse<false><<<kM, 256, 0, stream>>>(y2, f2p, bo2, y1, l2w, l2b, (float*)d_out, nullptr);
}

// Round 12
// 604.587 us; speedup vs baseline: 1.7133x; 1.1124x over previous
//
#include <hip/hip_runtime.h>
#include <hip/hip_bf16.h>
#include <cstdint>
#include <cstddef>

typedef __attribute__((ext_vector_type(8))) short short8;   // 8 x bf16 (4 VGPRs)
typedef __attribute__((ext_vector_type(4))) float f32x4;    // MFMA accumulator

#define DEV static __device__ __forceinline__

constexpr int kS = 1024, kD = 2048, kH = 16, kHD = 128, kF = 8192;
constexpr int kM = 4096;            // B*S rows
constexpr float kEPS = 1e-5f;

// ---------------- workspace layout (bytes) ----------------
constexpr size_t SZ_DD   = (size_t)kD * kD * 2;    // 8 MB   bf16 DxD weight
constexpr size_t SZ_FD   = (size_t)kF * kD * 2;    // 32 MB  bf16 FxD weight
constexpr size_t SZ_MD16 = (size_t)kM * kD * 2;    // 16 MB  bf16 activation
constexpr size_t SZ_MD32 = (size_t)kM * kD * 4;    // 32 MB  f32 activation
constexpr size_t OFF_WQ  = 0;                      // wq..wo2,x contiguous bf16 region
constexpr size_t OFF_WK  = OFF_WQ + SZ_DD;
constexpr size_t OFF_WV  = OFF_WK + SZ_DD;
constexpr size_t OFF_WO  = OFF_WV + SZ_DD;
constexpr size_t OFF_WI  = OFF_WO + SZ_DD;
constexpr size_t OFF_WO2 = OFF_WI + SZ_FD;
constexpr size_t OFF_XB  = OFF_WO2 + SZ_FD;        // region reused for h later
constexpr size_t OFF_Q   = OFF_XB + SZ_MD16;       // q/k/v contiguous (fused epilogue)
constexpr size_t OFF_K   = OFF_Q + SZ_MD16;
constexpr size_t OFF_V   = OFF_K + SZ_MD16;        // V in [b,h,s,hd] (attn transposes)
constexpr size_t OFF_H   = OFF_XB;                 // 64 MB: xb+q+k+v dead by FFN1
constexpr size_t OFF_CTX = OFF_V + SZ_MD16;
constexpr size_t OFF_Y1  = OFF_CTX + SZ_MD16;      // f32
constexpr size_t OFF_A1B = OFF_Y1 + SZ_MD32;       // bf16 attn_out
constexpr size_t OFF_Y2  = OFF_A1B + SZ_MD16;      // f32 (first 24KB doubles as bqkv early)
constexpr size_t WS_NEED = OFF_Y2 + SZ_MD32;       // 256 MB total
// FFN2 second split-K partial reuses dead wq..wo region (4 x 8MB = 32MB) at OFF_WQ.

DEV void gload16(const void* g, void* l) {
  __builtin_amdgcn_global_load_lds(
      (const __attribute__((address_space(1))) unsigned int*)g,
      (__attribute__((address_space(3))) unsigned int*)l, 16, 0, 0);
}

// ------------- fused fp32->bf16 convert (all weights + x) + bias concat -------------
// Destinations are contiguous bf16 at ws+OFF_WQ in order wq,wk,wv,wo,wi,wo2,x
// (12M float4 of weights + 2M float4 of x). Tail segment copies bq|bk|bv into
// bqkv (f32). One launch replaces 7 cvt kernels + 3 memcpy nodes.
__global__ void cvt_all(const float* __restrict__ x,  const float* __restrict__ wq,
                        const float* __restrict__ wk, const float* __restrict__ wv,
                        const float* __restrict__ wo, const float* __restrict__ wi,
                        const float* __restrict__ wo2,
                        const float* __restrict__ bq, const float* __restrict__ bk,
                        const float* __restrict__ bv,
                        __hip_bfloat16* __restrict__ outw, float* __restrict__ bqkv) {
  constexpr int M1 = 1 << 20;          // float4 count of one DxD matrix
  constexpr int NW = 14 * M1;          // total bf16-dest float4s
  int stride = gridDim.x * blockDim.x;
  for (int i = blockIdx.x * blockDim.x + threadIdx.x; i < NW + 1536; i += stride) {
    if (i < NW) {
      const float* src; int off;
      if (i < 4 * M1)       { src = (i < M1) ? wq : (i < 2 * M1) ? wk : (i < 3 * M1) ? wv : wo;
                              off = i & (M1 - 1); }
      else if (i < 8 * M1)  { src = wi;  off = i - 4 * M1; }
      else if (i < 12 * M1) { src = wo2; off = i - 8 * M1; }
      else                  { src = x;   off = i - 12 * M1; }
      float4 v = reinterpret_cast<const float4*>(src)[off];
      union { ushort4 u; __hip_bfloat16 h[4]; } o;
      o.h[0] = __float2bfloat16(v.x);
      o.h[1] = __float2bfloat16(v.y);
      o.h[2] = __float2bfloat16(v.z);
      o.h[3] = __float2bfloat16(v.w);
      reinterpret_cast<ushort4*>(outw)[i] = o.u;
    } else {
      int j = i - NW;                   // 0..1535 (512 float4 per bias)
      const float* src = (j < 512) ? bq : (j < 1024) ? bk : bv;
      reinterpret_cast<float4*>(bqkv)[j] =
          reinterpret_cast<const float4*>(src)[j & 511];
    }
  }
}

// ---------------- 256x256 GEMM (r8/r11 schedule — frozen) ----------------
// MODE 0: fused QKV scatter — all of q/k/v -> [b,h,s,hd] (uniform), outb = q base
// MODE 2: out bf16 = gelu(acc + bias) at [row*N+col], outb
// MODE 3: raw f32 partial (split-K): out0/out1 selected by split index
template <int MODE>
__global__ __launch_bounds__(512, 2)
void gemm256(const __hip_bfloat16* __restrict__ A,
             const __hip_bfloat16* __restrict__ Bt,
             const float* __restrict__ bias,
             float* __restrict__ out0, float* __restrict__ out1,
             void* __restrict__ outb,
             int M, int N, int K, int kLen) {
  __shared__ __align__(16) char lds[131072];   // A: [2][256][64]b16 @0, B: @65536
  const int tid = threadIdx.x;
  const int lane = tid & 63, w = tid >> 6;
  const int wm = w >> 2, wn = w & 3;
  const int hw = w >> 2;
  const int lg = lane >> 4, lr = lane & 15;
  const int gy = M >> 8, gx = N >> 8;
  const int nwg = gridDim.x, orig = blockIdx.x;
  const int l = (orig & 7) * (nwg >> 3) + (orig >> 3);   // XCD-chunked (nwg%8==0)
  const int tilesPer = gx * gy;
  const int spl = l / tilesPer;
  const int rem = l - spl * tilesPer;
  const int bx = rem / gy, by = rem - bx * gy;           // n-panel-major
  const int m0 = by * 256, n0 = bx * 256;
  const int k0 = spl * kLen;
  const int NT = kLen >> 6;

  const char* gs[8];
  #pragma unroll
  for (int h = 0; h < 4; ++h) {
    const __hip_bfloat16* src = (h < 2) ? A : Bt;
    const int r0 = ((h < 2) ? m0 : n0) + (h & 1) * 128;
    #pragma unroll
    for (int i = 0; i < 2; ++i) {
      int c = i * 512 + tid;
      int row = c >> 3, slot = c & 7;
      gs[h * 2 + i] =
          (const char*)(src + (size_t)(r0 + row) * K + k0 + (slot ^ (row & 7)) * 8);
    }
  }

#define STAGE(P, H, TOFF)                                                          \
  {                                                                                \
    char* dstb = lds + (((H) < 2) ? 0 : 65536) + (P) * 32768 + ((H) & 1) * 16384;  \
    gload16(gs[(H) * 2 + 0] + (TOFF) * 128, dstb + (0 * 512 + tid) * 16);          \
    gload16(gs[(H) * 2 + 1] + (TOFF) * 128, dstb + (1 * 512 + tid) * 16);          \
  }

  auto ldA = [&](int P, int qm, int mr, int kk) {
    int row = qm * 128 + wm * 64 + mr * 16 + lr;
    return *reinterpret_cast<const short8*>(
        lds + P * 32768 + row * 128 + (((kk * 4 + lg) ^ (row & 7)) * 16));
  };
  auto ldB = [&](int P, int qn, int nr, int kk) {
    int row = qn * 128 + wn * 32 + nr * 16 + lr;
    return *reinterpret_cast<const short8*>(
        lds + 65536 + P * 32768 + row * 128 + (((kk * 4 + lg) ^ (row & 7)) * 16));
  };

  f32x4 acc[4][4][2] = {};   // [phase][mi][ni]

#define MFMA_HALF(p, kk, B)                                                     \
  _Pragma("unroll")                                                             \
  for (int mi = 0; mi < 4; ++mi)                                                \
    _Pragma("unroll")                                                           \
    for (int ni = 0; ni < 2; ++ni)                                              \
      acc[p][mi][ni] = __builtin_amdgcn_mfma_f32_16x16x32_bf16(                 \
          av[kk][mi], B[kk][ni], acc[p][mi][ni], 0, 0, 0);

#define WAIT_LGKM(n)                                                            \
  asm volatile("s_waitcnt lgkmcnt(" #n ")" ::: "memory");                       \
  __builtin_amdgcn_sched_barrier(0);

#define TILE_BODY(P, PF)                                                        \
  {                                                                             \
    asm volatile("s_waitcnt vmcnt(0)" ::: "memory");                            \
    __builtin_amdgcn_s_barrier();                                               \
    _Pragma("unroll")                                                           \
    for (int i = 0; i < 4; ++i) av[0][i] = ldA(P, hw, i, 0);                    \
    _Pragma("unroll")                                                           \
    for (int i = 0; i < 2; ++i) b0[0][i] = ldB(P, hw, i, 0);                    \
    _Pragma("unroll")                                                           \
    for (int i = 0; i < 4; ++i) av[1][i] = ldA(P, hw, i, 1);                    \
    _Pragma("unroll")                                                           \
    for (int i = 0; i < 2; ++i) b0[1][i] = ldB(P, hw, i, 1);                    \
    if (PF) { STAGE((P) ^ 1, 0, 1 + (P)) STAGE((P) ^ 1, 2, 1 + (P)) }           \
    WAIT_LGKM(6)                                                                \
    __builtin_amdgcn_s_setprio(1);                                              \
    MFMA_HALF(0, 0, b0)                                                         \
    WAIT_LGKM(0)                                                                \
    MFMA_HALF(0, 1, b0)                                                         \
    __builtin_amdgcn_s_setprio(0);                                              \
    _Pragma("unroll")                                                           \
    for (int i = 0; i < 2; ++i) b1[0][i] = ldB(P, 1 - hw, i, 0);                \
    _Pragma("unroll")                                                           \
    for (int i = 0; i < 2; ++i) b1[1][i] = ldB(P, 1 - hw, i, 1);                \
    if (PF) { STAGE((P) ^ 1, 3, 1 + (P)) STAGE((P) ^ 1, 1, 1 + (P)) }           \
    WAIT_LGKM(2)                                                                \
    __builtin_amdgcn_s_setprio(1);                                              \
    MFMA_HALF(1, 0, b1)                                                         \
    WAIT_LGKM(0)                                                                \
    MFMA_HALF(1, 1, b1)                                                         \
    __builtin_amdgcn_s_setprio(0);                                              \
    _Pragma("unroll")                                                           \
    for (int i = 0; i < 4; ++i) av[0][i] = ldA(P, 1 - hw, i, 0);                \
    _Pragma("unroll")                                                           \
    for (int i = 0; i < 4; ++i) av[1][i] = ldA(P, 1 - hw, i, 1);                \
    WAIT_LGKM(4)                                                                \
    __builtin_amdgcn_s_setprio(1);                                              \
    MFMA_HALF(2, 0, b1)                                                         \
    WAIT_LGKM(0)                                                                \
    MFMA_HALF(2, 1, b1)                                                         \
    __builtin_amdgcn_s_setprio(0);                                              \
    _Pragma("unroll")                                                           \
    for (int i = 0; i < 2; ++i) b0[0][i] = ldB(P, hw, i, 0);                    \
    _Pragma("unroll")                                                           \
    for (int i = 0; i < 2; ++i) b0[1][i] = ldB(P, hw, i, 1);                    \
    WAIT_LGKM(2)                                                                \
    __builtin_amdgcn_s_setprio(1);                                              \
    MFMA_HALF(3, 0, b0)                                                         \
    WAIT_LGKM(0)                                                                \
    MFMA_HALF(3, 1, b0)                                                         \
    __builtin_amdgcn_s_setprio(0);                                              \
  }

  STAGE(0, 0, 0) STAGE(0, 2, 0) STAGE(0, 3, 0) STAGE(0, 1, 0)

  for (int t2 = 0; t2 < NT; t2 += 2) {
    short8 av[2][4], b0[2][2], b1[2][2];
    TILE_BODY(0, true)
    TILE_BODY(1, (t2 + 2 < NT))
    #pragma unroll
    for (int j = 0; j < 8; ++j) gs[j] += 256;
  }
#undef TILE_BODY
#undef MFMA_HALF
#undef WAIT_LGKM
#undef STAGE

  // epilogue: p0:(hw,hw) p1:(hw,1-hw) p2:(1-hw,1-hw) p3:(1-hw,hw)
  #pragma unroll
  for (int p = 0; p < 4; ++p) {
    const int qm = (p < 2) ? hw : 1 - hw;
    const int qn = (p == 0 || p == 3) ? hw : 1 - hw;
    #pragma unroll
    for (int ni = 0; ni < 2; ++ni) {
      int col = n0 + qn * 128 + wn * 32 + ni * 16 + lr;
      float bvv = 0.f;
      if constexpr (MODE != 3) bvv = bias[col];
      #pragma unroll
      for (int mi = 0; mi < 4; ++mi) {
        int row0 = m0 + qm * 128 + wm * 64 + mi * 16 + lg * 4;
        #pragma unroll
        for (int r = 0; r < 4; ++r) {
          int row = row0 + r;
          float val = acc[p][mi][ni][r] + bvv;
          if constexpr (MODE == 0) {
            int which = col >> 11;
            int d = col & 2047;
            int hh = d >> 7, hd = d & 127;
            int bb = row >> 10, ss = row & 1023;
            __hip_bfloat16* base = (__hip_bfloat16*)outb + (size_t)which * ((size_t)kM * kD);
            base[(((size_t)(bb * kH + hh)) * kS + ss) * kHD + hd] = __float2bfloat16(val);
          } else if constexpr (MODE == 2) {
            float g = 0.5f * val * (1.0f + erff(val * 0.70710678118654752f));
            ((__hip_bfloat16*)outb)[(size_t)row * N + col] = __float2bfloat16(g);
          } else {
            float* o = spl ? out1 : out0;
            o[(size_t)row * N + col] = val;
          }
        }
      }
    }
  }
}

// ---------------- flash attention — 2 q-tiles per block ----------------
// 256 blocks; each block owns 256 q-rows (2 tiles of 128) of one bh and
// streams K/V once: KV global traffic and staging/sync amortized 2x.
// K via global_load_lds (swizzled source); V reg-staged + in-reg transpose
// into swizzled Vt (write swizzle matches PV read swizzle).
__global__ __launch_bounds__(512, 2)
void attn_fwd(const __hip_bfloat16* __restrict__ q,
              const __hip_bfloat16* __restrict__ k,
              const __hip_bfloat16* __restrict__ v,
              const float* __restrict__ mask,
              __hip_bfloat16* __restrict__ ctx) {
  __shared__ __align__(16) char Ks[2][64 * 256];    // [buf][key][dim] slot16^(row&15)
  __shared__ __align__(16) char Vt[2][128 * 128];   // [buf][hd][key64] slot8^(hd&7)
  __shared__ __align__(16) char Ps[8][2048];        // per-wave P [16][64], ^((row&7)<<4)
  const int tid = threadIdx.x, lane = tid & 63, w = tid >> 6;
  const int lg = lane >> 4, lr = lane & 15;
  const int orig = blockIdx.x;                      // 256 blocks
  const int l = (orig & 7) * 32 + (orig >> 3);      // XCD-chunked: 8 bh per XCD
  const int qp = l & 3, bh = l >> 2;                // q-pair 0..3, bh 0..63
  const int b = bh >> 4;
  const int s4 = tid >> 5, hd4 = tid & 31;          // V-transpose role

  short8 qf[2][4];
  #pragma unroll
  for (int s = 0; s < 2; ++s) {
    const __hip_bfloat16* qp_ =
        q + ((size_t)bh * kS + qp * 256 + s * 128 + w * 16 + lr) * kHD + lg * 8;
    #pragma unroll
    for (int kk = 0; kk < 4; ++kk)
      qf[s][kk] = *reinterpret_cast<const short8*>(qp_ + kk * 32);
  }

  auto stageK = [&](int bufi, int t) {
    #pragma unroll
    for (int i = 0; i < 2; ++i) {                   // K tile: 64 rows x 256B
      int c = i * 512 + tid;
      int row = c >> 4, slot = c & 15;
      gload16(k + ((size_t)bh * kS + t * 64 + row) * kHD + (slot ^ (row & 15)) * 8,
              Ks[bufi] + c * 16);
    }
  };
  union VU { uint2 u; ushort s[4]; };
  VU vr[4];
  auto loadV = [&](int t) {
    #pragma unroll
    for (int i = 0; i < 4; ++i)
      vr[i].u = *reinterpret_cast<const uint2*>(
          v + ((size_t)bh * kS + t * 64 + s4 * 4 + i) * kHD + hd4 * 4);
  };
  auto writeV = [&](int bufi) {
    #pragma unroll
    for (int j = 0; j < 4; ++j) {
      int hd = hd4 * 4 + j;
      ushort4 o4;
      o4.x = vr[0].s[j]; o4.y = vr[1].s[j]; o4.z = vr[2].s[j]; o4.w = vr[3].s[j];
      *reinterpret_cast<ushort4*>(
          Vt[bufi] + hd * 128 + (((s4 >> 1) ^ (hd & 7)) << 4) + ((s4 & 1) << 3)) = o4;
    }
  };

  f32x4 o[2][8] = {};
  float mrun[2][4], lrun[2][4];
  #pragma unroll
  for (int s = 0; s < 2; ++s)
    #pragma unroll
    for (int r = 0; r < 4; ++r) { mrun[s][r] = -1e30f; lrun[s][r] = 0.f; }
  const float scale = 0.08838834764831845f;         // 1/sqrt(128)

  stageK(0, 0);
  loadV(0);
  writeV(0);
  __syncthreads();

  int buf = 0;
  for (int t = 0; t < 16; ++t) {
    if (t + 1 < 16) { stageK(buf ^ 1, t + 1); loadV(t + 1); }

    float mv[4];
    #pragma unroll
    for (int j = 0; j < 4; ++j) mv[j] = mask[(size_t)b * kS + t * 64 + j * 16 + lr];

    #pragma unroll
    for (int s = 0; s < 2; ++s) {
      // S = Q K^T
      f32x4 sacc[4] = {};
      #pragma unroll
      for (int j = 0; j < 4; ++j) {
        int key = j * 16 + lr;
        #pragma unroll
        for (int kk = 0; kk < 4; ++kk) {
          short8 bfrag = *reinterpret_cast<const short8*>(
              Ks[buf] + key * 256 + (((kk * 4 + lg) ^ (key & 15)) * 16));
          sacc[j] = __builtin_amdgcn_mfma_f32_16x16x32_bf16(qf[s][kk], bfrag, sacc[j], 0, 0, 0);
        }
      }
      float sarr[4][4];
      #pragma unroll
      for (int j = 0; j < 4; ++j)
        #pragma unroll
        for (int r = 0; r < 4; ++r) sarr[j][r] = sacc[j][r] * scale + mv[j];
      // online softmax
      #pragma unroll
      for (int r = 0; r < 4; ++r) {
        float tm = fmaxf(fmaxf(sarr[0][r], sarr[1][r]), fmaxf(sarr[2][r], sarr[3][r]));
        #pragma unroll
        for (int d = 1; d < 16; d <<= 1) tm = fmaxf(tm, __shfl_xor(tm, d));
        float mnew = fmaxf(mrun[s][r], tm);
        float alpha = __expf(mrun[s][r] - mnew);
        mrun[s][r] = mnew;
        float rs = 0.f;
        #pragma unroll
        for (int j = 0; j < 4; ++j) {
          float p = __expf(sarr[j][r] - mnew);
          sarr[j][r] = p;
          rs += p;
        }
        #pragma unroll
        for (int d = 1; d < 16; d <<= 1) rs += __shfl_xor(rs, d);
        lrun[s][r] = lrun[s][r] * alpha + rs;
        #pragma unroll
        for (int n = 0; n < 8; ++n) o[s][n][r] *= alpha;
      }
      // P -> per-wave LDS (wave-local, in-order DS => safe reuse across s)
      #pragma unroll
      for (int r = 0; r < 4; ++r) {
        int qr = lg * 4 + r;
        #pragma unroll
        for (int j = 0; j < 4; ++j)
          *reinterpret_cast<__hip_bfloat16*>(
              Ps[w] + ((qr * 128 + (j * 16 + lr) * 2) ^ ((qr & 7) << 4))) =
              __float2bfloat16(sarr[j][r]);
      }
      // O += P V
      #pragma unroll
      for (int kk2 = 0; kk2 < 2; ++kk2) {
        short8 pa = *reinterpret_cast<const short8*>(
            Ps[w] + ((lr * 128 + kk2 * 64 + lg * 16) ^ ((lr & 7) << 4)));
        #pragma unroll
        for (int n = 0; n < 8; ++n) {
          int hd = n * 16 + lr;
          short8 vb = *reinterpret_cast<const short8*>(
              Vt[buf] + hd * 128 + (((kk2 * 4 + lg) ^ (hd & 7)) * 16));
          o[s][n] = __builtin_amdgcn_mfma_f32_16x16x32_bf16(pa, vb, o[s][n], 0, 0, 0);
        }
      }
    }
    if (t + 1 < 16) writeV(buf ^ 1);
    __syncthreads();
    buf ^= 1;
  }

  const int h = bh & 15;
  #pragma unroll
  for (int s = 0; s < 2; ++s)
    #pragma unroll
    for (int r = 0; r < 4; ++r) {
      float inv = 1.0f / lrun[s][r];
      int srow = qp * 256 + s * 128 + w * 16 + lg * 4 + r;
      __hip_bfloat16* cp = ctx + ((size_t)b * kS + srow) * kD + h * 128 + lr;
      #pragma unroll
      for (int n = 0; n < 8; ++n) cp[n * 16] = __float2bfloat16(o[s][n][r] * inv);
    }
}

// ------- LayerNorm over (p0 + p1 + bias + res), one 2048-row per block -------
template <bool WB16>
__global__ void ln_fuse(const float* __restrict__ p0, const float* __restrict__ p1,
                        const float* __restrict__ bias, const float* __restrict__ res,
                        const float* __restrict__ w, const float* __restrict__ b,
                        float* __restrict__ outf, __hip_bfloat16* __restrict__ outb) {
  const int row = blockIdx.x, tid = threadIdx.x;
  const size_t base = (size_t)row * kD;
  float v[8];
  #pragma unroll
  for (int i = 0; i < 2; ++i) {
    int c4 = tid * 2 + i;
    float4 a  = reinterpret_cast<const float4*>(p0 + base)[c4];
    float4 bb = reinterpret_cast<const float4*>(p1 + base)[c4];
    float4 rr = reinterpret_cast<const float4*>(res + base)[c4];
    float4 bs = reinterpret_cast<const float4*>(bias)[c4];
    v[i * 4 + 0] = a.x + bb.x + rr.x + bs.x;
    v[i * 4 + 1] = a.y + bb.y + rr.y + bs.y;
    v[i * 4 + 2] = a.z + bb.z + rr.z + bs.z;
    v[i * 4 + 3] = a.w + bb.w + rr.w + bs.w;
  }
  float s = 0.f;
  #pragma unroll
  for (int i = 0; i < 8; ++i) s += v[i];
  #pragma unroll
  for (int off = 32; off > 0; off >>= 1) s += __shfl_down(s, off);
  __shared__ float r1[4], r2[4];
  if ((tid & 63) == 0) r1[tid >> 6] = s;
  __syncthreads();
  float mean = (r1[0] + r1[1] + r1[2] + r1[3]) * (1.0f / kD);
  float qv = 0.f;
  #pragma unroll
  for (int i = 0; i < 8; ++i) { float d = v[i] - mean; qv += d * d; }
  #pragma unroll
  for (int off = 32; off > 0; off >>= 1) qv += __shfl_down(qv, off);
  if ((tid & 63) == 0) r2[tid >> 6] = qv;
  __syncthreads();
  float rstd = rsqrtf((r2[0] + r2[1] + r2[2] + r2[3]) * (1.0f / kD) + kEPS);
  #pragma unroll
  for (int i = 0; i < 8; ++i) {
    int col = tid * 8 + i;
    float ov = (v[i] - mean) * rstd * w[col] + b[col];
    outf[base + col] = ov;
    if constexpr (WB16) outb[base + col] = __float2bfloat16(ov);
  }
}

// ---------------- launcher ----------------
extern "C" void kernel_launch(void* const* d_in, const int* in_sizes, int n_in,
                              void* d_out, int out_size, void* d_ws, size_t ws_size,
                              hipStream_t stream) {
  (void)in_sizes; (void)n_in; (void)out_size;
  if (ws_size < WS_NEED) return;
  const float* x    = (const float*)d_in[0];
  const float* mask = (const float*)d_in[1];
  const float* wq   = (const float*)d_in[2];
  const float* bq   = (const float*)d_in[3];
  const float* wk   = (const float*)d_in[4];
  const float* bk   = (const float*)d_in[5];
  const float* wv   = (const float*)d_in[6];
  const float* bv   = (const float*)d_in[7];
  const float* wo   = (const float*)d_in[8];
  const float* bo   = (const float*)d_in[9];
  const float* l1w  = (const float*)d_in[10];
  const float* l1b  = (const float*)d_in[11];
  const float* wi   = (const float*)d_in[12];
  const float* bi   = (const float*)d_in[13];
  const float* wo2  = (const float*)d_in[14];
  const float* bo2  = (const float*)d_in[15];
  const float* l2w  = (const float*)d_in[16];
  const float* l2b  = (const float*)d_in[17];

  char* ws = (char*)d_ws;
  __hip_bfloat16* wqb  = (__hip_bfloat16*)(ws + OFF_WQ);
  __hip_bfloat16* wob  = (__hip_bfloat16*)(ws + OFF_WO);
  __hip_bfloat16* wib  = (__hip_bfloat16*)(ws + OFF_WI);
  __hip_bfloat16* wo2b = (__hip_bfloat16*)(ws + OFF_WO2);
  __hip_bfloat16* xb   = (__hip_bfloat16*)(ws + OFF_XB);
  __hip_bfloat16* qb   = (__hip_bfloat16*)(ws + OFF_Q);
  __hip_bfloat16* kb2  = (__hip_bfloat16*)(ws + OFF_K);
  __hip_bfloat16* vb2  = (__hip_bfloat16*)(ws + OFF_V);
  __hip_bfloat16* hb   = (__hip_bfloat16*)(ws + OFF_H);
  __hip_bfloat16* ctxb = (__hip_bfloat16*)(ws + OFF_CTX);
  __hip_bfloat16* a1b  = (__hip_bfloat16*)(ws + OFF_A1B);
  float* y1   = (float*)(ws + OFF_Y1);
  float* y2   = (float*)(ws + OFF_Y2);
  float* f2p  = (float*)(ws + OFF_WQ);   // FFN2 split-K partial 1 (weights dead)
  float* bqkv = (float*)(ws + OFF_Y2);   // 24KB concat bias; dead before Wo writes y2

  // fused conversions + bias concat (1 launch)
  cvt_all<<<2048, 256, 0, stream>>>(x, wq, wk, wv, wo, wi, wo2, bq, bk, bv, wqb, bqkv);

  dim3 blk(512);
  // fused QKV projection: M=4096, N=6144, K=2048 -> grid 24*16 = 384
  gemm256<0><<<dim3(384), blk, 0, stream>>>(
      xb, wqb, bqkv, nullptr, nullptr, qb, kM, 6144, kD, kD);
  // attention (256 blocks, 2 q-tiles each)
  attn_fwd<<<dim3(256), dim3(512), 0, stream>>>(qb, kb2, vb2, mask, ctxb);
  // out proj, split-K x2 (grid 256), partials y1,y2; LN1 fuses +bo+x
  gemm256<3><<<dim3(256), blk, 0, stream>>>(
      ctxb, wob, nullptr, y1, y2, nullptr, kM, kD, kD, kD / 2);
  ln_fuse<true><<<kM, 256, 0, stream>>>(y1, y2, bo, x, l1w, l1b, y1, a1b);
  // FFN1: grid 32*16 = 512, GELU epilogue
  gemm256<2><<<dim3(512), blk, 0, stream>>>(
      a1b, wib, bi, nullptr, nullptr, hb, kM, kF, kD, kD);
  // FFN2: split-K x2 (grid 256), partials y2,f2p; LN2 fuses +bo2+attn_out(y1)
  gemm256<3><<<dim3(256), blk, 0, stream>>>(
      hb, wo2b, nullptr, y2, f2p, nullptr, kM, kD, kF, kF / 2);
  ln_fuse<false><<<kM, 256, 0, stream>>>(y2, f2p, bo2, y1, l2w, l2b, (float*)d_out, nullptr);
}

// Round 13
// 594.646 us; speedup vs baseline: 1.7419x; 1.0167x over previous
//
#include <hip/hip_runtime.h>
#include <hip/hip_bf16.h>
#include <cstdint>
#include <cstddef>

typedef __attribute__((ext_vector_type(8))) short short8;   // 8 x bf16 (4 VGPRs)
typedef __attribute__((ext_vector_type(4))) float f32x4;    // MFMA accumulator

#define DEV static __device__ __forceinline__

constexpr int kS = 1024, kD = 2048, kH = 16, kHD = 128, kF = 8192;
constexpr int kM = 4096;            // B*S rows
constexpr float kEPS = 1e-5f;

// ---------------- workspace layout (bytes) ----------------
constexpr size_t SZ_DD   = (size_t)kD * kD * 2;    // 8 MB   bf16 DxD weight
constexpr size_t SZ_FD   = (size_t)kF * kD * 2;    // 32 MB  bf16 FxD weight
constexpr size_t SZ_MD16 = (size_t)kM * kD * 2;    // 16 MB  bf16 activation
constexpr size_t SZ_MD32 = (size_t)kM * kD * 4;    // 32 MB  f32 activation
constexpr size_t OFF_WQ  = 0;                      // wq..wo2,x contiguous bf16 region
constexpr size_t OFF_WK  = OFF_WQ + SZ_DD;
constexpr size_t OFF_WV  = OFF_WK + SZ_DD;
constexpr size_t OFF_WO  = OFF_WV + SZ_DD;
constexpr size_t OFF_WI  = OFF_WO + SZ_DD;
constexpr size_t OFF_WO2 = OFF_WI + SZ_FD;
constexpr size_t OFF_XB  = OFF_WO2 + SZ_FD;        // region reused for h later
constexpr size_t OFF_Q   = OFF_XB + SZ_MD16;       // q/k/v contiguous (fused epilogue)
constexpr size_t OFF_K   = OFF_Q + SZ_MD16;
constexpr size_t OFF_V   = OFF_K + SZ_MD16;        // V in [b,h,s,hd] (attn transposes)
constexpr size_t OFF_H   = OFF_XB;                 // 64 MB: xb+q+k+v dead by FFN1
constexpr size_t OFF_CTX = OFF_V + SZ_MD16;
constexpr size_t OFF_Y1  = OFF_CTX + SZ_MD16;      // f32
constexpr size_t OFF_A1B = OFF_Y1 + SZ_MD32;       // bf16 attn_out
constexpr size_t OFF_Y2  = OFF_A1B + SZ_MD16;      // f32 (first 24KB doubles as bqkv early)
constexpr size_t WS_NEED = OFF_Y2 + SZ_MD32;       // 256 MB total
// FFN2 second split-K partial reuses dead wq..wo region (4 x 8MB = 32MB) at OFF_WQ.

DEV void gload16(const void* g, void* l) {
  __builtin_amdgcn_global_load_lds(
      (const __attribute__((address_space(1))) unsigned int*)g,
      (__attribute__((address_space(3))) unsigned int*)l, 16, 0, 0);
}

// ------------- fp32->bf16 convert: wq,wk,wv,wo + x + bias concat -------------
// wi/wo2 conversion moved INTO attn_fwd (overlaps its latency slack).
// Dest ushort4 indices: wq..wo -> [0,4M); x -> out[8M + i] for i in [4M,6M).
__global__ void cvt_all(const float* __restrict__ x,  const float* __restrict__ wq,
                        const float* __restrict__ wk, const float* __restrict__ wv,
                        const float* __restrict__ wo,
                        const float* __restrict__ bq, const float* __restrict__ bk,
                        const float* __restrict__ bv,
                        __hip_bfloat16* __restrict__ outw, float* __restrict__ bqkv) {
  constexpr int M1 = 1 << 20;          // float4 count of one DxD matrix
  constexpr int NW = 6 * M1;           // 4 DxD weights + x (2M float4)
  int stride = gridDim.x * blockDim.x;
  for (int i = blockIdx.x * blockDim.x + threadIdx.x; i < NW + 1536; i += stride) {
    if (i < NW) {
      const float* src; int off; int dst;
      if (i < 4 * M1) { src = (i < M1) ? wq : (i < 2 * M1) ? wk : (i < 3 * M1) ? wv : wo;
                        off = i & (M1 - 1); dst = i; }
      else            { src = x; off = i - 4 * M1; dst = i + 8 * M1; }
      float4 v = reinterpret_cast<const float4*>(src)[off];
      union { ushort4 u; __hip_bfloat16 h[4]; } o;
      o.h[0] = __float2bfloat16(v.x);
      o.h[1] = __float2bfloat16(v.y);
      o.h[2] = __float2bfloat16(v.z);
      o.h[3] = __float2bfloat16(v.w);
      reinterpret_cast<ushort4*>(outw)[dst] = o.u;
    } else {
      int j = i - NW;                   // 0..1535 (512 float4 per bias)
      const float* src = (j < 512) ? bq : (j < 1024) ? bk : bv;
      reinterpret_cast<float4*>(bqkv)[j] =
          reinterpret_cast<const float4*>(src)[j & 511];
    }
  }
}

// ---------------- 256x256 GEMM (r8/r11 schedule — frozen) ----------------
// MODE 0: fused QKV scatter — all of q/k/v -> [b,h,s,hd] (uniform), outb = q base
// MODE 2: out bf16 = gelu(acc + bias) at [row*N+col], outb
// MODE 3: raw f32 partial (split-K): out0/out1 selected by split index
template <int MODE>
__global__ __launch_bounds__(512, 2)
void gemm256(const __hip_bfloat16* __restrict__ A,
             const __hip_bfloat16* __restrict__ Bt,
             const float* __restrict__ bias,
             float* __restrict__ out0, float* __restrict__ out1,
             void* __restrict__ outb,
             int M, int N, int K, int kLen) {
  __shared__ __align__(16) char lds[131072];   // A: [2][256][64]b16 @0, B: @65536
  const int tid = threadIdx.x;
  const int lane = tid & 63, w = tid >> 6;
  const int wm = w >> 2, wn = w & 3;
  const int hw = w >> 2;
  const int lg = lane >> 4, lr = lane & 15;
  const int gy = M >> 8, gx = N >> 8;
  const int nwg = gridDim.x, orig = blockIdx.x;
  const int l = (orig & 7) * (nwg >> 3) + (orig >> 3);   // XCD-chunked (nwg%8==0)
  const int tilesPer = gx * gy;
  const int spl = l / tilesPer;
  const int rem = l - spl * tilesPer;
  const int bx = rem / gy, by = rem - bx * gy;           // n-panel-major
  const int m0 = by * 256, n0 = bx * 256;
  const int k0 = spl * kLen;
  const int NT = kLen >> 6;

  const char* gs[8];
  #pragma unroll
  for (int h = 0; h < 4; ++h) {
    const __hip_bfloat16* src = (h < 2) ? A : Bt;
    const int r0 = ((h < 2) ? m0 : n0) + (h & 1) * 128;
    #pragma unroll
    for (int i = 0; i < 2; ++i) {
      int c = i * 512 + tid;
      int row = c >> 3, slot = c & 7;
      gs[h * 2 + i] =
          (const char*)(src + (size_t)(r0 + row) * K + k0 + (slot ^ (row & 7)) * 8);
    }
  }

#define STAGE(P, H, TOFF)                                                          \
  {                                                                                \
    char* dstb = lds + (((H) < 2) ? 0 : 65536) + (P) * 32768 + ((H) & 1) * 16384;  \
    gload16(gs[(H) * 2 + 0] + (TOFF) * 128, dstb + (0 * 512 + tid) * 16);          \
    gload16(gs[(H) * 2 + 1] + (TOFF) * 128, dstb + (1 * 512 + tid) * 16);          \
  }

  auto ldA = [&](int P, int qm, int mr, int kk) {
    int row = qm * 128 + wm * 64 + mr * 16 + lr;
    return *reinterpret_cast<const short8*>(
        lds + P * 32768 + row * 128 + (((kk * 4 + lg) ^ (row & 7)) * 16));
  };
  auto ldB = [&](int P, int qn, int nr, int kk) {
    int row = qn * 128 + wn * 32 + nr * 16 + lr;
    return *reinterpret_cast<const short8*>(
        lds + 65536 + P * 32768 + row * 128 + (((kk * 4 + lg) ^ (row & 7)) * 16));
  };

  f32x4 acc[4][4][2] = {};   // [phase][mi][ni]

#define MFMA_HALF(p, kk, B)                                                     \
  _Pragma("unroll")                                                             \
  for (int mi = 0; mi < 4; ++mi)                                                \
    _Pragma("unroll")                                                           \
    for (int ni = 0; ni < 2; ++ni)                                              \
      acc[p][mi][ni] = __builtin_amdgcn_mfma_f32_16x16x32_bf16(                 \
          av[kk][mi], B[kk][ni], acc[p][mi][ni], 0, 0, 0);

#define WAIT_LGKM(n)                                                            \
  asm volatile("s_waitcnt lgkmcnt(" #n ")" ::: "memory");                       \
  __builtin_amdgcn_sched_barrier(0);

#define TILE_BODY(P, PF)                                                        \
  {                                                                             \
    asm volatile("s_waitcnt vmcnt(0)" ::: "memory");                            \
    __builtin_amdgcn_s_barrier();                                               \
    _Pragma("unroll")                                                           \
    for (int i = 0; i < 4; ++i) av[0][i] = ldA(P, hw, i, 0);                    \
    _Pragma("unroll")                                                           \
    for (int i = 0; i < 2; ++i) b0[0][i] = ldB(P, hw, i, 0);                    \
    _Pragma("unroll")                                                           \
    for (int i = 0; i < 4; ++i) av[1][i] = ldA(P, hw, i, 1);                    \
    _Pragma("unroll")                                                           \
    for (int i = 0; i < 2; ++i) b0[1][i] = ldB(P, hw, i, 1);                    \
    if (PF) { STAGE((P) ^ 1, 0, 1 + (P)) STAGE((P) ^ 1, 2, 1 + (P)) }           \
    WAIT_LGKM(6)                                                                \
    __builtin_amdgcn_s_setprio(1);                                              \
    MFMA_HALF(0, 0, b0)                                                         \
    WAIT_LGKM(0)                                                                \
    MFMA_HALF(0, 1, b0)                                                         \
    __builtin_amdgcn_s_setprio(0);                                              \
    _Pragma("unroll")                                                           \
    for (int i = 0; i < 2; ++i) b1[0][i] = ldB(P, 1 - hw, i, 0);                \
    _Pragma("unroll")                                                           \
    for (int i = 0; i < 2; ++i) b1[1][i] = ldB(P, 1 - hw, i, 1);                \
    if (PF) { STAGE((P) ^ 1, 3, 1 + (P)) STAGE((P) ^ 1, 1, 1 + (P)) }           \
    WAIT_LGKM(2)                                                                \
    __builtin_amdgcn_s_setprio(1);                                              \
    MFMA_HALF(1, 0, b1)                                                         \
    WAIT_LGKM(0)                                                                \
    MFMA_HALF(1, 1, b1)                                                         \
    __builtin_amdgcn_s_setprio(0);                                              \
    _Pragma("unroll")                                                           \
    for (int i = 0; i < 4; ++i) av[0][i] = ldA(P, 1 - hw, i, 0);                \
    _Pragma("unroll")                                                           \
    for (int i = 0; i < 4; ++i) av[1][i] = ldA(P, 1 - hw, i, 1);                \
    WAIT_LGKM(4)                                                                \
    __builtin_amdgcn_s_setprio(1);                                              \
    MFMA_HALF(2, 0, b1)                                                         \
    WAIT_LGKM(0)                                                                \
    MFMA_HALF(2, 1, b1)                                                         \
    __builtin_amdgcn_s_setprio(0);                                              \
    _Pragma("unroll")                                                           \
    for (int i = 0; i < 2; ++i) b0[0][i] = ldB(P, hw, i, 0);                    \
    _Pragma("unroll")                                                           \
    for (int i = 0; i < 2; ++i) b0[1][i] = ldB(P, hw, i, 1);                    \
    WAIT_LGKM(2)                                                                \
    __builtin_amdgcn_s_setprio(1);                                              \
    MFMA_HALF(3, 0, b0)                                                         \
    WAIT_LGKM(0)                                                                \
    MFMA_HALF(3, 1, b0)                                                         \
    __builtin_amdgcn_s_setprio(0);                                              \
  }

  STAGE(0, 0, 0) STAGE(0, 2, 0) STAGE(0, 3, 0) STAGE(0, 1, 0)

  for (int t2 = 0; t2 < NT; t2 += 2) {
    short8 av[2][4], b0[2][2], b1[2][2];
    TILE_BODY(0, true)
    TILE_BODY(1, (t2 + 2 < NT))
    #pragma unroll
    for (int j = 0; j < 8; ++j) gs[j] += 256;
  }
#undef TILE_BODY
#undef MFMA_HALF
#undef WAIT_LGKM
#undef STAGE

  // epilogue: p0:(hw,hw) p1:(hw,1-hw) p2:(1-hw,1-hw) p3:(1-hw,hw)
  #pragma unroll
  for (int p = 0; p < 4; ++p) {
    const int qm = (p < 2) ? hw : 1 - hw;
    const int qn = (p == 0 || p == 3) ? hw : 1 - hw;
    #pragma unroll
    for (int ni = 0; ni < 2; ++ni) {
      int col = n0 + qn * 128 + wn * 32 + ni * 16 + lr;
      float bvv = 0.f;
      if constexpr (MODE != 3) bvv = bias[col];
      #pragma unroll
      for (int mi = 0; mi < 4; ++mi) {
        int row0 = m0 + qm * 128 + wm * 64 + mi * 16 + lg * 4;
        #pragma unroll
        for (int r = 0; r < 4; ++r) {
          int row = row0 + r;
          float val = acc[p][mi][ni][r] + bvv;
          if constexpr (MODE == 0) {
            int which = col >> 11;
            int d = col & 2047;
            int hh = d >> 7, hd = d & 127;
            int bb = row >> 10, ss = row & 1023;
            __hip_bfloat16* base = (__hip_bfloat16*)outb + (size_t)which * ((size_t)kM * kD);
            base[(((size_t)(bb * kH + hh)) * kS + ss) * kHD + hd] = __float2bfloat16(val);
          } else if constexpr (MODE == 2) {
            float g = 0.5f * val * (1.0f + erff(val * 0.70710678118654752f));
            ((__hip_bfloat16*)outb)[(size_t)row * N + col] = __float2bfloat16(g);
          } else {
            float* o = spl ? out1 : out0;
            o[(size_t)row * N + col] = val;
          }
        }
      }
    }
  }
}

// ---------------- flash attention — 2 q-tiles/block + interleaved wi/wo2 cvt ----------------
// 256 blocks; each owns 256 q-rows of one bh, streams K/V once. Additionally
// converts wi|wo2 (fp32->bf16, 8M float4 total) spread over blocks x 16 tiles x
// 512 threads x 4 float4 — issued alongside the K/V prefetch so the fp32 loads
// share attention's latency slack. wib/wo2b consumed 2+ kernels later (stream
// order guarantees completion).
__global__ __launch_bounds__(512, 2)
void attn_fwd(const __hip_bfloat16* __restrict__ q,
              const __hip_bfloat16* __restrict__ k,
              const __hip_bfloat16* __restrict__ v,
              const float* __restrict__ mask,
              __hip_bfloat16* __restrict__ ctx,
              const float* __restrict__ wi, const float* __restrict__ wo2,
              __hip_bfloat16* __restrict__ outw /* ushort4 base, wi at +4M */) {
  __shared__ __align__(16) char Ks[2][64 * 256];    // [buf][key][dim] slot16^(row&15)
  __shared__ __align__(16) char Vt[2][128 * 128];   // [buf][hd][key64] slot8^(hd&7)
  __shared__ __align__(16) char Ps[8][2048];        // per-wave P [16][64], ^((row&7)<<4)
  const int tid = threadIdx.x, lane = tid & 63, w = tid >> 6;
  const int lg = lane >> 4, lr = lane & 15;
  const int orig = blockIdx.x;                      // 256 blocks
  const int l = (orig & 7) * 32 + (orig >> 3);      // XCD-chunked: 8 bh per XCD
  const int qp = l & 3, bh = l >> 2;                // q-pair 0..3, bh 0..63
  const int b = bh >> 4;
  const int s4 = tid >> 5, hd4 = tid & 31;          // V-transpose role

  short8 qf[2][4];
  #pragma unroll
  for (int s = 0; s < 2; ++s) {
    const __hip_bfloat16* qp_ =
        q + ((size_t)bh * kS + qp * 256 + s * 128 + w * 16 + lr) * kHD + lg * 8;
    #pragma unroll
    for (int kk = 0; kk < 4; ++kk)
      qf[s][kk] = *reinterpret_cast<const short8*>(qp_ + kk * 32);
  }

  auto stageK = [&](int bufi, int t) {
    #pragma unroll
    for (int i = 0; i < 2; ++i) {                   // K tile: 64 rows x 256B
      int c = i * 512 + tid;
      int row = c >> 4, slot = c & 15;
      gload16(k + ((size_t)bh * kS + t * 64 + row) * kHD + (slot ^ (row & 15)) * 8,
              Ks[bufi] + c * 16);
    }
  };
  union VU { uint2 u; ushort s[4]; };
  VU vr[4];
  auto loadV = [&](int t) {
    #pragma unroll
    for (int i = 0; i < 4; ++i)
      vr[i].u = *reinterpret_cast<const uint2*>(
          v + ((size_t)bh * kS + t * 64 + s4 * 4 + i) * kHD + hd4 * 4);
  };
  auto writeV = [&](int bufi) {
    #pragma unroll
    for (int j = 0; j < 4; ++j) {
      int hd = hd4 * 4 + j;
      ushort4 o4;
      o4.x = vr[0].s[j]; o4.y = vr[1].s[j]; o4.z = vr[2].s[j]; o4.w = vr[3].s[j];
      *reinterpret_cast<ushort4*>(
          Vt[bufi] + hd * 128 + (((s4 >> 1) ^ (hd & 7)) << 4) + ((s4 & 1) << 3)) = o4;
    }
  };
  // interleaved wi/wo2 conversion: 4 float4 per thread per tile
  float4 cw[4];
  auto cvLoad = [&](int t) {
    int g0 = ((orig * 16 + t) * 512 + tid) * 4;     // 0..8M-4
    #pragma unroll
    for (int j = 0; j < 4; ++j) {
      int g = g0 + j;
      const float* src = (g < (4 << 20)) ? wi : wo2;
      int off = g & ((4 << 20) - 1);
      cw[j] = reinterpret_cast<const float4*>(src)[off];
    }
  };
  auto cvStore = [&](int t) {
    int g0 = ((orig * 16 + t) * 512 + tid) * 4;
    #pragma unroll
    for (int j = 0; j < 4; ++j) {
      union { ushort4 u; __hip_bfloat16 h[4]; } o4;
      o4.h[0] = __float2bfloat16(cw[j].x);
      o4.h[1] = __float2bfloat16(cw[j].y);
      o4.h[2] = __float2bfloat16(cw[j].z);
      o4.h[3] = __float2bfloat16(cw[j].w);
      reinterpret_cast<ushort4*>(outw)[(4 << 20) + g0 + j] = o4.u;
    }
  };

  f32x4 o[2][8] = {};
  float mrun[2][4], lrun[2][4];
  #pragma unroll
  for (int s = 0; s < 2; ++s)
    #pragma unroll
    for (int r = 0; r < 4; ++r) { mrun[s][r] = -1e30f; lrun[s][r] = 0.f; }
  const float scale = 0.08838834764831845f;         // 1/sqrt(128)

  stageK(0, 0);
  loadV(0);
  writeV(0);
  __syncthreads();

  int buf = 0;
  for (int t = 0; t < 16; ++t) {
    if (t + 1 < 16) { stageK(buf ^ 1, t + 1); loadV(t + 1); }
    cvLoad(t);                                      // fp32 weight chunk in flight

    float mv[4];
    #pragma unroll
    for (int j = 0; j < 4; ++j) mv[j] = mask[(size_t)b * kS + t * 64 + j * 16 + lr];

    #pragma unroll
    for (int s = 0; s < 2; ++s) {
      f32x4 sacc[4] = {};
      #pragma unroll
      for (int j = 0; j < 4; ++j) {
        int key = j * 16 + lr;
        #pragma unroll
        for (int kk = 0; kk < 4; ++kk) {
          short8 bfrag = *reinterpret_cast<const short8*>(
              Ks[buf] + key * 256 + (((kk * 4 + lg) ^ (key & 15)) * 16));
          sacc[j] = __builtin_amdgcn_mfma_f32_16x16x32_bf16(qf[s][kk], bfrag, sacc[j], 0, 0, 0);
        }
      }
      float sarr[4][4];
      #pragma unroll
      for (int j = 0; j < 4; ++j)
        #pragma unroll
        for (int r = 0; r < 4; ++r) sarr[j][r] = sacc[j][r] * scale + mv[j];
      #pragma unroll
      for (int r = 0; r < 4; ++r) {
        float tm = fmaxf(fmaxf(sarr[0][r], sarr[1][r]), fmaxf(sarr[2][r], sarr[3][r]));
        #pragma unroll
        for (int d = 1; d < 16; d <<= 1) tm = fmaxf(tm, __shfl_xor(tm, d));
        float mnew = fmaxf(mrun[s][r], tm);
        float alpha = __expf(mrun[s][r] - mnew);
        mrun[s][r] = mnew;
        float rs = 0.f;
        #pragma unroll
        for (int j = 0; j < 4; ++j) {
          float p = __expf(sarr[j][r] - mnew);
          sarr[j][r] = p;
          rs += p;
        }
        #pragma unroll
        for (int d = 1; d < 16; d <<= 1) rs += __shfl_xor(rs, d);
        lrun[s][r] = lrun[s][r] * alpha + rs;
        #pragma unroll
        for (int n = 0; n < 8; ++n) o[s][n][r] *= alpha;
      }
      #pragma unroll
      for (int r = 0; r < 4; ++r) {
        int qr = lg * 4 + r;
        #pragma unroll
        for (int j = 0; j < 4; ++j)
          *reinterpret_cast<__hip_bfloat16*>(
              Ps[w] + ((qr * 128 + (j * 16 + lr) * 2) ^ ((qr & 7) << 4))) =
              __float2bfloat16(sarr[j][r]);
      }
      #pragma unroll
      for (int kk2 = 0; kk2 < 2; ++kk2) {
        short8 pa = *reinterpret_cast<const short8*>(
            Ps[w] + ((lr * 128 + kk2 * 64 + lg * 16) ^ ((lr & 7) << 4)));
        #pragma unroll
        for (int n = 0; n < 8; ++n) {
          int hd = n * 16 + lr;
          short8 vb = *reinterpret_cast<const short8*>(
              Vt[buf] + hd * 128 + (((kk2 * 4 + lg) ^ (hd & 7)) * 16));
          o[s][n] = __builtin_amdgcn_mfma_f32_16x16x32_bf16(pa, vb, o[s][n], 0, 0, 0);
        }
      }
    }
    cvStore(t);                                     // convert + store (auto-waits cw)
    if (t + 1 < 16) writeV(buf ^ 1);
    __syncthreads();
    buf ^= 1;
  }

  const int h = bh & 15;
  #pragma unroll
  for (int s = 0; s < 2; ++s)
    #pragma unroll
    for (int r = 0; r < 4; ++r) {
      float inv = 1.0f / lrun[s][r];
      int srow = qp * 256 + s * 128 + w * 16 + lg * 4 + r;
      __hip_bfloat16* cp = ctx + ((size_t)b * kS + srow) * kD + h * 128 + lr;
      #pragma unroll
      for (int n = 0; n < 8; ++n) cp[n * 16] = __float2bfloat16(o[s][n][r] * inv);
    }
}

// ------- LayerNorm over (p0 + p1 + bias + res), one 2048-row per block -------
template <bool WB16>
__global__ void ln_fuse(const float* __restrict__ p0, const float* __restrict__ p1,
                        const float* __restrict__ bias, const float* __restrict__ res,
                        const float* __restrict__ w, const float* __restrict__ b,
                        float* __restrict__ outf, __hip_bfloat16* __restrict__ outb) {
  const int row = blockIdx.x, tid = threadIdx.x;
  const size_t base = (size_t)row * kD;
  float v[8];
  #pragma unroll
  for (int i = 0; i < 2; ++i) {
    int c4 = tid * 2 + i;
    float4 a  = reinterpret_cast<const float4*>(p0 + base)[c4];
    float4 bb = reinterpret_cast<const float4*>(p1 + base)[c4];
    float4 rr = reinterpret_cast<const float4*>(res + base)[c4];
    float4 bs = reinterpret_cast<const float4*>(bias)[c4];
    v[i * 4 + 0] = a.x + bb.x + rr.x + bs.x;
    v[i * 4 + 1] = a.y + bb.y + rr.y + bs.y;
    v[i * 4 + 2] = a.z + bb.z + rr.z + bs.z;
    v[i * 4 + 3] = a.w + bb.w + rr.w + bs.w;
  }
  float s = 0.f;
  #pragma unroll
  for (int i = 0; i < 8; ++i) s += v[i];
  #pragma unroll
  for (int off = 32; off > 0; off >>= 1) s += __shfl_down(s, off);
  __shared__ float r1[4], r2[4];
  if ((tid & 63) == 0) r1[tid >> 6] = s;
  __syncthreads();
  float mean = (r1[0] + r1[1] + r1[2] + r1[3]) * (1.0f / kD);
  float qv = 0.f;
  #pragma unroll
  for (int i = 0; i < 8; ++i) { float d = v[i] - mean; qv += d * d; }
  #pragma unroll
  for (int off = 32; off > 0; off >>= 1) qv += __shfl_down(qv, off);
  if ((tid & 63) == 0) r2[tid >> 6] = qv;
  __syncthreads();
  float rstd = rsqrtf((r2[0] + r2[1] + r2[2] + r2[3]) * (1.0f / kD) + kEPS);
  #pragma unroll
  for (int i = 0; i < 8; ++i) {
    int col = tid * 8 + i;
    float ov = (v[i] - mean) * rstd * w[col] + b[col];
    outf[base + col] = ov;
    if constexpr (WB16) outb[base + col] = __float2bfloat16(ov);
  }
}

// ---------------- launcher ----------------
extern "C" void kernel_launch(void* const* d_in, const int* in_sizes, int n_in,
                              void* d_out, int out_size, void* d_ws, size_t ws_size,
                              hipStream_t stream) {
  (void)in_sizes; (void)n_in; (void)out_size;
  if (ws_size < WS_NEED) return;
  const float* x    = (const float*)d_in[0];
  const float* mask = (const float*)d_in[1];
  const float* wq   = (const float*)d_in[2];
  const float* bq   = (const float*)d_in[3];
  const float* wk   = (const float*)d_in[4];
  const float* bk   = (const float*)d_in[5];
  const float* wv   = (const float*)d_in[6];
  const float* bv   = (const float*)d_in[7];
  const float* wo   = (const float*)d_in[8];
  const float* bo   = (const float*)d_in[9];
  const float* l1w  = (const float*)d_in[10];
  const float* l1b  = (const float*)d_in[11];
  const float* wi   = (const float*)d_in[12];
  const float* bi   = (const float*)d_in[13];
  const float* wo2  = (const float*)d_in[14];
  const float* bo2  = (const float*)d_in[15];
  const float* l2w  = (const float*)d_in[16];
  const float* l2b  = (const float*)d_in[17];

  char* ws = (char*)d_ws;
  __hip_bfloat16* wqb  = (__hip_bfloat16*)(ws + OFF_WQ);
  __hip_bfloat16* wob  = (__hip_bfloat16*)(ws + OFF_WO);
  __hip_bfloat16* wib  = (__hip_bfloat16*)(ws + OFF_WI);
  __hip_bfloat16* wo2b = (__hip_bfloat16*)(ws + OFF_WO2);
  __hip_bfloat16* xb   = (__hip_bfloat16*)(ws + OFF_XB);
  __hip_bfloat16* qb   = (__hip_bfloat16*)(ws + OFF_Q);
  __hip_bfloat16* kb2  = (__hip_bfloat16*)(ws + OFF_K);
  __hip_bfloat16* vb2  = (__hip_bfloat16*)(ws + OFF_V);
  __hip_bfloat16* hb   = (__hip_bfloat16*)(ws + OFF_H);
  __hip_bfloat16* ctxb = (__hip_bfloat16*)(ws + OFF_CTX);
  __hip_bfloat16* a1b  = (__hip_bfloat16*)(ws + OFF_A1B);
  float* y1   = (float*)(ws + OFF_Y1);
  float* y2   = (float*)(ws + OFF_Y2);
  float* f2p  = (float*)(ws + OFF_WQ);   // FFN2 split-K partial 1 (weights dead)
  float* bqkv = (float*)(ws + OFF_Y2);   // 24KB concat bias; dead before Wo writes y2

  // conversions: x + wq/wk/wv/wo + bias concat (wi/wo2 handled inside attn)
  cvt_all<<<2048, 256, 0, stream>>>(x, wq, wk, wv, wo, bq, bk, bv, wqb, bqkv);

  dim3 blk(512);
  // fused QKV projection: M=4096, N=6144, K=2048 -> grid 24*16 = 384
  gemm256<0><<<dim3(384), blk, 0, stream>>>(
      xb, wqb, bqkv, nullptr, nullptr, qb, kM, 6144, kD, kD);
  // attention (256 blocks, 2 q-tiles each) + wi/wo2 conversion
  attn_fwd<<<dim3(256), dim3(512), 0, stream>>>(qb, kb2, vb2, mask, ctxb, wi, wo2, wqb);
  // out proj, split-K x2 (grid 256), partials y1,y2; LN1 fuses +bo+x
  gemm256<3><<<dim3(256), blk, 0, stream>>>(
      ctxb, wob, nullptr, y1, y2, nullptr, kM, kD, kD, kD / 2);
  ln_fuse<true><<<kM, 256, 0, stream>>>(y1, y2, bo, x, l1w, l1b, y1, a1b);
  // FFN1: grid 32*16 = 512, GELU epilogue
  gemm256<2><<<dim3(512), blk, 0, stream>>>(
      a1b, wib, bi, nullptr, nullptr, hb, kM, kF, kD, kD);
  // FFN2: split-K x2 (grid 256), partials y2,f2p; LN2 fuses +bo2+attn_out(y1)
  gemm256<3><<<dim3(256), blk, 0, stream>>>(
      hb, wo2b, nullptr, y2, f2p, nullptr, kM, kD, kF, kF / 2);
  ln_fuse<false><<<kM, 256, 0, stream>>>(y2, f2p, bo2, y1, l2w, l2b, (float*)d_out, nullptr);
}

// Round 14
// 587.469 us; speedup vs baseline: 1.7632x; 1.0122x over previous
//
#include <hip/hip_runtime.h>
#include <hip/hip_bf16.h>
#include <cstdint>
#include <cstddef>

typedef __attribute__((ext_vector_type(8))) short short8;   // 8 x bf16 (4 VGPRs)
typedef __attribute__((ext_vector_type(4))) float f32x4;    // MFMA accumulator

#define DEV static __device__ __forceinline__

constexpr int kS = 1024, kD = 2048, kH = 16, kHD = 128, kF = 8192;
constexpr int kM = 4096;            // B*S rows
constexpr int kDQKV = 6144;         // row-major QKV width
constexpr float kEPS = 1e-5f;

// ---------------- workspace layout (bytes) ----------------
constexpr size_t SZ_DD   = (size_t)kD * kD * 2;    // 8 MB   bf16 DxD weight
constexpr size_t SZ_FD   = (size_t)kF * kD * 2;    // 32 MB  bf16 FxD weight
constexpr size_t SZ_MD16 = (size_t)kM * kD * 2;    // 16 MB  bf16 activation
constexpr size_t SZ_MD32 = (size_t)kM * kD * 4;    // 32 MB  f32 activation
constexpr size_t OFF_WQ  = 0;                      // wq..wo2,x contiguous bf16 region
constexpr size_t OFF_WK  = OFF_WQ + SZ_DD;
constexpr size_t OFF_WV  = OFF_WK + SZ_DD;
constexpr size_t OFF_WO  = OFF_WV + SZ_DD;
constexpr size_t OFF_WI  = OFF_WO + SZ_DD;
constexpr size_t OFF_WO2 = OFF_WI + SZ_FD;
constexpr size_t OFF_XB  = OFF_WO2 + SZ_FD;        // region reused for h later
constexpr size_t OFF_Q   = OFF_XB + SZ_MD16;       // row-major QKV [4096][6144] bf16 (48MB)
constexpr size_t OFF_H   = OFF_XB;                 // 64 MB: xb+qkv dead by FFN1
constexpr size_t OFF_CTX = OFF_Q + 3 * SZ_MD16;
constexpr size_t OFF_Y1  = OFF_CTX + SZ_MD16;      // f32
constexpr size_t OFF_A1B = OFF_Y1 + SZ_MD32;       // bf16 attn_out
constexpr size_t OFF_Y2  = OFF_A1B + SZ_MD16;      // f32 (first 24KB doubles as bqkv early)
constexpr size_t WS_NEED = OFF_Y2 + SZ_MD32;       // 256 MB total
// FFN2 second split-K partial reuses dead wq..wo region (4 x 8MB = 32MB) at OFF_WQ.

DEV void gload16(const void* g, void* l) {
  __builtin_amdgcn_global_load_lds(
      (const __attribute__((address_space(1))) unsigned int*)g,
      (__attribute__((address_space(3))) unsigned int*)l, 16, 0, 0);
}

// ------------- fp32->bf16 convert: wq,wk,wv + x + bias concat -------------
// wo/wi/wo2 conversions live INSIDE attn_fwd (overlap its latency slack).
// Dest ushort4 indices: wq..wv -> [0,3M); x -> [12M,14M).
__global__ void cvt_all(const float* __restrict__ x,  const float* __restrict__ wq,
                        const float* __restrict__ wk, const float* __restrict__ wv,
                        const float* __restrict__ bq, const float* __restrict__ bk,
                        const float* __restrict__ bv,
                        __hip_bfloat16* __restrict__ outw, float* __restrict__ bqkv) {
  constexpr int M1 = 1 << 20;          // float4 count of one DxD matrix
  constexpr int NW = 5 * M1;           // 3 DxD weights + x (2M float4)
  int stride = gridDim.x * blockDim.x;
  for (int i = blockIdx.x * blockDim.x + threadIdx.x; i < NW + 1536; i += stride) {
    if (i < NW) {
      const float* src; int off; int dst;
      if (i < 3 * M1) { src = (i < M1) ? wq : (i < 2 * M1) ? wk : wv;
                        off = i & (M1 - 1); dst = i; }
      else            { src = x; off = i - 3 * M1; dst = i + 9 * M1; }
      float4 v = reinterpret_cast<const float4*>(src)[off];
      union { ushort4 u; __hip_bfloat16 h[4]; } o;
      o.h[0] = __float2bfloat16(v.x);
      o.h[1] = __float2bfloat16(v.y);
      o.h[2] = __float2bfloat16(v.z);
      o.h[3] = __float2bfloat16(v.w);
      reinterpret_cast<ushort4*>(outw)[dst] = o.u;
    } else {
      int j = i - NW;                   // 0..1535 (512 float4 per bias)
      const float* src = (j < 512) ? bq : (j < 1024) ? bk : bv;
      reinterpret_cast<float4*>(bqkv)[j] =
          reinterpret_cast<const float4*>(src)[j & 511];
    }
  }
}

// ---------------- 256x256 GEMM (r8/r11 schedule — frozen) ----------------
// MODE 0: out bf16 = acc + bias at [row*N+col] (plain row-major; used for QKV)
// MODE 2: out bf16 = gelu(acc + bias) at [row*N+col]
// MODE 3: raw f32 partial (split-K): out0/out1 selected by split index
template <int MODE>
__global__ __launch_bounds__(512, 2)
void gemm256(const __hip_bfloat16* __restrict__ A,
             const __hip_bfloat16* __restrict__ Bt,
             const float* __restrict__ bias,
             float* __restrict__ out0, float* __restrict__ out1,
             void* __restrict__ outb,
             int M, int N, int K, int kLen) {
  __shared__ __align__(16) char lds[131072];   // A: [2][256][64]b16 @0, B: @65536
  const int tid = threadIdx.x;
  const int lane = tid & 63, w = tid >> 6;
  const int wm = w >> 2, wn = w & 3;
  const int hw = w >> 2;
  const int lg = lane >> 4, lr = lane & 15;
  const int gy = M >> 8, gx = N >> 8;
  const int nwg = gridDim.x, orig = blockIdx.x;
  const int l = (orig & 7) * (nwg >> 3) + (orig >> 3);   // XCD-chunked (nwg%8==0)
  const int tilesPer = gx * gy;
  const int spl = l / tilesPer;
  const int rem = l - spl * tilesPer;
  const int bx = rem / gy, by = rem - bx * gy;           // n-panel-major
  const int m0 = by * 256, n0 = bx * 256;
  const int k0 = spl * kLen;
  const int NT = kLen >> 6;

  const char* gs[8];
  #pragma unroll
  for (int h = 0; h < 4; ++h) {
    const __hip_bfloat16* src = (h < 2) ? A : Bt;
    const int r0 = ((h < 2) ? m0 : n0) + (h & 1) * 128;
    #pragma unroll
    for (int i = 0; i < 2; ++i) {
      int c = i * 512 + tid;
      int row = c >> 3, slot = c & 7;
      gs[h * 2 + i] =
          (const char*)(src + (size_t)(r0 + row) * K + k0 + (slot ^ (row & 7)) * 8);
    }
  }

#define STAGE(P, H, TOFF)                                                          \
  {                                                                                \
    char* dstb = lds + (((H) < 2) ? 0 : 65536) + (P) * 32768 + ((H) & 1) * 16384;  \
    gload16(gs[(H) * 2 + 0] + (TOFF) * 128, dstb + (0 * 512 + tid) * 16);          \
    gload16(gs[(H) * 2 + 1] + (TOFF) * 128, dstb + (1 * 512 + tid) * 16);          \
  }

  auto ldA = [&](int P, int qm, int mr, int kk) {
    int row = qm * 128 + wm * 64 + mr * 16 + lr;
    return *reinterpret_cast<const short8*>(
        lds + P * 32768 + row * 128 + (((kk * 4 + lg) ^ (row & 7)) * 16));
  };
  auto ldB = [&](int P, int qn, int nr, int kk) {
    int row = qn * 128 + wn * 32 + nr * 16 + lr;
    return *reinterpret_cast<const short8*>(
        lds + 65536 + P * 32768 + row * 128 + (((kk * 4 + lg) ^ (row & 7)) * 16));
  };

  f32x4 acc[4][4][2] = {};   // [phase][mi][ni]

#define MFMA_HALF(p, kk, B)                                                     \
  _Pragma("unroll")                                                             \
  for (int mi = 0; mi < 4; ++mi)                                                \
    _Pragma("unroll")                                                           \
    for (int ni = 0; ni < 2; ++ni)                                              \
      acc[p][mi][ni] = __builtin_amdgcn_mfma_f32_16x16x32_bf16(                 \
          av[kk][mi], B[kk][ni], acc[p][mi][ni], 0, 0, 0);

#define WAIT_LGKM(n)                                                            \
  asm volatile("s_waitcnt lgkmcnt(" #n ")" ::: "memory");                       \
  __builtin_amdgcn_sched_barrier(0);

#define TILE_BODY(P, PF)                                                        \
  {                                                                             \
    asm volatile("s_waitcnt vmcnt(0)" ::: "memory");                            \
    __builtin_amdgcn_s_barrier();                                               \
    _Pragma("unroll")                                                           \
    for (int i = 0; i < 4; ++i) av[0][i] = ldA(P, hw, i, 0);                    \
    _Pragma("unroll")                                                           \
    for (int i = 0; i < 2; ++i) b0[0][i] = ldB(P, hw, i, 0);                    \
    _Pragma("unroll")                                                           \
    for (int i = 0; i < 4; ++i) av[1][i] = ldA(P, hw, i, 1);                    \
    _Pragma("unroll")                                                           \
    for (int i = 0; i < 2; ++i) b0[1][i] = ldB(P, hw, i, 1);                    \
    if (PF) { STAGE((P) ^ 1, 0, 1 + (P)) STAGE((P) ^ 1, 2, 1 + (P)) }           \
    WAIT_LGKM(6)                                                                \
    __builtin_amdgcn_s_setprio(1);                                              \
    MFMA_HALF(0, 0, b0)                                                         \
    WAIT_LGKM(0)                                                                \
    MFMA_HALF(0, 1, b0)                                                         \
    __builtin_amdgcn_s_setprio(0);                                              \
    _Pragma("unroll")                                                           \
    for (int i = 0; i < 2; ++i) b1[0][i] = ldB(P, 1 - hw, i, 0);                \
    _Pragma("unroll")                                                           \
    for (int i = 0; i < 2; ++i) b1[1][i] = ldB(P, 1 - hw, i, 1);                \
    if (PF) { STAGE((P) ^ 1, 3, 1 + (P)) STAGE((P) ^ 1, 1, 1 + (P)) }           \
    WAIT_LGKM(2)                                                                \
    __builtin_amdgcn_s_setprio(1);                                              \
    MFMA_HALF(1, 0, b1)                                                         \
    WAIT_LGKM(0)                                                                \
    MFMA_HALF(1, 1, b1)                                                         \
    __builtin_amdgcn_s_setprio(0);                                              \
    _Pragma("unroll")                                                           \
    for (int i = 0; i < 4; ++i) av[0][i] = ldA(P, 1 - hw, i, 0);                \
    _Pragma("unroll")                                                           \
    for (int i = 0; i < 4; ++i) av[1][i] = ldA(P, 1 - hw, i, 1);                \
    WAIT_LGKM(4)                                                                \
    __builtin_amdgcn_s_setprio(1);                                              \
    MFMA_HALF(2, 0, b1)                                                         \
    WAIT_LGKM(0)                                                                \
    MFMA_HALF(2, 1, b1)                                                         \
    __builtin_amdgcn_s_setprio(0);                                              \
    _Pragma("unroll")                                                           \
    for (int i = 0; i < 2; ++i) b0[0][i] = ldB(P, hw, i, 0);                    \
    _Pragma("unroll")                                                           \
    for (int i = 0; i < 2; ++i) b0[1][i] = ldB(P, hw, i, 1);                    \
    WAIT_LGKM(2)                                                                \
    __builtin_amdgcn_s_setprio(1);                                              \
    MFMA_HALF(3, 0, b0)                                                         \
    WAIT_LGKM(0)                                                                \
    MFMA_HALF(3, 1, b0)                                                         \
    __builtin_amdgcn_s_setprio(0);                                              \
  }

  STAGE(0, 0, 0) STAGE(0, 2, 0) STAGE(0, 3, 0) STAGE(0, 1, 0)

  for (int t2 = 0; t2 < NT; t2 += 2) {
    short8 av[2][4], b0[2][2], b1[2][2];
    TILE_BODY(0, true)
    TILE_BODY(1, (t2 + 2 < NT))
    #pragma unroll
    for (int j = 0; j < 8; ++j) gs[j] += 256;
  }
#undef TILE_BODY
#undef MFMA_HALF
#undef WAIT_LGKM
#undef STAGE

  // epilogue: p0:(hw,hw) p1:(hw,1-hw) p2:(1-hw,1-hw) p3:(1-hw,hw)
  #pragma unroll
  for (int p = 0; p < 4; ++p) {
    const int qm = (p < 2) ? hw : 1 - hw;
    const int qn = (p == 0 || p == 3) ? hw : 1 - hw;
    #pragma unroll
    for (int ni = 0; ni < 2; ++ni) {
      int col = n0 + qn * 128 + wn * 32 + ni * 16 + lr;
      float bvv = 0.f;
      if constexpr (MODE != 3) bvv = bias[col];
      #pragma unroll
      for (int mi = 0; mi < 4; ++mi) {
        int row0 = m0 + qm * 128 + wm * 64 + mi * 16 + lg * 4;
        #pragma unroll
        for (int r = 0; r < 4; ++r) {
          int row = row0 + r;
          float val = acc[p][mi][ni][r] + bvv;
          if constexpr (MODE == 0) {
            ((__hip_bfloat16*)outb)[(size_t)row * N + col] = __float2bfloat16(val);
          } else if constexpr (MODE == 2) {
            float g = 0.5f * val * (1.0f + erff(val * 0.70710678118654752f));
            ((__hip_bfloat16*)outb)[(size_t)row * N + col] = __float2bfloat16(g);
          } else {
            float* o = spl ? out1 : out0;
            o[(size_t)row * N + col] = val;
          }
        }
      }
    }
  }
}

// ------- flash attention — row-major QKV input; 2 q-tiles/block; wo/wi/wo2 cvt -------
// QKV buffer is [row][6144] bf16 (q|k|v each 2048 wide; head h at col h*128).
// 256 blocks; each owns 256 q-rows of one bh, streams K/V once. Interleaved
// fp32->bf16 conversion of wo (1M float4) + wi/wo2 (8M float4) spread over
// blocks x 16 tiles, issued in attention's latency slack. Consumers (Wo GEMM,
// FFN1/FFN2) launch after attn — stream order guarantees completion.
__global__ __launch_bounds__(512, 2)
void attn_fwd(const __hip_bfloat16* __restrict__ qkv,
              const float* __restrict__ mask,
              __hip_bfloat16* __restrict__ ctx,
              const float* __restrict__ wo,
              const float* __restrict__ wi, const float* __restrict__ wo2,
              __hip_bfloat16* __restrict__ outw /* ushort4: wo@3M, wi@4M, wo2@8M */) {
  __shared__ __align__(16) char Ks[2][64 * 256];    // [buf][key][dim] slot16^(row&15)
  __shared__ __align__(16) char Vt[2][128 * 128];   // [buf][hd][key64] slot8^(hd&7)
  __shared__ __align__(16) char Ps[8][2048];        // per-wave P [16][64], ^((row&7)<<4)
  const int tid = threadIdx.x, lane = tid & 63, w = tid >> 6;
  const int lg = lane >> 4, lr = lane & 15;
  const int orig = blockIdx.x;                      // 256 blocks
  const int l = (orig & 7) * 32 + (orig >> 3);      // XCD-chunked: 8 bh per XCD
  const int qp = l & 3, bh = l >> 2;                // q-pair 0..3, bh 0..63
  const int b = bh >> 4, h = bh & 15;
  const int s4 = tid >> 5, hd4 = tid & 31;          // V-transpose role
  const size_t rb = (size_t)b * kS;                 // global row base
  const int hc = h * kHD;                           // head column offset

  short8 qf[2][4];
  #pragma unroll
  for (int s = 0; s < 2; ++s) {
    const __hip_bfloat16* qp_ =
        qkv + (rb + qp * 256 + s * 128 + w * 16 + lr) * kDQKV + hc + lg * 8;
    #pragma unroll
    for (int kk = 0; kk < 4; ++kk)
      qf[s][kk] = *reinterpret_cast<const short8*>(qp_ + kk * 32);
  }

  auto stageK = [&](int bufi, int t) {
    #pragma unroll
    for (int i = 0; i < 2; ++i) {                   // K tile: 64 rows x 256B
      int c = i * 512 + tid;
      int row = c >> 4, slot = c & 15;
      gload16(qkv + (rb + t * 64 + row) * kDQKV + kD + hc + (slot ^ (row & 15)) * 8,
              Ks[bufi] + c * 16);
    }
  };
  union VU { uint2 u; ushort s[4]; };
  VU vr[4];
  auto loadV = [&](int t) {
    #pragma unroll
    for (int i = 0; i < 4; ++i)
      vr[i].u = *reinterpret_cast<const uint2*>(
          qkv + (rb + t * 64 + s4 * 4 + i) * kDQKV + 2 * kD + hc + hd4 * 4);
  };
  auto writeV = [&](int bufi) {
    #pragma unroll
    for (int j = 0; j < 4; ++j) {
      int hd = hd4 * 4 + j;
      ushort4 o4;
      o4.x = vr[0].s[j]; o4.y = vr[1].s[j]; o4.z = vr[2].s[j]; o4.w = vr[3].s[j];
      *reinterpret_cast<ushort4*>(
          Vt[bufi] + hd * 128 + (((s4 >> 1) ^ (hd & 7)) << 4) + ((s4 & 1) << 3)) = o4;
    }
  };
  // interleaved weight conversion: 4 float4 (wi|wo2) + up to 1 float4 (wo) per slot
  float4 cw[4]; float4 cwo;
  auto cvLoad = [&](int t) {
    int g0 = ((orig * 16 + t) * 512 + tid) * 4;     // 0..8M-4
    #pragma unroll
    for (int j = 0; j < 4; ++j) {
      int g = g0 + j;
      const float* src = (g < (4 << 20)) ? wi : wo2;
      int off = g & ((4 << 20) - 1);
      cw[j] = reinterpret_cast<const float4*>(src)[off];
    }
    int slot = (orig * 16 + t) * 512 + tid;         // 0..2M-1
    if (slot < (1 << 20)) cwo = reinterpret_cast<const float4*>(wo)[slot];
  };
  auto cvStore = [&](int t) {
    int g0 = ((orig * 16 + t) * 512 + tid) * 4;
    #pragma unroll
    for (int j = 0; j < 4; ++j) {
      union { ushort4 u; __hip_bfloat16 hh[4]; } o4;
      o4.hh[0] = __float2bfloat16(cw[j].x);
      o4.hh[1] = __float2bfloat16(cw[j].y);
      o4.hh[2] = __float2bfloat16(cw[j].z);
      o4.hh[3] = __float2bfloat16(cw[j].w);
      reinterpret_cast<ushort4*>(outw)[(4 << 20) + g0 + j] = o4.u;
    }
    int slot = (orig * 16 + t) * 512 + tid;
    if (slot < (1 << 20)) {
      union { ushort4 u; __hip_bfloat16 hh[4]; } o4;
      o4.hh[0] = __float2bfloat16(cwo.x);
      o4.hh[1] = __float2bfloat16(cwo.y);
      o4.hh[2] = __float2bfloat16(cwo.z);
      o4.hh[3] = __float2bfloat16(cwo.w);
      reinterpret_cast<ushort4*>(outw)[(3 << 20) + slot] = o4.u;
    }
  };

  f32x4 o[2][8] = {};
  float mrun[2][4], lrun[2][4];
  #pragma unroll
  for (int s = 0; s < 2; ++s)
    #pragma unroll
    for (int r = 0; r < 4; ++r) { mrun[s][r] = -1e30f; lrun[s][r] = 0.f; }
  const float scale = 0.08838834764831845f;         // 1/sqrt(128)

  stageK(0, 0);
  loadV(0);
  writeV(0);
  __syncthreads();

  int buf = 0;
  for (int t = 0; t < 16; ++t) {
    if (t + 1 < 16) { stageK(buf ^ 1, t + 1); loadV(t + 1); }
    cvLoad(t);                                      // fp32 weight chunk in flight

    float mv[4];
    #pragma unroll
    for (int j = 0; j < 4; ++j) mv[j] = mask[(size_t)b * kS + t * 64 + j * 16 + lr];

    #pragma unroll
    for (int s = 0; s < 2; ++s) {
      f32x4 sacc[4] = {};
      #pragma unroll
      for (int j = 0; j < 4; ++j) {
        int key = j * 16 + lr;
        #pragma unroll
        for (int kk = 0; kk < 4; ++kk) {
          short8 bfrag = *reinterpret_cast<const short8*>(
              Ks[buf] + key * 256 + (((kk * 4 + lg) ^ (key & 15)) * 16));
          sacc[j] = __builtin_amdgcn_mfma_f32_16x16x32_bf16(qf[s][kk], bfrag, sacc[j], 0, 0, 0);
        }
      }
      float sarr[4][4];
      #pragma unroll
      for (int j = 0; j < 4; ++j)
        #pragma unroll
        for (int r = 0; r < 4; ++r) sarr[j][r] = sacc[j][r] * scale + mv[j];
      #pragma unroll
      for (int r = 0; r < 4; ++r) {
        float tm = fmaxf(fmaxf(sarr[0][r], sarr[1][r]), fmaxf(sarr[2][r], sarr[3][r]));
        #pragma unroll
        for (int d = 1; d < 16; d <<= 1) tm = fmaxf(tm, __shfl_xor(tm, d));
        float mnew = fmaxf(mrun[s][r], tm);
        float alpha = __expf(mrun[s][r] - mnew);
        mrun[s][r] = mnew;
        float rs = 0.f;
        #pragma unroll
        for (int j = 0; j < 4; ++j) {
          float p = __expf(sarr[j][r] - mnew);
          sarr[j][r] = p;
          rs += p;
        }
        #pragma unroll
        for (int d = 1; d < 16; d <<= 1) rs += __shfl_xor(rs, d);
        lrun[s][r] = lrun[s][r] * alpha + rs;
        #pragma unroll
        for (int n = 0; n < 8; ++n) o[s][n][r] *= alpha;
      }
      #pragma unroll
      for (int r = 0; r < 4; ++r) {
        int qr = lg * 4 + r;
        #pragma unroll
        for (int j = 0; j < 4; ++j)
          *reinterpret_cast<__hip_bfloat16*>(
              Ps[w] + ((qr * 128 + (j * 16 + lr) * 2) ^ ((qr & 7) << 4))) =
              __float2bfloat16(sarr[j][r]);
      }
      #pragma unroll
      for (int kk2 = 0; kk2 < 2; ++kk2) {
        short8 pa = *reinterpret_cast<const short8*>(
            Ps[w] + ((lr * 128 + kk2 * 64 + lg * 16) ^ ((lr & 7) << 4)));
        #pragma unroll
        for (int n = 0; n < 8; ++n) {
          int hd = n * 16 + lr;
          short8 vb = *reinterpret_cast<const short8*>(
              Vt[buf] + hd * 128 + (((kk2 * 4 + lg) ^ (hd & 7)) * 16));
          o[s][n] = __builtin_amdgcn_mfma_f32_16x16x32_bf16(pa, vb, o[s][n], 0, 0, 0);
        }
      }
    }
    cvStore(t);                                     // convert + store (auto-waits cw)
    if (t + 1 < 16) writeV(buf ^ 1);
    __syncthreads();
    buf ^= 1;
  }

  #pragma unroll
  for (int s = 0; s < 2; ++s)
    #pragma unroll
    for (int r = 0; r < 4; ++r) {
      float inv = 1.0f / lrun[s][r];
      int srow = qp * 256 + s * 128 + w * 16 + lg * 4 + r;
      __hip_bfloat16* cp = ctx + (rb + srow) * kD + hc + lr;
      #pragma unroll
      for (int n = 0; n < 8; ++n) cp[n * 16] = __float2bfloat16(o[s][n][r] * inv);
    }
}

// ------- LayerNorm over (p0 + p1 + bias + res), one 2048-row per block -------
template <bool WB16>
__global__ void ln_fuse(const float* __restrict__ p0, const float* __restrict__ p1,
                        const float* __restrict__ bias, const float* __restrict__ res,
                        const float* __restrict__ w, const float* __restrict__ b,
                        float* __restrict__ outf, __hip_bfloat16* __restrict__ outb) {
  const int row = blockIdx.x, tid = threadIdx.x;
  const size_t base = (size_t)row * kD;
  float v[8];
  #pragma unroll
  for (int i = 0; i < 2; ++i) {
    int c4 = tid * 2 + i;
    float4 a  = reinterpret_cast<const float4*>(p0 + base)[c4];
    float4 bb = reinterpret_cast<const float4*>(p1 + base)[c4];
    float4 rr = reinterpret_cast<const float4*>(res + base)[c4];
    float4 bs = reinterpret_cast<const float4*>(bias)[c4];
    v[i * 4 + 0] = a.x + bb.x + rr.x + bs.x;
    v[i * 4 + 1] = a.y + bb.y + rr.y + bs.y;
    v[i * 4 + 2] = a.z + bb.z + rr.z + bs.z;
    v[i * 4 + 3] = a.w + bb.w + rr.w + bs.w;
  }
  float s = 0.f;
  #pragma unroll
  for (int i = 0; i < 8; ++i) s += v[i];
  #pragma unroll
  for (int off = 32; off > 0; off >>= 1) s += __shfl_down(s, off);
  __shared__ float r1[4], r2[4];
  if ((tid & 63) == 0) r1[tid >> 6] = s;
  __syncthreads();
  float mean = (r1[0] + r1[1] + r1[2] + r1[3]) * (1.0f / kD);
  float qv = 0.f;
  #pragma unroll
  for (int i = 0; i < 8; ++i) { float d = v[i] - mean; qv += d * d; }
  #pragma unroll
  for (int off = 32; off > 0; off >>= 1) qv += __shfl_down(qv, off);
  if ((tid & 63) == 0) r2[tid >> 6] = qv;
  __syncthreads();
  float rstd = rsqrtf((r2[0] + r2[1] + r2[2] + r2[3]) * (1.0f / kD) + kEPS);
  #pragma unroll
  for (int i = 0; i < 8; ++i) {
    int col = tid * 8 + i;
    float ov = (v[i] - mean) * rstd * w[col] + b[col];
    outf[base + col] = ov;
    if constexpr (WB16) outb[base + col] = __float2bfloat16(ov);
  }
}

// ---------------- launcher ----------------
extern "C" void kernel_launch(void* const* d_in, const int* in_sizes, int n_in,
                              void* d_out, int out_size, void* d_ws, size_t ws_size,
                              hipStream_t stream) {
  (void)in_sizes; (void)n_in; (void)out_size;
  if (ws_size < WS_NEED) return;
  const float* x    = (const float*)d_in[0];
  const float* mask = (const float*)d_in[1];
  const float* wq   = (const float*)d_in[2];
  const float* bq   = (const float*)d_in[3];
  const float* wk   = (const float*)d_in[4];
  const float* bk   = (const float*)d_in[5];
  const float* wv   = (const float*)d_in[6];
  const float* bv   = (const float*)d_in[7];
  const float* wo   = (const float*)d_in[8];
  const float* bo   = (const float*)d_in[9];
  const float* l1w  = (const float*)d_in[10];
  const float* l1b  = (const float*)d_in[11];
  const float* wi   = (const float*)d_in[12];
  const float* bi   = (const float*)d_in[13];
  const float* wo2  = (const float*)d_in[14];
  const float* bo2  = (const float*)d_in[15];
  const float* l2w  = (const float*)d_in[16];
  const float* l2b  = (const float*)d_in[17];

  char* ws = (char*)d_ws;
  __hip_bfloat16* wqb  = (__hip_bfloat16*)(ws + OFF_WQ);
  __hip_bfloat16* wob  = (__hip_bfloat16*)(ws + OFF_WO);
  __hip_bfloat16* wib  = (__hip_bfloat16*)(ws + OFF_WI);
  __hip_bfloat16* wo2b = (__hip_bfloat16*)(ws + OFF_WO2);
  __hip_bfloat16* xb   = (__hip_bfloat16*)(ws + OFF_XB);
  __hip_bfloat16* qkvb = (__hip_bfloat16*)(ws + OFF_Q);    // [4096][6144]
  __hip_bfloat16* hb   = (__hip_bfloat16*)(ws + OFF_H);
  __hip_bfloat16* ctxb = (__hip_bfloat16*)(ws + OFF_CTX);
  __hip_bfloat16* a1b  = (__hip_bfloat16*)(ws + OFF_A1B);
  float* y1   = (float*)(ws + OFF_Y1);
  float* y2   = (float*)(ws + OFF_Y2);
  float* f2p  = (float*)(ws + OFF_WQ);   // FFN2 split-K partial 1 (weights dead)
  float* bqkv = (float*)(ws + OFF_Y2);   // 24KB concat bias; dead before Wo writes y2

  // conversions: x + wq/wk/wv + bias concat (wo/wi/wo2 handled inside attn)
  cvt_all<<<2048, 256, 0, stream>>>(x, wq, wk, wv, bq, bk, bv, wqb, bqkv);

  dim3 blk(512);
  // fused QKV projection: M=4096, N=6144, K=2048 -> grid 384, row-major out
  gemm256<0><<<dim3(384), blk, 0, stream>>>(
      xb, wqb, bqkv, nullptr, nullptr, qkvb, kM, kDQKV, kD, kD);
  // attention (256 blocks, 2 q-tiles each) + wo/wi/wo2 conversion
  attn_fwd<<<dim3(256), dim3(512), 0, stream>>>(qkvb, mask, ctxb, wo, wi, wo2, wqb);
  // out proj, split-K x2 (grid 256), partials y1,y2; LN1 fuses +bo+x
  gemm256<3><<<dim3(256), blk, 0, stream>>>(
      ctxb, wob, nullptr, y1, y2, nullptr, kM, kD, kD, kD / 2);
  ln_fuse<true><<<kM, 256, 0, stream>>>(y1, y2, bo, x, l1w, l1b, y1, a1b);
  // FFN1: grid 32*16 = 512, GELU epilogue
  gemm256<2><<<dim3(512), blk, 0, stream>>>(
      a1b, wib, bi, nullptr, nullptr, hb, kM, kF, kD, kD);
  // FFN2: split-K x2 (grid 256), partials y2,f2p; LN2 fuses +bo2+attn_out(y1)
  gemm256<3><<<dim3(256), blk, 0, stream>>>(
      hb, wo2b, nullptr, y2, f2p, nullptr, kM, kD, kF, kF / 2);
  ln_fuse<false><<<kM, 256, 0, stream>>>(y2, f2p, bo2, y1, l2w, l2b, (float*)d_out, nullptr);
}

// Round 15
// 574.233 us; speedup vs baseline: 1.8038x; 1.0230x over previous
//
#include <hip/hip_runtime.h>
#include <hip/hip_bf16.h>
#include <cstdint>
#include <cstddef>

typedef __attribute__((ext_vector_type(8))) short short8;   // 8 x bf16 (4 VGPRs)
typedef __attribute__((ext_vector_type(4))) float f32x4;    // MFMA accumulator

#define DEV static __device__ __forceinline__

constexpr int kS = 1024, kD = 2048, kH = 16, kHD = 128, kF = 8192;
constexpr int kM = 4096;            // B*S rows
constexpr int kDQKV = 6144;         // row-major QKV width
constexpr float kEPS = 1e-5f;

// ---------------- workspace layout (bytes) ----------------
constexpr size_t SZ_DD   = (size_t)kD * kD * 2;    // 8 MB   bf16 DxD weight
constexpr size_t SZ_FD   = (size_t)kF * kD * 2;    // 32 MB  bf16 FxD weight
constexpr size_t SZ_MD16 = (size_t)kM * kD * 2;    // 16 MB  bf16 activation
constexpr size_t SZ_MD32 = (size_t)kM * kD * 4;    // 32 MB  f32 activation
constexpr size_t OFF_WQ  = 0;                      // wq..wo2,x contiguous bf16 region
constexpr size_t OFF_WK  = OFF_WQ + SZ_DD;
constexpr size_t OFF_WV  = OFF_WK + SZ_DD;
constexpr size_t OFF_WO  = OFF_WV + SZ_DD;
constexpr size_t OFF_WI  = OFF_WO + SZ_DD;
constexpr size_t OFF_WO2 = OFF_WI + SZ_FD;
constexpr size_t OFF_XB  = OFF_WO2 + SZ_FD;        // region reused for h later
constexpr size_t OFF_Q   = OFF_XB + SZ_MD16;       // row-major QKV [4096][6144] bf16 (48MB)
constexpr size_t OFF_H   = OFF_XB;                 // 64 MB: xb+qkv dead by FFN1
constexpr size_t OFF_CTX = OFF_Q + 3 * SZ_MD16;
constexpr size_t OFF_Y1  = OFF_CTX + SZ_MD16;      // f32 attn_out (LN1 output)
constexpr size_t OFF_A1B = OFF_Y1 + SZ_MD32;       // bf16 attn_out
constexpr size_t OFF_Y2  = OFF_A1B + SZ_MD16;      // Wo bf16 partials (2x16MB); bqkv early
constexpr size_t WS_NEED = OFF_Y2 + SZ_MD32;       // 256 MB total
// FFN2 bf16 partials (2x16MB) reuse dead wq..wo region at OFF_WQ.

DEV void gload16(const void* g, void* l) {
  __builtin_amdgcn_global_load_lds(
      (const __attribute__((address_space(1))) unsigned int*)g,
      (__attribute__((address_space(3))) unsigned int*)l, 16, 0, 0);
}

DEV float b2f(short s) {
  union { unsigned u; float f; } x;
  x.u = ((unsigned)(unsigned short)s) << 16;
  return x.f;
}

// ------------- fp32->bf16 convert: wq,wk,wv + x + bias concat -------------
// wo/wi/wo2 conversions live INSIDE attn_fwd (overlap its latency slack).
// Dest ushort4 indices: wq..wv -> [0,3M); x -> [12M,14M).
__global__ void cvt_all(const float* __restrict__ x,  const float* __restrict__ wq,
                        const float* __restrict__ wk, const float* __restrict__ wv,
                        const float* __restrict__ bq, const float* __restrict__ bk,
                        const float* __restrict__ bv,
                        __hip_bfloat16* __restrict__ outw, float* __restrict__ bqkv) {
  constexpr int M1 = 1 << 20;          // float4 count of one DxD matrix
  constexpr int NW = 5 * M1;           // 3 DxD weights + x (2M float4)
  int stride = gridDim.x * blockDim.x;
  for (int i = blockIdx.x * blockDim.x + threadIdx.x; i < NW + 1536; i += stride) {
    if (i < NW) {
      const float* src; int off; int dst;
      if (i < 3 * M1) { src = (i < M1) ? wq : (i < 2 * M1) ? wk : wv;
                        off = i & (M1 - 1); dst = i; }
      else            { src = x; off = i - 3 * M1; dst = i + 9 * M1; }
      float4 v = reinterpret_cast<const float4*>(src)[off];
      union { ushort4 u; __hip_bfloat16 h[4]; } o;
      o.h[0] = __float2bfloat16(v.x);
      o.h[1] = __float2bfloat16(v.y);
      o.h[2] = __float2bfloat16(v.z);
      o.h[3] = __float2bfloat16(v.w);
      reinterpret_cast<ushort4*>(outw)[dst] = o.u;
    } else {
      int j = i - NW;                   // 0..1535 (512 float4 per bias)
      const float* src = (j < 512) ? bq : (j < 1024) ? bk : bv;
      reinterpret_cast<float4*>(bqkv)[j] =
          reinterpret_cast<const float4*>(src)[j & 511];
    }
  }
}

// ---------------- 256x256 GEMM (r8/r11 schedule — frozen) ----------------
// MODE 0: out bf16 = acc + bias at [row*N+col] (plain row-major; used for QKV)
// MODE 2: out bf16 = gelu(acc + bias) at [row*N+col]
// MODE 3: bf16 partial (split-K): out0/out1 selected by split index
template <int MODE>
__global__ __launch_bounds__(512, 2)
void gemm256(const __hip_bfloat16* __restrict__ A,
             const __hip_bfloat16* __restrict__ Bt,
             const float* __restrict__ bias,
             __hip_bfloat16* __restrict__ out0, __hip_bfloat16* __restrict__ out1,
             void* __restrict__ outb,
             int M, int N, int K, int kLen) {
  __shared__ __align__(16) char lds[131072];   // A: [2][256][64]b16 @0, B: @65536
  const int tid = threadIdx.x;
  const int lane = tid & 63, w = tid >> 6;
  const int wm = w >> 2, wn = w & 3;
  const int hw = w >> 2;
  const int lg = lane >> 4, lr = lane & 15;
  const int gy = M >> 8, gx = N >> 8;
  const int nwg = gridDim.x, orig = blockIdx.x;
  const int l = (orig & 7) * (nwg >> 3) + (orig >> 3);   // XCD-chunked (nwg%8==0)
  const int tilesPer = gx * gy;
  const int spl = l / tilesPer;
  const int rem = l - spl * tilesPer;
  const int bx = rem / gy, by = rem - bx * gy;           // n-panel-major
  const int m0 = by * 256, n0 = bx * 256;
  const int k0 = spl * kLen;
  const int NT = kLen >> 6;

  const char* gs[8];
  #pragma unroll
  for (int h = 0; h < 4; ++h) {
    const __hip_bfloat16* src = (h < 2) ? A : Bt;
    const int r0 = ((h < 2) ? m0 : n0) + (h & 1) * 128;
    #pragma unroll
    for (int i = 0; i < 2; ++i) {
      int c = i * 512 + tid;
      int row = c >> 3, slot = c & 7;
      gs[h * 2 + i] =
          (const char*)(src + (size_t)(r0 + row) * K + k0 + (slot ^ (row & 7)) * 8);
    }
  }

#define STAGE(P, H, TOFF)                                                          \
  {                                                                                \
    char* dstb = lds + (((H) < 2) ? 0 : 65536) + (P) * 32768 + ((H) & 1) * 16384;  \
    gload16(gs[(H) * 2 + 0] + (TOFF) * 128, dstb + (0 * 512 + tid) * 16);          \
    gload16(gs[(H) * 2 + 1] + (TOFF) * 128, dstb + (1 * 512 + tid) * 16);          \
  }

  auto ldA = [&](int P, int qm, int mr, int kk) {
    int row = qm * 128 + wm * 64 + mr * 16 + lr;
    return *reinterpret_cast<const short8*>(
        lds + P * 32768 + row * 128 + (((kk * 4 + lg) ^ (row & 7)) * 16));
  };
  auto ldB = [&](int P, int qn, int nr, int kk) {
    int row = qn * 128 + wn * 32 + nr * 16 + lr;
    return *reinterpret_cast<const short8*>(
        lds + 65536 + P * 32768 + row * 128 + (((kk * 4 + lg) ^ (row & 7)) * 16));
  };

  f32x4 acc[4][4][2] = {};   // [phase][mi][ni]

#define MFMA_HALF(p, kk, B)                                                     \
  _Pragma("unroll")                                                             \
  for (int mi = 0; mi < 4; ++mi)                                                \
    _Pragma("unroll")                                                           \
    for (int ni = 0; ni < 2; ++ni)                                              \
      acc[p][mi][ni] = __builtin_amdgcn_mfma_f32_16x16x32_bf16(                 \
          av[kk][mi], B[kk][ni], acc[p][mi][ni], 0, 0, 0);

#define WAIT_LGKM(n)                                                            \
  asm volatile("s_waitcnt lgkmcnt(" #n ")" ::: "memory");                       \
  __builtin_amdgcn_sched_barrier(0);

#define TILE_BODY(P, PF)                                                        \
  {                                                                             \
    asm volatile("s_waitcnt vmcnt(0)" ::: "memory");                            \
    __builtin_amdgcn_s_barrier();                                               \
    _Pragma("unroll")                                                           \
    for (int i = 0; i < 4; ++i) av[0][i] = ldA(P, hw, i, 0);                    \
    _Pragma("unroll")                                                           \
    for (int i = 0; i < 2; ++i) b0[0][i] = ldB(P, hw, i, 0);                    \
    _Pragma("unroll")                                                           \
    for (int i = 0; i < 4; ++i) av[1][i] = ldA(P, hw, i, 1);                    \
    _Pragma("unroll")                                                           \
    for (int i = 0; i < 2; ++i) b0[1][i] = ldB(P, hw, i, 1);                    \
    if (PF) { STAGE((P) ^ 1, 0, 1 + (P)) STAGE((P) ^ 1, 2, 1 + (P)) }           \
    WAIT_LGKM(6)                                                                \
    __builtin_amdgcn_s_setprio(1);                                              \
    MFMA_HALF(0, 0, b0)                                                         \
    WAIT_LGKM(0)                                                                \
    MFMA_HALF(0, 1, b0)                                                         \
    __builtin_amdgcn_s_setprio(0);                                              \
    _Pragma("unroll")                                                           \
    for (int i = 0; i < 2; ++i) b1[0][i] = ldB(P, 1 - hw, i, 0);                \
    _Pragma("unroll")                                                           \
    for (int i = 0; i < 2; ++i) b1[1][i] = ldB(P, 1 - hw, i, 1);                \
    if (PF) { STAGE((P) ^ 1, 3, 1 + (P)) STAGE((P) ^ 1, 1, 1 + (P)) }           \
    WAIT_LGKM(2)                                                                \
    __builtin_amdgcn_s_setprio(1);                                              \
    MFMA_HALF(1, 0, b1)                                                         \
    WAIT_LGKM(0)                                                                \
    MFMA_HALF(1, 1, b1)                                                         \
    __builtin_amdgcn_s_setprio(0);                                              \
    _Pragma("unroll")                                                           \
    for (int i = 0; i < 4; ++i) av[0][i] = ldA(P, 1 - hw, i, 0);                \
    _Pragma("unroll")                                                           \
    for (int i = 0; i < 4; ++i) av[1][i] = ldA(P, 1 - hw, i, 1);                \
    WAIT_LGKM(4)                                                                \
    __builtin_amdgcn_s_setprio(1);                                              \
    MFMA_HALF(2, 0, b1)                                                         \
    WAIT_LGKM(0)                                                                \
    MFMA_HALF(2, 1, b1)                                                         \
    __builtin_amdgcn_s_setprio(0);                                              \
    _Pragma("unroll")                                                           \
    for (int i = 0; i < 2; ++i) b0[0][i] = ldB(P, hw, i, 0);                    \
    _Pragma("unroll")                                                           \
    for (int i = 0; i < 2; ++i) b0[1][i] = ldB(P, hw, i, 1);                    \
    WAIT_LGKM(2)                                                                \
    __builtin_amdgcn_s_setprio(1);                                              \
    MFMA_HALF(3, 0, b0)                                                         \
    WAIT_LGKM(0)                                                                \
    MFMA_HALF(3, 1, b0)                                                         \
    __builtin_amdgcn_s_setprio(0);                                              \
  }

  STAGE(0, 0, 0) STAGE(0, 2, 0) STAGE(0, 3, 0) STAGE(0, 1, 0)

  for (int t2 = 0; t2 < NT; t2 += 2) {
    short8 av[2][4], b0[2][2], b1[2][2];
    TILE_BODY(0, true)
    TILE_BODY(1, (t2 + 2 < NT))
    #pragma unroll
    for (int j = 0; j < 8; ++j) gs[j] += 256;
  }
#undef TILE_BODY
#undef MFMA_HALF
#undef WAIT_LGKM
#undef STAGE

  // epilogue: p0:(hw,hw) p1:(hw,1-hw) p2:(1-hw,1-hw) p3:(1-hw,hw)
  #pragma unroll
  for (int p = 0; p < 4; ++p) {
    const int qm = (p < 2) ? hw : 1 - hw;
    const int qn = (p == 0 || p == 3) ? hw : 1 - hw;
    #pragma unroll
    for (int ni = 0; ni < 2; ++ni) {
      int col = n0 + qn * 128 + wn * 32 + ni * 16 + lr;
      float bvv = 0.f;
      if constexpr (MODE != 3) bvv = bias[col];
      #pragma unroll
      for (int mi = 0; mi < 4; ++mi) {
        int row0 = m0 + qm * 128 + wm * 64 + mi * 16 + lg * 4;
        #pragma unroll
        for (int r = 0; r < 4; ++r) {
          int row = row0 + r;
          float val = acc[p][mi][ni][r] + bvv;
          if constexpr (MODE == 0) {
            ((__hip_bfloat16*)outb)[(size_t)row * N + col] = __float2bfloat16(val);
          } else if constexpr (MODE == 2) {
            float g = 0.5f * val * (1.0f + erff(val * 0.70710678118654752f));
            ((__hip_bfloat16*)outb)[(size_t)row * N + col] = __float2bfloat16(g);
          } else {
            __hip_bfloat16* o = spl ? out1 : out0;
            o[(size_t)row * N + col] = __float2bfloat16(val);
          }
        }
      }
    }
  }
}

// ------- flash attention — row-major QKV input; 2 q-tiles/block; wo/wi/wo2 cvt -------
__global__ __launch_bounds__(512, 2)
void attn_fwd(const __hip_bfloat16* __restrict__ qkv,
              const float* __restrict__ mask,
              __hip_bfloat16* __restrict__ ctx,
              const float* __restrict__ wo,
              const float* __restrict__ wi, const float* __restrict__ wo2,
              __hip_bfloat16* __restrict__ outw /* ushort4: wo@3M, wi@4M, wo2@8M */) {
  __shared__ __align__(16) char Ks[2][64 * 256];    // [buf][key][dim] slot16^(row&15)
  __shared__ __align__(16) char Vt[2][128 * 128];   // [buf][hd][key64] slot8^(hd&7)
  __shared__ __align__(16) char Ps[8][2048];        // per-wave P [16][64], ^((row&7)<<4)
  const int tid = threadIdx.x, lane = tid & 63, w = tid >> 6;
  const int lg = lane >> 4, lr = lane & 15;
  const int orig = blockIdx.x;                      // 256 blocks
  const int l = (orig & 7) * 32 + (orig >> 3);      // XCD-chunked: 8 bh per XCD
  const int qp = l & 3, bh = l >> 2;                // q-pair 0..3, bh 0..63
  const int b = bh >> 4, h = bh & 15;
  const int s4 = tid >> 5, hd4 = tid & 31;          // V-transpose role
  const size_t rb = (size_t)b * kS;                 // global row base
  const int hc = h * kHD;                           // head column offset

  short8 qf[2][4];
  #pragma unroll
  for (int s = 0; s < 2; ++s) {
    const __hip_bfloat16* qp_ =
        qkv + (rb + qp * 256 + s * 128 + w * 16 + lr) * kDQKV + hc + lg * 8;
    #pragma unroll
    for (int kk = 0; kk < 4; ++kk)
      qf[s][kk] = *reinterpret_cast<const short8*>(qp_ + kk * 32);
  }

  auto stageK = [&](int bufi, int t) {
    #pragma unroll
    for (int i = 0; i < 2; ++i) {                   // K tile: 64 rows x 256B
      int c = i * 512 + tid;
      int row = c >> 4, slot = c & 15;
      gload16(qkv + (rb + t * 64 + row) * kDQKV + kD + hc + (slot ^ (row & 15)) * 8,
              Ks[bufi] + c * 16);
    }
  };
  union VU { uint2 u; ushort s[4]; };
  VU vr[4];
  auto loadV = [&](int t) {
    #pragma unroll
    for (int i = 0; i < 4; ++i)
      vr[i].u = *reinterpret_cast<const uint2*>(
          qkv + (rb + t * 64 + s4 * 4 + i) * kDQKV + 2 * kD + hc + hd4 * 4);
  };
  auto writeV = [&](int bufi) {
    #pragma unroll
    for (int j = 0; j < 4; ++j) {
      int hd = hd4 * 4 + j;
      ushort4 o4;
      o4.x = vr[0].s[j]; o4.y = vr[1].s[j]; o4.z = vr[2].s[j]; o4.w = vr[3].s[j];
      *reinterpret_cast<ushort4*>(
          Vt[bufi] + hd * 128 + (((s4 >> 1) ^ (hd & 7)) << 4) + ((s4 & 1) << 3)) = o4;
    }
  };
  // interleaved weight conversion: 4 float4 (wi|wo2) + up to 1 float4 (wo) per slot
  float4 cw[4]; float4 cwo;
  auto cvLoad = [&](int t) {
    int g0 = ((orig * 16 + t) * 512 + tid) * 4;     // 0..8M-4
    #pragma unroll
    for (int j = 0; j < 4; ++j) {
      int g = g0 + j;
      const float* src = (g < (4 << 20)) ? wi : wo2;
      int off = g & ((4 << 20) - 1);
      cw[j] = reinterpret_cast<const float4*>(src)[off];
    }
    int slot = (orig * 16 + t) * 512 + tid;         // 0..2M-1
    if (slot < (1 << 20)) cwo = reinterpret_cast<const float4*>(wo)[slot];
  };
  auto cvStore = [&](int t) {
    int g0 = ((orig * 16 + t) * 512 + tid) * 4;
    #pragma unroll
    for (int j = 0; j < 4; ++j) {
      union { ushort4 u; __hip_bfloat16 hh[4]; } o4;
      o4.hh[0] = __float2bfloat16(cw[j].x);
      o4.hh[1] = __float2bfloat16(cw[j].y);
      o4.hh[2] = __float2bfloat16(cw[j].z);
      o4.hh[3] = __float2bfloat16(cw[j].w);
      reinterpret_cast<ushort4*>(outw)[(4 << 20) + g0 + j] = o4.u;
    }
    int slot = (orig * 16 + t) * 512 + tid;
    if (slot < (1 << 20)) {
      union { ushort4 u; __hip_bfloat16 hh[4]; } o4;
      o4.hh[0] = __float2bfloat16(cwo.x);
      o4.hh[1] = __float2bfloat16(cwo.y);
      o4.hh[2] = __float2bfloat16(cwo.z);
      o4.hh[3] = __float2bfloat16(cwo.w);
      reinterpret_cast<ushort4*>(outw)[(3 << 20) + slot] = o4.u;
    }
  };

  f32x4 o[2][8] = {};
  float mrun[2][4], lrun[2][4];
  #pragma unroll
  for (int s = 0; s < 2; ++s)
    #pragma unroll
    for (int r = 0; r < 4; ++r) { mrun[s][r] = -1e30f; lrun[s][r] = 0.f; }
  const float scale = 0.08838834764831845f;         // 1/sqrt(128)

  stageK(0, 0);
  loadV(0);
  writeV(0);
  __syncthreads();

  int buf = 0;
  for (int t = 0; t < 16; ++t) {
    if (t + 1 < 16) { stageK(buf ^ 1, t + 1); loadV(t + 1); }
    cvLoad(t);                                      // fp32 weight chunk in flight

    float mv[4];
    #pragma unroll
    for (int j = 0; j < 4; ++j) mv[j] = mask[(size_t)b * kS + t * 64 + j * 16 + lr];

    #pragma unroll
    for (int s = 0; s < 2; ++s) {
      f32x4 sacc[4] = {};
      #pragma unroll
      for (int j = 0; j < 4; ++j) {
        int key = j * 16 + lr;
        #pragma unroll
        for (int kk = 0; kk < 4; ++kk) {
          short8 bfrag = *reinterpret_cast<const short8*>(
              Ks[buf] + key * 256 + (((kk * 4 + lg) ^ (key & 15)) * 16));
          sacc[j] = __builtin_amdgcn_mfma_f32_16x16x32_bf16(qf[s][kk], bfrag, sacc[j], 0, 0, 0);
        }
      }
      float sarr[4][4];
      #pragma unroll
      for (int j = 0; j < 4; ++j)
        #pragma unroll
        for (int r = 0; r < 4; ++r) sarr[j][r] = sacc[j][r] * scale + mv[j];
      #pragma unroll
      for (int r = 0; r < 4; ++r) {
        float tm = fmaxf(fmaxf(sarr[0][r], sarr[1][r]), fmaxf(sarr[2][r], sarr[3][r]));
        #pragma unroll
        for (int d = 1; d < 16; d <<= 1) tm = fmaxf(tm, __shfl_xor(tm, d));
        float mnew = fmaxf(mrun[s][r], tm);
        float alpha = __expf(mrun[s][r] - mnew);
        mrun[s][r] = mnew;
        float rs = 0.f;
        #pragma unroll
        for (int j = 0; j < 4; ++j) {
          float p = __expf(sarr[j][r] - mnew);
          sarr[j][r] = p;
          rs += p;
        }
        #pragma unroll
        for (int d = 1; d < 16; d <<= 1) rs += __shfl_xor(rs, d);
        lrun[s][r] = lrun[s][r] * alpha + rs;
        #pragma unroll
        for (int n = 0; n < 8; ++n) o[s][n][r] *= alpha;
      }
      #pragma unroll
      for (int r = 0; r < 4; ++r) {
        int qr = lg * 4 + r;
        #pragma unroll
        for (int j = 0; j < 4; ++j)
          *reinterpret_cast<__hip_bfloat16*>(
              Ps[w] + ((qr * 128 + (j * 16 + lr) * 2) ^ ((qr & 7) << 4))) =
              __float2bfloat16(sarr[j][r]);
      }
      #pragma unroll
      for (int kk2 = 0; kk2 < 2; ++kk2) {
        short8 pa = *reinterpret_cast<const short8*>(
            Ps[w] + ((lr * 128 + kk2 * 64 + lg * 16) ^ ((lr & 7) << 4)));
        #pragma unroll
        for (int n = 0; n < 8; ++n) {
          int hd = n * 16 + lr;
          short8 vb = *reinterpret_cast<const short8*>(
              Vt[buf] + hd * 128 + (((kk2 * 4 + lg) ^ (hd & 7)) * 16));
          o[s][n] = __builtin_amdgcn_mfma_f32_16x16x32_bf16(pa, vb, o[s][n], 0, 0, 0);
        }
      }
    }
    cvStore(t);                                     // convert + store (auto-waits cw)
    if (t + 1 < 16) writeV(buf ^ 1);
    __syncthreads();
    buf ^= 1;
  }

  #pragma unroll
  for (int s = 0; s < 2; ++s)
    #pragma unroll
    for (int r = 0; r < 4; ++r) {
      float inv = 1.0f / lrun[s][r];
      int srow = qp * 256 + s * 128 + w * 16 + lg * 4 + r;
      __hip_bfloat16* cp = ctx + (rb + srow) * kD + hc + lr;
      #pragma unroll
      for (int n = 0; n < 8; ++n) cp[n * 16] = __float2bfloat16(o[s][n][r] * inv);
    }
}

// ----- LayerNorm over (bf16 p0 + bf16 p1 + bias + res), one 2048-row per block -----
template <bool WB16>
__global__ void ln_fuse(const __hip_bfloat16* __restrict__ p0,
                        const __hip_bfloat16* __restrict__ p1,
                        const float* __restrict__ bias, const float* __restrict__ res,
                        const float* __restrict__ w, const float* __restrict__ b,
                        float* __restrict__ outf, __hip_bfloat16* __restrict__ outb) {
  const int row = blockIdx.x, tid = threadIdx.x;
  const size_t base = (size_t)row * kD;
  short8 a = reinterpret_cast<const short8*>(p0 + base)[tid];
  short8 c = reinterpret_cast<const short8*>(p1 + base)[tid];
  float v[8];
  #pragma unroll
  for (int i = 0; i < 2; ++i) {
    int c4 = tid * 2 + i;
    float4 rr = reinterpret_cast<const float4*>(res + base)[c4];
    float4 bs = reinterpret_cast<const float4*>(bias)[c4];
    v[i * 4 + 0] = b2f(a[i * 4 + 0]) + b2f(c[i * 4 + 0]) + rr.x + bs.x;
    v[i * 4 + 1] = b2f(a[i * 4 + 1]) + b2f(c[i * 4 + 1]) + rr.y + bs.y;
    v[i * 4 + 2] = b2f(a[i * 4 + 2]) + b2f(c[i * 4 + 2]) + rr.z + bs.z;
    v[i * 4 + 3] = b2f(a[i * 4 + 3]) + b2f(c[i * 4 + 3]) + rr.w + bs.w;
  }
  float s = 0.f;
  #pragma unroll
  for (int i = 0; i < 8; ++i) s += v[i];
  #pragma unroll
  for (int off = 32; off > 0; off >>= 1) s += __shfl_down(s, off);
  __shared__ float r1[4], r2[4];
  if ((tid & 63) == 0) r1[tid >> 6] = s;
  __syncthreads();
  float mean = (r1[0] + r1[1] + r1[2] + r1[3]) * (1.0f / kD);
  float qv = 0.f;
  #pragma unroll
  for (int i = 0; i < 8; ++i) { float d = v[i] - mean; qv += d * d; }
  #pragma unroll
  for (int off = 32; off > 0; off >>= 1) qv += __shfl_down(qv, off);
  if ((tid & 63) == 0) r2[tid >> 6] = qv;
  __syncthreads();
  float rstd = rsqrtf((r2[0] + r2[1] + r2[2] + r2[3]) * (1.0f / kD) + kEPS);
  #pragma unroll
  for (int i = 0; i < 8; ++i) {
    int col = tid * 8 + i;
    float ov = (v[i] - mean) * rstd * w[col] + b[col];
    outf[base + col] = ov;
    if constexpr (WB16) outb[base + col] = __float2bfloat16(ov);
  }
}

// ---------------- launcher ----------------
extern "C" void kernel_launch(void* const* d_in, const int* in_sizes, int n_in,
                              void* d_out, int out_size, void* d_ws, size_t ws_size,
                              hipStream_t stream) {
  (void)in_sizes; (void)n_in; (void)out_size;
  if (ws_size < WS_NEED) return;
  const float* x    = (const float*)d_in[0];
  const float* mask = (const float*)d_in[1];
  const float* wq   = (const float*)d_in[2];
  const float* bq   = (const float*)d_in[3];
  const float* wk   = (const float*)d_in[4];
  const float* bk   = (const float*)d_in[5];
  const float* wv   = (const float*)d_in[6];
  const float* bv   = (const float*)d_in[7];
  const float* wo   = (const float*)d_in[8];
  const float* bo   = (const float*)d_in[9];
  const float* l1w  = (const float*)d_in[10];
  const float* l1b  = (const float*)d_in[11];
  const float* wi   = (const float*)d_in[12];
  const float* bi   = (const float*)d_in[13];
  const float* wo2  = (const float*)d_in[14];
  const float* bo2  = (const float*)d_in[15];
  const float* l2w  = (const float*)d_in[16];
  const float* l2b  = (const float*)d_in[17];

  char* ws = (char*)d_ws;
  __hip_bfloat16* wqb  = (__hip_bfloat16*)(ws + OFF_WQ);
  __hip_bfloat16* wob  = (__hip_bfloat16*)(ws + OFF_WO);
  __hip_bfloat16* wib  = (__hip_bfloat16*)(ws + OFF_WI);
  __hip_bfloat16* wo2b = (__hip_bfloat16*)(ws + OFF_WO2);
  __hip_bfloat16* xb   = (__hip_bfloat16*)(ws + OFF_XB);
  __hip_bfloat16* qkvb = (__hip_bfloat16*)(ws + OFF_Q);    // [4096][6144]
  __hip_bfloat16* hb   = (__hip_bfloat16*)(ws + OFF_H);
  __hip_bfloat16* ctxb = (__hip_bfloat16*)(ws + OFF_CTX);
  __hip_bfloat16* a1b  = (__hip_bfloat16*)(ws + OFF_A1B);
  float* y1   = (float*)(ws + OFF_Y1);                     // f32 attn_out
  __hip_bfloat16* wp0 = (__hip_bfloat16*)(ws + OFF_Y2);            // Wo partial 0
  __hip_bfloat16* wp1 = (__hip_bfloat16*)(ws + OFF_Y2 + SZ_MD16);  // Wo partial 1
  __hip_bfloat16* fp0 = (__hip_bfloat16*)(ws + OFF_WQ);            // FFN2 partial 0
  __hip_bfloat16* fp1 = (__hip_bfloat16*)(ws + OFF_WQ + SZ_MD16);  // FFN2 partial 1
  float* bqkv = (float*)(ws + OFF_Y2);   // 24KB concat bias; dead before Wo partials

  // conversions: x + wq/wk/wv + bias concat (wo/wi/wo2 handled inside attn)
  cvt_all<<<2048, 256, 0, stream>>>(x, wq, wk, wv, bq, bk, bv, wqb, bqkv);

  dim3 blk(512);
  // fused QKV projection: M=4096, N=6144, K=2048 -> grid 384, row-major out
  gemm256<0><<<dim3(384), blk, 0, stream>>>(
      xb, wqb, bqkv, nullptr, nullptr, qkvb, kM, kDQKV, kD, kD);
  // attention (256 blocks, 2 q-tiles each) + wo/wi/wo2 conversion
  attn_fwd<<<dim3(256), dim3(512), 0, stream>>>(qkvb, mask, ctxb, wo, wi, wo2, wqb);
  // out proj, split-K x2 (grid 256), bf16 partials wp0,wp1; LN1 fuses +bo+x
  gemm256<3><<<dim3(256), blk, 0, stream>>>(
      ctxb, wob, nullptr, wp0, wp1, nullptr, kM, kD, kD, kD / 2);
  ln_fuse<true><<<kM, 256, 0, stream>>>(wp0, wp1, bo, x, l1w, l1b, y1, a1b);
  // FFN1: grid 32*16 = 512, GELU epilogue
  gemm256<2><<<dim3(512), blk, 0, stream>>>(
      a1b, wib, bi, nullptr, nullptr, hb, kM, kF, kD, kD);
  // FFN2: split-K x2 (grid 256), bf16 partials fp0,fp1; LN2 fuses +bo2+attn_out(y1)
  gemm256<3><<<dim3(256), blk, 0, stream>>>(
      hb, wo2b, nullptr, fp0, fp1, nullptr, kM, kD, kF, kF / 2);
  ln_fuse<false><<<kM, 256, 0, stream>>>(fp0, fp1, bo2, y1, l2w, l2b, (float*)d_out, nullptr);
}

// Round 16
// 554.379 us; speedup vs baseline: 1.8684x; 1.0358x over previous
//
#include <hip/hip_runtime.h>
#include <hip/hip_bf16.h>
#include <cstdint>
#include <cstddef>

typedef __attribute__((ext_vector_type(8))) short short8;   // 8 x bf16 (4 VGPRs)
typedef __attribute__((ext_vector_type(4))) float f32x4;    // MFMA accumulator

#define DEV static __device__ __forceinline__

constexpr int kS = 1024, kD = 2048, kH = 16, kHD = 128, kF = 8192;
constexpr int kM = 4096;            // B*S rows
constexpr int kDQKV = 6144;         // row-major QKV width
constexpr float kEPS = 1e-5f;

// ---------------- workspace layout (bytes) ----------------
constexpr size_t SZ_DD   = (size_t)kD * kD * 2;    // 8 MB   bf16 DxD weight
constexpr size_t SZ_FD   = (size_t)kF * kD * 2;    // 32 MB  bf16 FxD weight
constexpr size_t SZ_MD16 = (size_t)kM * kD * 2;    // 16 MB  bf16 activation
constexpr size_t SZ_MD32 = (size_t)kM * kD * 4;    // 32 MB  f32 activation
constexpr size_t OFF_WQ  = 0;                      // wq..wo2,x contiguous bf16 region
constexpr size_t OFF_WK  = OFF_WQ + SZ_DD;
constexpr size_t OFF_WV  = OFF_WK + SZ_DD;
constexpr size_t OFF_WO  = OFF_WV + SZ_DD;
constexpr size_t OFF_WI  = OFF_WO + SZ_DD;
constexpr size_t OFF_WO2 = OFF_WI + SZ_FD;
constexpr size_t OFF_XB  = OFF_WO2 + SZ_FD;        // region reused for h later
constexpr size_t OFF_Q   = OFF_XB + SZ_MD16;       // row-major QKV [4096][6144] bf16 (48MB)
constexpr size_t OFF_H   = OFF_XB;                 // 64 MB: xb+qkv dead by FFN1
constexpr size_t OFF_CTX = OFF_Q + 3 * SZ_MD16;
constexpr size_t OFF_Y1  = OFF_CTX + SZ_MD16;      // (unused, kept for layout stability)
constexpr size_t OFF_A1B = OFF_Y1 + SZ_MD32;       // bf16 attn_out (LN1 output)
constexpr size_t OFF_Y2  = OFF_A1B + SZ_MD16;      // Wo bf16 partials (2x16MB); bqkv early
constexpr size_t WS_NEED = OFF_Y2 + SZ_MD32;       // 256 MB total
// FFN2 bf16 partials (2x16MB) reuse dead wq..wo region at OFF_WQ.

DEV void gload16(const void* g, void* l) {
  __builtin_amdgcn_global_load_lds(
      (const __attribute__((address_space(1))) unsigned int*)g,
      (__attribute__((address_space(3))) unsigned int*)l, 16, 0, 0);
}

DEV float b2f(short s) {
  union { unsigned u; float f; } x;
  x.u = ((unsigned)(unsigned short)s) << 16;
  return x.f;
}

// ------------- fp32->bf16 convert: wq,wk,wv + x + bias concat -------------
// wo/wi/wo2 conversions live INSIDE attn_fwd (overlap its latency slack).
// Dest ushort4 indices: wq..wv -> [0,3M); x -> [12M,14M).
__global__ void cvt_all(const float* __restrict__ x,  const float* __restrict__ wq,
                        const float* __restrict__ wk, const float* __restrict__ wv,
                        const float* __restrict__ bq, const float* __restrict__ bk,
                        const float* __restrict__ bv,
                        __hip_bfloat16* __restrict__ outw, float* __restrict__ bqkv) {
  constexpr int M1 = 1 << 20;          // float4 count of one DxD matrix
  constexpr int NW = 5 * M1;           // 3 DxD weights + x (2M float4)
  int stride = gridDim.x * blockDim.x;
  for (int i = blockIdx.x * blockDim.x + threadIdx.x; i < NW + 1536; i += stride) {
    if (i < NW) {
      const float* src; int off; int dst;
      if (i < 3 * M1) { src = (i < M1) ? wq : (i < 2 * M1) ? wk : wv;
                        off = i & (M1 - 1); dst = i; }
      else            { src = x; off = i - 3 * M1; dst = i + 9 * M1; }
      float4 v = reinterpret_cast<const float4*>(src)[off];
      union { ushort4 u; __hip_bfloat16 h[4]; } o;
      o.h[0] = __float2bfloat16(v.x);
      o.h[1] = __float2bfloat16(v.y);
      o.h[2] = __float2bfloat16(v.z);
      o.h[3] = __float2bfloat16(v.w);
      reinterpret_cast<ushort4*>(outw)[dst] = o.u;
    } else {
      int j = i - NW;                   // 0..1535 (512 float4 per bias)
      const float* src = (j < 512) ? bq : (j < 1024) ? bk : bv;
      reinterpret_cast<float4*>(bqkv)[j] =
          reinterpret_cast<const float4*>(src)[j & 511];
    }
  }
}

// ---------------- 256x256 GEMM (r8/r11 schedule — frozen) ----------------
// MODE 0: out bf16 = acc + bias at [row*N+col] (plain row-major; used for QKV)
// MODE 2: out bf16 = gelu(acc + bias) at [row*N+col]
// MODE 3: bf16 partial (split-K): out0/out1 selected by split index
template <int MODE>
__global__ __launch_bounds__(512, 2)
void gemm256(const __hip_bfloat16* __restrict__ A,
             const __hip_bfloat16* __restrict__ Bt,
             const float* __restrict__ bias,
             __hip_bfloat16* __restrict__ out0, __hip_bfloat16* __restrict__ out1,
             void* __restrict__ outb,
             int M, int N, int K, int kLen) {
  __shared__ __align__(16) char lds[131072];   // A: [2][256][64]b16 @0, B: @65536
  const int tid = threadIdx.x;
  const int lane = tid & 63, w = tid >> 6;
  const int wm = w >> 2, wn = w & 3;
  const int hw = w >> 2;
  const int lg = lane >> 4, lr = lane & 15;
  const int gy = M >> 8, gx = N >> 8;
  const int nwg = gridDim.x, orig = blockIdx.x;
  const int l = (orig & 7) * (nwg >> 3) + (orig >> 3);   // XCD-chunked (nwg%8==0)
  const int tilesPer = gx * gy;
  const int spl = l / tilesPer;
  const int rem = l - spl * tilesPer;
  const int bx = rem / gy, by = rem - bx * gy;           // n-panel-major
  const int m0 = by * 256, n0 = bx * 256;
  const int k0 = spl * kLen;
  const int NT = kLen >> 6;

  const char* gs[8];
  #pragma unroll
  for (int h = 0; h < 4; ++h) {
    const __hip_bfloat16* src = (h < 2) ? A : Bt;
    const int r0 = ((h < 2) ? m0 : n0) + (h & 1) * 128;
    #pragma unroll
    for (int i = 0; i < 2; ++i) {
      int c = i * 512 + tid;
      int row = c >> 3, slot = c & 7;
      gs[h * 2 + i] =
          (const char*)(src + (size_t)(r0 + row) * K + k0 + (slot ^ (row & 7)) * 8);
    }
  }

#define STAGE(P, H, TOFF)                                                          \
  {                                                                                \
    char* dstb = lds + (((H) < 2) ? 0 : 65536) + (P) * 32768 + ((H) & 1) * 16384;  \
    gload16(gs[(H) * 2 + 0] + (TOFF) * 128, dstb + (0 * 512 + tid) * 16);          \
    gload16(gs[(H) * 2 + 1] + (TOFF) * 128, dstb + (1 * 512 + tid) * 16);          \
  }

  auto ldA = [&](int P, int qm, int mr, int kk) {
    int row = qm * 128 + wm * 64 + mr * 16 + lr;
    return *reinterpret_cast<const short8*>(
        lds + P * 32768 + row * 128 + (((kk * 4 + lg) ^ (row & 7)) * 16));
  };
  auto ldB = [&](int P, int qn, int nr, int kk) {
    int row = qn * 128 + wn * 32 + nr * 16 + lr;
    return *reinterpret_cast<const short8*>(
        lds + 65536 + P * 32768 + row * 128 + (((kk * 4 + lg) ^ (row & 7)) * 16));
  };

  f32x4 acc[4][4][2] = {};   // [phase][mi][ni]

#define MFMA_HALF(p, kk, B)                                                     \
  _Pragma("unroll")                                                             \
  for (int mi = 0; mi < 4; ++mi)                                                \
    _Pragma("unroll")                                                           \
    for (int ni = 0; ni < 2; ++ni)                                              \
      acc[p][mi][ni] = __builtin_amdgcn_mfma_f32_16x16x32_bf16(                 \
          av[kk][mi], B[kk][ni], acc[p][mi][ni], 0, 0, 0);

#define WAIT_LGKM(n)                                                            \
  asm volatile("s_waitcnt lgkmcnt(" #n ")" ::: "memory");                       \
  __builtin_amdgcn_sched_barrier(0);

#define TILE_BODY(P, PF)                                                        \
  {                                                                             \
    asm volatile("s_waitcnt vmcnt(0)" ::: "memory");                            \
    __builtin_amdgcn_s_barrier();                                               \
    _Pragma("unroll")                                                           \
    for (int i = 0; i < 4; ++i) av[0][i] = ldA(P, hw, i, 0);                    \
    _Pragma("unroll")                                                           \
    for (int i = 0; i < 2; ++i) b0[0][i] = ldB(P, hw, i, 0);                    \
    _Pragma("unroll")                                                           \
    for (int i = 0; i < 4; ++i) av[1][i] = ldA(P, hw, i, 1);                    \
    _Pragma("unroll")                                                           \
    for (int i = 0; i < 2; ++i) b0[1][i] = ldB(P, hw, i, 1);                    \
    if (PF) { STAGE((P) ^ 1, 0, 1 + (P)) STAGE((P) ^ 1, 2, 1 + (P)) }           \
    WAIT_LGKM(6)                                                                \
    __builtin_amdgcn_s_setprio(1);                                              \
    MFMA_HALF(0, 0, b0)                                                         \
    WAIT_LGKM(0)                                                                \
    MFMA_HALF(0, 1, b0)                                                         \
    __builtin_amdgcn_s_setprio(0);                                              \
    _Pragma("unroll")                                                           \
    for (int i = 0; i < 2; ++i) b1[0][i] = ldB(P, 1 - hw, i, 0);                \
    _Pragma("unroll")                                                           \
    for (int i = 0; i < 2; ++i) b1[1][i] = ldB(P, 1 - hw, i, 1);                \
    if (PF) { STAGE((P) ^ 1, 3, 1 + (P)) STAGE((P) ^ 1, 1, 1 + (P)) }           \
    WAIT_LGKM(2)                                                                \
    __builtin_amdgcn_s_setprio(1);                                              \
    MFMA_HALF(1, 0, b1)                                                         \
    WAIT_LGKM(0)                                                                \
    MFMA_HALF(1, 1, b1)                                                         \
    __builtin_amdgcn_s_setprio(0);                                              \
    _Pragma("unroll")                                                           \
    for (int i = 0; i < 4; ++i) av[0][i] = ldA(P, 1 - hw, i, 0);                \
    _Pragma("unroll")                                                           \
    for (int i = 0; i < 4; ++i) av[1][i] = ldA(P, 1 - hw, i, 1);                \
    WAIT_LGKM(4)                                                                \
    __builtin_amdgcn_s_setprio(1);                                              \
    MFMA_HALF(2, 0, b1)                                                         \
    WAIT_LGKM(0)                                                                \
    MFMA_HALF(2, 1, b1)                                                         \
    __builtin_amdgcn_s_setprio(0);                                              \
    _Pragma("unroll")                                                           \
    for (int i = 0; i < 2; ++i) b0[0][i] = ldB(P, hw, i, 0);                    \
    _Pragma("unroll")                                                           \
    for (int i = 0; i < 2; ++i) b0[1][i] = ldB(P, hw, i, 1);                    \
    WAIT_LGKM(2)                                                                \
    __builtin_amdgcn_s_setprio(1);                                              \
    MFMA_HALF(3, 0, b0)                                                         \
    WAIT_LGKM(0)                                                                \
    MFMA_HALF(3, 1, b0)                                                         \
    __builtin_amdgcn_s_setprio(0);                                              \
  }

  STAGE(0, 0, 0) STAGE(0, 2, 0) STAGE(0, 3, 0) STAGE(0, 1, 0)

  for (int t2 = 0; t2 < NT; t2 += 2) {
    short8 av[2][4], b0[2][2], b1[2][2];
    TILE_BODY(0, true)
    TILE_BODY(1, (t2 + 2 < NT))
    #pragma unroll
    for (int j = 0; j < 8; ++j) gs[j] += 256;
  }
#undef TILE_BODY
#undef MFMA_HALF
#undef WAIT_LGKM
#undef STAGE

  // epilogue: p0:(hw,hw) p1:(hw,1-hw) p2:(1-hw,1-hw) p3:(1-hw,hw)
  #pragma unroll
  for (int p = 0; p < 4; ++p) {
    const int qm = (p < 2) ? hw : 1 - hw;
    const int qn = (p == 0 || p == 3) ? hw : 1 - hw;
    #pragma unroll
    for (int ni = 0; ni < 2; ++ni) {
      int col = n0 + qn * 128 + wn * 32 + ni * 16 + lr;
      float bvv = 0.f;
      if constexpr (MODE != 3) bvv = bias[col];
      #pragma unroll
      for (int mi = 0; mi < 4; ++mi) {
        int row0 = m0 + qm * 128 + wm * 64 + mi * 16 + lg * 4;
        #pragma unroll
        for (int r = 0; r < 4; ++r) {
          int row = row0 + r;
          float val = acc[p][mi][ni][r] + bvv;
          if constexpr (MODE == 0) {
            ((__hip_bfloat16*)outb)[(size_t)row * N + col] = __float2bfloat16(val);
          } else if constexpr (MODE == 2) {
            float g = 0.5f * val * (1.0f + erff(val * 0.70710678118654752f));
            ((__hip_bfloat16*)outb)[(size_t)row * N + col] = __float2bfloat16(g);
          } else {
            __hip_bfloat16* o = spl ? out1 : out0;
            o[(size_t)row * N + col] = __float2bfloat16(val);
          }
        }
      }
    }
  }
}

// ------- flash attention — row-major QKV input; 2 q-tiles/block; wo/wi/wo2 cvt -------
__global__ __launch_bounds__(512, 2)
void attn_fwd(const __hip_bfloat16* __restrict__ qkv,
              const float* __restrict__ mask,
              __hip_bfloat16* __restrict__ ctx,
              const float* __restrict__ wo,
              const float* __restrict__ wi, const float* __restrict__ wo2,
              __hip_bfloat16* __restrict__ outw /* ushort4: wo@3M, wi@4M, wo2@8M */) {
  __shared__ __align__(16) char Ks[2][64 * 256];    // [buf][key][dim] slot16^(row&15)
  __shared__ __align__(16) char Vt[2][128 * 128];   // [buf][hd][key64] slot8^(hd&7)
  __shared__ __align__(16) char Ps[8][2048];        // per-wave P [16][64], ^((row&7)<<4)
  const int tid = threadIdx.x, lane = tid & 63, w = tid >> 6;
  const int lg = lane >> 4, lr = lane & 15;
  const int orig = blockIdx.x;                      // 256 blocks
  const int l = (orig & 7) * 32 + (orig >> 3);      // XCD-chunked: 8 bh per XCD
  const int qp = l & 3, bh = l >> 2;                // q-pair 0..3, bh 0..63
  const int b = bh >> 4, h = bh & 15;
  const int s4 = tid >> 5, hd4 = tid & 31;          // V-transpose role
  const size_t rb = (size_t)b * kS;                 // global row base
  const int hc = h * kHD;                           // head column offset

  short8 qf[2][4];
  #pragma unroll
  for (int s = 0; s < 2; ++s) {
    const __hip_bfloat16* qp_ =
        qkv + (rb + qp * 256 + s * 128 + w * 16 + lr) * kDQKV + hc + lg * 8;
    #pragma unroll
    for (int kk = 0; kk < 4; ++kk)
      qf[s][kk] = *reinterpret_cast<const short8*>(qp_ + kk * 32);
  }

  auto stageK = [&](int bufi, int t) {
    #pragma unroll
    for (int i = 0; i < 2; ++i) {                   // K tile: 64 rows x 256B
      int c = i * 512 + tid;
      int row = c >> 4, slot = c & 15;
      gload16(qkv + (rb + t * 64 + row) * kDQKV + kD + hc + (slot ^ (row & 15)) * 8,
              Ks[bufi] + c * 16);
    }
  };
  union VU { uint2 u; ushort s[4]; };
  VU vr[4];
  auto loadV = [&](int t) {
    #pragma unroll
    for (int i = 0; i < 4; ++i)
      vr[i].u = *reinterpret_cast<const uint2*>(
          qkv + (rb + t * 64 + s4 * 4 + i) * kDQKV + 2 * kD + hc + hd4 * 4);
  };
  auto writeV = [&](int bufi) {
    #pragma unroll
    for (int j = 0; j < 4; ++j) {
      int hd = hd4 * 4 + j;
      ushort4 o4;
      o4.x = vr[0].s[j]; o4.y = vr[1].s[j]; o4.z = vr[2].s[j]; o4.w = vr[3].s[j];
      *reinterpret_cast<ushort4*>(
          Vt[bufi] + hd * 128 + (((s4 >> 1) ^ (hd & 7)) << 4) + ((s4 & 1) << 3)) = o4;
    }
  };
  // interleaved weight conversion: 4 float4 (wi|wo2) + up to 1 float4 (wo) per slot
  float4 cw[4]; float4 cwo;
  auto cvLoad = [&](int t) {
    int g0 = ((orig * 16 + t) * 512 + tid) * 4;     // 0..8M-4
    #pragma unroll
    for (int j = 0; j < 4; ++j) {
      int g = g0 + j;
      const float* src = (g < (4 << 20)) ? wi : wo2;
      int off = g & ((4 << 20) - 1);
      cw[j] = reinterpret_cast<const float4*>(src)[off];
    }
    int slot = (orig * 16 + t) * 512 + tid;         // 0..2M-1
    if (slot < (1 << 20)) cwo = reinterpret_cast<const float4*>(wo)[slot];
  };
  auto cvStore = [&](int t) {
    int g0 = ((orig * 16 + t) * 512 + tid) * 4;
    #pragma unroll
    for (int j = 0; j < 4; ++j) {
      union { ushort4 u; __hip_bfloat16 hh[4]; } o4;
      o4.hh[0] = __float2bfloat16(cw[j].x);
      o4.hh[1] = __float2bfloat16(cw[j].y);
      o4.hh[2] = __float2bfloat16(cw[j].z);
      o4.hh[3] = __float2bfloat16(cw[j].w);
      reinterpret_cast<ushort4*>(outw)[(4 << 20) + g0 + j] = o4.u;
    }
    int slot = (orig * 16 + t) * 512 + tid;
    if (slot < (1 << 20)) {
      union { ushort4 u; __hip_bfloat16 hh[4]; } o4;
      o4.hh[0] = __float2bfloat16(cwo.x);
      o4.hh[1] = __float2bfloat16(cwo.y);
      o4.hh[2] = __float2bfloat16(cwo.z);
      o4.hh[3] = __float2bfloat16(cwo.w);
      reinterpret_cast<ushort4*>(outw)[(3 << 20) + slot] = o4.u;
    }
  };

  f32x4 o[2][8] = {};
  float mrun[2][4], lrun[2][4];
  #pragma unroll
  for (int s = 0; s < 2; ++s)
    #pragma unroll
    for (int r = 0; r < 4; ++r) { mrun[s][r] = -1e30f; lrun[s][r] = 0.f; }
  const float scale = 0.08838834764831845f;         // 1/sqrt(128)

  stageK(0, 0);
  loadV(0);
  writeV(0);
  __syncthreads();

  int buf = 0;
  for (int t = 0; t < 16; ++t) {
    if (t + 1 < 16) { stageK(buf ^ 1, t + 1); loadV(t + 1); }
    cvLoad(t);                                      // fp32 weight chunk in flight

    float mv[4];
    #pragma unroll
    for (int j = 0; j < 4; ++j) mv[j] = mask[(size_t)b * kS + t * 64 + j * 16 + lr];

    #pragma unroll
    for (int s = 0; s < 2; ++s) {
      f32x4 sacc[4] = {};
      #pragma unroll
      for (int j = 0; j < 4; ++j) {
        int key = j * 16 + lr;
        #pragma unroll
        for (int kk = 0; kk < 4; ++kk) {
          short8 bfrag = *reinterpret_cast<const short8*>(
              Ks[buf] + key * 256 + (((kk * 4 + lg) ^ (key & 15)) * 16));
          sacc[j] = __builtin_amdgcn_mfma_f32_16x16x32_bf16(qf[s][kk], bfrag, sacc[j], 0, 0, 0);
        }
      }
      float sarr[4][4];
      #pragma unroll
      for (int j = 0; j < 4; ++j)
        #pragma unroll
        for (int r = 0; r < 4; ++r) sarr[j][r] = sacc[j][r] * scale + mv[j];
      #pragma unroll
      for (int r = 0; r < 4; ++r) {
        float tm = fmaxf(fmaxf(sarr[0][r], sarr[1][r]), fmaxf(sarr[2][r], sarr[3][r]));
        #pragma unroll
        for (int d = 1; d < 16; d <<= 1) tm = fmaxf(tm, __shfl_xor(tm, d));
        float mnew = fmaxf(mrun[s][r], tm);
        float alpha = __expf(mrun[s][r] - mnew);
        mrun[s][r] = mnew;
        float rs = 0.f;
        #pragma unroll
        for (int j = 0; j < 4; ++j) {
          float p = __expf(sarr[j][r] - mnew);
          sarr[j][r] = p;
          rs += p;
        }
        #pragma unroll
        for (int d = 1; d < 16; d <<= 1) rs += __shfl_xor(rs, d);
        lrun[s][r] = lrun[s][r] * alpha + rs;
        #pragma unroll
        for (int n = 0; n < 8; ++n) o[s][n][r] *= alpha;
      }
      #pragma unroll
      for (int r = 0; r < 4; ++r) {
        int qr = lg * 4 + r;
        #pragma unroll
        for (int j = 0; j < 4; ++j)
          *reinterpret_cast<__hip_bfloat16*>(
              Ps[w] + ((qr * 128 + (j * 16 + lr) * 2) ^ ((qr & 7) << 4))) =
              __float2bfloat16(sarr[j][r]);
      }
      #pragma unroll
      for (int kk2 = 0; kk2 < 2; ++kk2) {
        short8 pa = *reinterpret_cast<const short8*>(
            Ps[w] + ((lr * 128 + kk2 * 64 + lg * 16) ^ ((lr & 7) << 4)));
        #pragma unroll
        for (int n = 0; n < 8; ++n) {
          int hd = n * 16 + lr;
          short8 vb = *reinterpret_cast<const short8*>(
              Vt[buf] + hd * 128 + (((kk2 * 4 + lg) ^ (hd & 7)) * 16));
          o[s][n] = __builtin_amdgcn_mfma_f32_16x16x32_bf16(pa, vb, o[s][n], 0, 0, 0);
        }
      }
    }
    cvStore(t);                                     // convert + store (auto-waits cw)
    if (t + 1 < 16) writeV(buf ^ 1);
    __syncthreads();
    buf ^= 1;
  }

  #pragma unroll
  for (int s = 0; s < 2; ++s)
    #pragma unroll
    for (int r = 0; r < 4; ++r) {
      float inv = 1.0f / lrun[s][r];
      int srow = qp * 256 + s * 128 + w * 16 + lg * 4 + r;
      __hip_bfloat16* cp = ctx + (rb + srow) * kD + hc + lr;
      #pragma unroll
      for (int n = 0; n < 8; ++n) cp[n * 16] = __float2bfloat16(o[s][n][r] * inv);
    }
}

// -- LayerNorm over (bf16 p0 + bf16 p1 + f32 bias + bf16 res), one 2048-row/block --
// F32OUT=false: write bf16 only (LN1 -> a1b). F32OUT=true: write f32 (LN2 -> d_out).
template <bool F32OUT>
__global__ void ln_fuse(const __hip_bfloat16* __restrict__ p0,
                        const __hip_bfloat16* __restrict__ p1,
                        const float* __restrict__ bias,
                        const __hip_bfloat16* __restrict__ res,
                        const float* __restrict__ w, const float* __restrict__ b,
                        float* __restrict__ outf, __hip_bfloat16* __restrict__ outb) {
  const int row = blockIdx.x, tid = threadIdx.x;
  const size_t base = (size_t)row * kD;
  short8 a = reinterpret_cast<const short8*>(p0 + base)[tid];
  short8 c = reinterpret_cast<const short8*>(p1 + base)[tid];
  short8 rr = reinterpret_cast<const short8*>(res + base)[tid];
  float v[8];
  #pragma unroll
  for (int i = 0; i < 2; ++i) {
    int c4 = tid * 2 + i;
    float4 bs = reinterpret_cast<const float4*>(bias)[c4];
    v[i * 4 + 0] = b2f(a[i * 4 + 0]) + b2f(c[i * 4 + 0]) + b2f(rr[i * 4 + 0]) + bs.x;
    v[i * 4 + 1] = b2f(a[i * 4 + 1]) + b2f(c[i * 4 + 1]) + b2f(rr[i * 4 + 1]) + bs.y;
    v[i * 4 + 2] = b2f(a[i * 4 + 2]) + b2f(c[i * 4 + 2]) + b2f(rr[i * 4 + 2]) + bs.z;
    v[i * 4 + 3] = b2f(a[i * 4 + 3]) + b2f(c[i * 4 + 3]) + b2f(rr[i * 4 + 3]) + bs.w;
  }
  float s = 0.f;
  #pragma unroll
  for (int i = 0; i < 8; ++i) s += v[i];
  #pragma unroll
  for (int off = 32; off > 0; off >>= 1) s += __shfl_down(s, off);
  __shared__ float r1[4], r2[4];
  if ((tid & 63) == 0) r1[tid >> 6] = s;
  __syncthreads();
  float mean = (r1[0] + r1[1] + r1[2] + r1[3]) * (1.0f / kD);
  float qv = 0.f;
  #pragma unroll
  for (int i = 0; i < 8; ++i) { float d = v[i] - mean; qv += d * d; }
  #pragma unroll
  for (int off = 32; off > 0; off >>= 1) qv += __shfl_down(qv, off);
  if ((tid & 63) == 0) r2[tid >> 6] = qv;
  __syncthreads();
  float rstd = rsqrtf((r2[0] + r2[1] + r2[2] + r2[3]) * (1.0f / kD) + kEPS);
  #pragma unroll
  for (int i = 0; i < 8; ++i) {
    int col = tid * 8 + i;
    float ov = (v[i] - mean) * rstd * w[col] + b[col];
    if constexpr (F32OUT) outf[base + col] = ov;
    else                  outb[base + col] = __float2bfloat16(ov);
  }
}

// ---------------- launcher ----------------
extern "C" void kernel_launch(void* const* d_in, const int* in_sizes, int n_in,
                              void* d_out, int out_size, void* d_ws, size_t ws_size,
                              hipStream_t stream) {
  (void)in_sizes; (void)n_in; (void)out_size;
  if (ws_size < WS_NEED) return;
  const float* x    = (const float*)d_in[0];
  const float* mask = (const float*)d_in[1];
  const float* wq   = (const float*)d_in[2];
  const float* bq   = (const float*)d_in[3];
  const float* wk   = (const float*)d_in[4];
  const float* bk   = (const float*)d_in[5];
  const float* wv   = (const float*)d_in[6];
  const float* bv   = (const float*)d_in[7];
  const float* wo   = (const float*)d_in[8];
  const float* bo   = (const float*)d_in[9];
  const float* l1w  = (const float*)d_in[10];
  const float* l1b  = (const float*)d_in[11];
  const float* wi   = (const float*)d_in[12];
  const float* bi   = (const float*)d_in[13];
  const float* wo2  = (const float*)d_in[14];
  const float* bo2  = (const float*)d_in[15];
  const float* l2w  = (const float*)d_in[16];
  const float* l2b  = (const float*)d_in[17];

  char* ws = (char*)d_ws;
  __hip_bfloat16* wqb  = (__hip_bfloat16*)(ws + OFF_WQ);
  __hip_bfloat16* wob  = (__hip_bfloat16*)(ws + OFF_WO);
  __hip_bfloat16* wib  = (__hip_bfloat16*)(ws + OFF_WI);
  __hip_bfloat16* wo2b = (__hip_bfloat16*)(ws + OFF_WO2);
  __hip_bfloat16* xb   = (__hip_bfloat16*)(ws + OFF_XB);
  __hip_bfloat16* qkvb = (__hip_bfloat16*)(ws + OFF_Q);    // [4096][6144]
  __hip_bfloat16* hb   = (__hip_bfloat16*)(ws + OFF_H);
  __hip_bfloat16* ctxb = (__hip_bfloat16*)(ws + OFF_CTX);
  __hip_bfloat16* a1b  = (__hip_bfloat16*)(ws + OFF_A1B);  // bf16 attn_out (LN1 out)
  __hip_bfloat16* wp0 = (__hip_bfloat16*)(ws + OFF_Y2);            // Wo partial 0
  __hip_bfloat16* wp1 = (__hip_bfloat16*)(ws + OFF_Y2 + SZ_MD16);  // Wo partial 1
  __hip_bfloat16* fp0 = (__hip_bfloat16*)(ws + OFF_WQ);            // FFN2 partial 0
  __hip_bfloat16* fp1 = (__hip_bfloat16*)(ws + OFF_WQ + SZ_MD16);  // FFN2 partial 1
  float* bqkv = (float*)(ws + OFF_Y2);   // 24KB concat bias; dead before Wo partials

  // conversions: x + wq/wk/wv + bias concat (wo/wi/wo2 handled inside attn)
  cvt_all<<<2048, 256, 0, stream>>>(x, wq, wk, wv, bq, bk, bv, wqb, bqkv);

  dim3 blk(512);
  // fused QKV projection: M=4096, N=6144, K=2048 -> grid 384, row-major out
  gemm256<0><<<dim3(384), blk, 0, stream>>>(
      xb, wqb, bqkv, nullptr, nullptr, qkvb, kM, kDQKV, kD, kD);
  // attention (256 blocks, 2 q-tiles each) + wo/wi/wo2 conversion
  attn_fwd<<<dim3(256), dim3(512), 0, stream>>>(qkvb, mask, ctxb, wo, wi, wo2, wqb);
  // out proj, split-K x2 (grid 256), bf16 partials wp0,wp1; LN1 fuses +bo+xb -> a1b
  gemm256<3><<<dim3(256), blk, 0, stream>>>(
      ctxb, wob, nullptr, wp0, wp1, nullptr, kM, kD, kD, kD / 2);
  ln_fuse<false><<<kM, 256, 0, stream>>>(wp0, wp1, bo, xb, l1w, l1b, nullptr, a1b);
  // FFN1: grid 32*16 = 512, GELU epilogue
  gemm256<2><<<dim3(512), blk, 0, stream>>>(
      a1b, wib, bi, nullptr, nullptr, hb, kM, kF, kD, kD);
  // FFN2: split-K x2 (grid 256), bf16 partials fp0,fp1; LN2 fuses +bo2+a1b -> d_out
  gemm256<3><<<dim3(256), blk, 0, stream>>>(
      hb, wo2b, nullptr, fp0, fp1, nullptr, kM, kD, kF, kF / 2);
  ln_fuse<true><<<kM, 256, 0, stream>>>(fp0, fp1, bo2, a1b, l2w, l2b, (float*)d_out, nullptr);
}